// Round 7
// baseline (125.919 us; speedup 1.0000x reference)
//
#include <hip/hip_runtime.h>
#include <math.h>

// Problem constants (static config)
#define NB 1024     // batches
#define NS 64       // steps S
#define NT 63       // T = S-1
#define NV 192      // N = S*3 variables
#define BW 7        // band half-width+1 (fallback kernel)
#define NC 314      // constraint rows (fallback kernel)
#define NG 16       // 1024/64 wave-groups

// ws regions (per group, per lane): lane-transposed layout slot*64+lane
#define IN_SLOTS 328   // coeffs 0..191, rhs 192..255, steps 256..318, iv 320..323
#define BP_SLOTS 2048  // 64 steps x 32 precomputed band pieces
#define L_SLOTS  1536  // 8 per column (dinv, L1..L6, z) x 192
#define X_SLOTS  192
#define IN_COEF 0
#define IN_RHS  192
#define IN_STP  256
#define IN_IV   320

// ============================================================================
// K1: transpose inputs into lane-transposed ws layout (coalesced both sides).
// If wsBP != null, also precompute the 32 band-piece values per (step,batch)
// (formulas copied verbatim from the verified r5/r6 kernels).
// ============================================================================
__global__ __launch_bounds__(1024, 1)
void ode_tin(const float* __restrict__ coeffs,
             const float* __restrict__ rhs,
             const float* __restrict__ steps,
             const float* __restrict__ iv_rhs,
             float* __restrict__ wsIn,
             float* __restrict__ wsBP)
{
    const int g   = blockIdx.x;
    const int tid = threadIdx.x;
    __shared__ float tile[64 * 65];

    for (int c = 0; c < 3; ++c) {
        for (int idx = tid; idx < 64 * 64; idx += 1024) {
            const int b = idx >> 6, i = idx & 63;
            tile[b * 65 + i] = coeffs[(size_t)g * 12288 + (size_t)b * 192 + c * 64 + i];
        }
        __syncthreads();
        for (int idx = tid; idx < 64 * 64; idx += 1024) {
            const int i = idx >> 6, l = idx & 63;
            wsIn[((size_t)g * IN_SLOTS + IN_COEF + c * 64 + i) * 64 + l] = tile[l * 65 + i];
        }
        __syncthreads();
    }
    for (int idx = tid; idx < 64 * 64; idx += 1024) {
        const int b = idx >> 6, i = idx & 63;
        tile[b * 65 + i] = rhs[(size_t)g * 4096 + idx];
    }
    __syncthreads();
    for (int idx = tid; idx < 64 * 64; idx += 1024) {
        const int i = idx >> 6, l = idx & 63;
        wsIn[((size_t)g * IN_SLOTS + IN_RHS + i) * 64 + l] = tile[l * 65 + i];
    }
    __syncthreads();
    for (int idx = tid; idx < 64 * 63; idx += 1024) {
        const int b = idx / 63, i = idx - b * 63;
        tile[b * 65 + i] = steps[(size_t)g * 4032 + idx];
    }
    __syncthreads();
    for (int idx = tid; idx < 63 * 64; idx += 1024) {
        const int i = idx >> 6, l = idx & 63;
        wsIn[((size_t)g * IN_SLOTS + IN_STP + i) * 64 + l] = tile[l * 65 + i];
    }
    __syncthreads();
    for (int idx = tid; idx < 64 * 4; idx += 1024) {
        const int b = idx >> 2, i = idx & 3;
        tile[b * 65 + i] = iv_rhs[(size_t)g * 256 + idx];
    }
    __syncthreads();
    for (int idx = tid; idx < 4 * 64; idx += 1024) {
        const int i = idx >> 6, l = idx & 63;
        wsIn[((size_t)g * IN_SLOTS + IN_IV + i) * 64 + l] = tile[l * 65 + i];
    }

    // ---- band-piece precompute (reads raw globals; order-independent) ----
    if (wsBP != nullptr) {
        for (int idx = tid; idx < 64 * 64; idx += 1024) {
            const int t = idx >> 6;   // step 0..63
            const int l = idx & 63;   // batch lane
            const int b = g * 64 + l;

            const float c0 = coeffs[(size_t)b * 192 + 3 * t + 0];
            const float c1 = coeffs[(size_t)b * 192 + 3 * t + 1];
            const float c2 = coeffs[(size_t)b * 192 + 3 * t + 2];
            const float r  = rhs[(size_t)b * 64 + t];
            const float pp = (t >= 2) ? steps[(size_t)b * 63 + t - 2] : 0.f;
            const float p  = (t >= 1) ? steps[(size_t)b * 63 + t - 1] : 0.f;
            const float s  = (t < 63) ? steps[(size_t)b * 63 + t] : 0.f;
            const float sn = (t + 1 < 63) ? steps[(size_t)b * 63 + t + 1] : 0.f;
            float iv0 = 0.f, iv1 = 0.f;
            if (t < 2) {
                iv0 = iv_rhs[(size_t)b * 4 + t * 2 + 0];
                iv1 = iv_rhs[(size_t)b * 4 + t * 2 + 1];
            }

            const float s2 = s*s, s3 = s2*s, p2 = p*p, p3 = p2*p;
            const float gt = p + s;
            const float mP  = (t >= 1) ? 1.f : 0.f;
            const float rg  = (t < 2) ? 1.f : 0.f;
            const float mSb  = (t < 63) ? 1.f : 0.f;
            const float mCNb = (t < 62) ? 1.f : 0.f;

            float v[32];
            // fwd pieces (valid/used for t <= 31; fwd chain has mS=mCN=1 there)
            v[0]  = c0*c0 + rg + 2.f*(1.f + mP);      // A0
            v[1]  = c0*c1 + s - p;                     // A1
            v[2]  = c0*c2 + 0.5f*(s2 + p2);            // A2
            v[3]  = s;                                 // A4
            v[4]  = -0.5f*s2;                          // A5
            v[5]  = c1*c1 + 3.f*(s2 + p2) + 2.f;       // B0
            v[6]  = c1*c2 + 1.5f*(s3 - p3);            // B1
            v[7]  = -s;                                // B2
            v[8]  = -2.f*s2;                           // B3
            v[9]  = s3 + (s + sn);                     // B4
            v[10] = c2*c2 + 1.25f*(s2*s2 + p2*p2) + gt*gt*mP;  // Cv0
            v[11] = -0.5f*s2;                          // Cv1
            v[12] = -s3 - gt*mP;                       // Cv2
            v[13] = c0*r + iv0;                        // rv0
            v[14] = c1*r + iv1;                        // rv1
            v[15] = c2*r;                              // rv2
            // bwd pieces (used for t >= 32)
            v[16] = c0*c0 + 2.f*(mSb + 1.f);           // A0b
            v[17] = c0*c1 + s - p;                     // A1b
            v[18] = c0*c2 + 0.5f*(s2 + p2);            // A2b
            v[19] = c1*c1 + 3.f*(s2 + p2) + mCNb + 1.f;// B0b
            v[20] = c1*c2 + 1.5f*(s3 - p3);            // B1b
            v[21] = c2*c2 + 1.25f*(s2*s2 + p2*p2) + gt*gt*mSb; // Cv0b
            v[22] = p;                                 // A4m
            v[23] = -0.5f*p2;                          // A5m
            v[24] = -p;                                // B2m
            v[25] = -2.f*p2;                           // B3m
            v[26] = p3 + (p + s)*mSb;                  // B4m
            v[27] = -0.5f*p2;                          // Cv1m
            v[28] = -p3 - (pp + p);                    // Cv2m
            v[29] = c0*r;                              // rv0b
            v[30] = c1*r;                              // rv1b
            v[31] = c2*r;                              // rv2b

            float* __restrict__ dst = wsBP + ((size_t)g * BP_SLOTS + (size_t)t * 32) * 64 + l;
            #pragma unroll
            for (int k = 0; k < 32; ++k) dst[(size_t)k * 64] = v[k];
        }
    }
}

// ============================================================================
// Shared macros for the twisted dual-chain kernels
// ============================================================================
#define CHOL_COL_G(W, Y, j, b0, b1, b2, b3, b4, b5, b6, rvv)                   \
    {                                                                          \
        const float t0_ = (b0) - (W##11*W##11 + W##22*W##22 + W##33*W##33 +    \
                                  W##44*W##44 + W##55*W##55 + W##66*W##66);    \
        const float di_ = rsqrtf(t0_);                                         \
        const float u1_ = (b1) - (W##11*W##12 + W##22*W##23 + W##33*W##34 +    \
                                  W##44*W##45 + W##55*W##56);                  \
        const float u2_ = (b2) - (W##11*W##13 + W##22*W##24 + W##33*W##35 +    \
                                  W##44*W##46);                                \
        const float u3_ = (b3) - (W##11*W##14 + W##22*W##25 + W##33*W##36);    \
        const float u4_ = (b4) - (W##11*W##15 + W##22*W##26);                  \
        const float u5_ = (b5) - (W##11*W##16);                                \
        const float u6_ = (b6);                                                \
        const float yj_ = ((rvv) - (W##11*Y##1 + W##22*Y##2 + W##33*Y##3 +     \
                                    W##44*Y##4 + W##55*Y##5 + W##66*Y##6))*di_;\
        const float n1_ = u1_*di_, n2_ = u2_*di_, n3_ = u3_*di_;               \
        const float n4_ = u4_*di_, n5_ = u5_*di_, n6_ = u6_*di_;               \
        SL((j)*8 + 0) = di_; SL((j)*8 + 1) = n1_; SL((j)*8 + 2) = n2_;         \
        SL((j)*8 + 3) = n3_; SL((j)*8 + 4) = n4_; SL((j)*8 + 5) = n5_;         \
        SL((j)*8 + 6) = n6_; SL((j)*8 + 7) = yj_;                              \
        W##66 = W##56;                                                         \
        W##55 = W##45; W##56 = W##46;                                          \
        W##44 = W##34; W##45 = W##35; W##46 = W##36;                           \
        W##33 = W##23; W##34 = W##24; W##35 = W##25; W##36 = W##26;            \
        W##22 = W##12; W##23 = W##13; W##24 = W##14; W##25 = W##15;            \
        W##26 = W##16;                                                         \
        W##11 = n1_; W##12 = n2_; W##13 = n3_; W##14 = n4_; W##15 = n5_;       \
        W##16 = n6_;                                                           \
        Y##6 = Y##5; Y##5 = Y##4; Y##4 = Y##3; Y##3 = Y##2; Y##2 = Y##1;       \
        Y##1 = yj_;                                                            \
    }

#define MIDDLE_AND_BACKSUB()                                                   \
    {                                                                          \
        const float pA  = SLI(IN_STP + 30), sA = SLI(IN_STP + 31);             \
        const float snA = SLI(IN_STP + 32), sB = SLI(IN_STP + 32);             \
        const float pB  = sA;                                                  \
        const float c0A = SLI(IN_COEF + 93), c1A = SLI(IN_COEF + 94), c2A = SLI(IN_COEF + 95); \
        const float c0B = SLI(IN_COEF + 96), c1B = SLI(IN_COEF + 97), c2B = SLI(IN_COEF + 98); \
        const float rA  = SLI(IN_RHS + 31),  rB  = SLI(IN_RHS + 32);           \
        const float sA2 = sA*sA, sA3 = sA2*sA, pA2 = pA*pA, pA3 = pA2*pA;      \
        const float sB2 = sB*sB, sB3 = sB2*sB, pB2 = pB*pB, pB3 = pB2*pB;      \
        float S00 = c0A*c0A + 4.f;                                             \
        float S10 = c0A*c1A + sA - pA;                                         \
        float S20 = c0A*c2A + 0.5f*(sA2 + pA2);                                \
        float S30 = -2.f;                                                      \
        float S40 = sA;                                                        \
        float S50 = -0.5f*sA2;                                                 \
        float S11 = c1A*c1A + 3.f*(sA2 + pA2) + 2.f;                           \
        float S21 = c1A*c2A + 1.5f*(sA3 - pA3);                                \
        float S31 = -sA;                                                       \
        float S41 = -2.f*sA2;                                                  \
        float S51 = sA3 + (sA + snA);                                          \
        float S22 = c2A*c2A + 1.25f*(sA2*sA2 + pA2*pA2) + (pA + sA)*(pA + sA); \
        float S32 = -0.5f*sA2;                                                 \
        float S42 = -sA3 - (pA + sA);                                          \
        float S52 = 0.f;                                                       \
        float S33 = c0B*c0B + 4.f;                                             \
        float S43 = c0B*c1B + sB - pB;                                         \
        float S53 = c0B*c2B + 0.5f*(sB2 + pB2);                                \
        float S44 = c1B*c1B + 3.f*(sB2 + pB2) + 2.f;                           \
        float S54 = c1B*c2B + 1.5f*(sB3 - pB3);                                \
        float S55 = c2B*c2B + 1.25f*(sB2*sB2 + pB2*pB2) + (pB + sB)*(pB + sB); \
        S00 -= W11*W11 + W22*W22 + W33*W33 + W44*W44 + W55*W55 + W66*W66;      \
        S10 -= W12*W11 + W23*W22 + W34*W33 + W45*W44 + W56*W55;                \
        S11 -= W12*W12 + W23*W23 + W34*W34 + W45*W45 + W56*W56;                \
        S20 -= W13*W11 + W24*W22 + W35*W33 + W46*W44;                          \
        S21 -= W13*W12 + W24*W23 + W35*W34 + W46*W45;                          \
        S22 -= W13*W13 + W24*W24 + W35*W35 + W46*W46;                          \
        S30 -= W14*W11 + W25*W22 + W36*W33;                                    \
        S31 -= W14*W12 + W25*W23 + W36*W34;                                    \
        S32 -= W14*W13 + W25*W24 + W36*W35;                                    \
        S33 -= W14*W14 + W25*W25 + W36*W36;                                    \
        S40 -= W15*W11 + W26*W22;                                              \
        S41 -= W15*W12 + W26*W23;                                              \
        S42 -= W15*W13 + W26*W24;                                              \
        S43 -= W15*W14 + W26*W25;                                              \
        S44 -= W15*W15 + W26*W26;                                              \
        S50 -= W16*W11;                                                        \
        S51 -= W16*W12;                                                        \
        S52 -= W16*W13;                                                        \
        S53 -= W16*W14;                                                        \
        S54 -= W16*W15;                                                        \
        S55 -= W16*W16;                                                        \
        S00 -= V16*V16;                                                        \
        S10 -= V15*V16;                                                        \
        S11 -= V15*V15 + V26*V26;                                              \
        S20 -= V14*V16;                                                        \
        S21 -= V14*V15 + V25*V26;                                              \
        S22 -= V14*V14 + V25*V25 + V36*V36;                                    \
        S30 -= V13*V16;                                                        \
        S31 -= V13*V15 + V24*V26;                                              \
        S32 -= V13*V14 + V24*V25 + V35*V36;                                    \
        S33 -= V13*V13 + V24*V24 + V35*V35 + V46*V46;                          \
        S40 -= V12*V16;                                                        \
        S41 -= V12*V15 + V23*V26;                                              \
        S42 -= V12*V14 + V23*V25 + V34*V36;                                    \
        S43 -= V12*V13 + V23*V24 + V34*V35 + V45*V46;                          \
        S44 -= V12*V12 + V23*V23 + V34*V34 + V45*V45 + V56*V56;                \
        S50 -= V11*V16;                                                        \
        S51 -= V11*V15 + V22*V26;                                              \
        S52 -= V11*V14 + V22*V25 + V33*V36;                                    \
        S53 -= V11*V13 + V22*V24 + V33*V35 + V44*V46;                          \
        S54 -= V11*V12 + V22*V23 + V33*V34 + V44*V45 + V55*V56;                \
        S55 -= V11*V11 + V22*V22 + V33*V33 + V44*V44 + V55*V55 + V66*V66;      \
        float fm0 = c0A*rA - (W11*fy1 + W22*fy2 + W33*fy3 + W44*fy4 + W55*fy5 + W66*fy6) \
                           - (V16*bz1);                                        \
        float fm1 = c1A*rA - (W12*fy1 + W23*fy2 + W34*fy3 + W45*fy4 + W56*fy5) \
                           - (V15*bz1 + V26*bz2);                              \
        float fm2 = c2A*rA - (W13*fy1 + W24*fy2 + W35*fy3 + W46*fy4)           \
                           - (V14*bz1 + V25*bz2 + V36*bz3);                    \
        float fm3 = c0B*rB - (W14*fy1 + W25*fy2 + W36*fy3)                     \
                           - (V13*bz1 + V24*bz2 + V35*bz3 + V46*bz4);          \
        float fm4 = c1B*rB - (W15*fy1 + W26*fy2)                               \
                           - (V12*bz1 + V23*bz2 + V34*bz3 + V45*bz4 + V56*bz5);\
        float fm5 = c2B*rB - (W16*fy1)                                         \
                           - (V11*bz1 + V22*bz2 + V33*bz3 + V44*bz4 + V55*bz5 + V66*bz6); \
        const float md0 = rsqrtf(S00);                                         \
        const float M10 = S10*md0, M20 = S20*md0, M30 = S30*md0,               \
                    M40 = S40*md0, M50 = S50*md0;                              \
        const float zm0 = fm0*md0;                                             \
        const float md1 = rsqrtf(S11 - M10*M10);                               \
        const float M21 = (S21 - M20*M10)*md1;                                 \
        const float M31 = (S31 - M30*M10)*md1;                                 \
        const float M41 = (S41 - M40*M10)*md1;                                 \
        const float M51 = (S51 - M50*M10)*md1;                                 \
        const float zm1 = (fm1 - M10*zm0)*md1;                                 \
        const float md2 = rsqrtf(S22 - M20*M20 - M21*M21);                     \
        const float M32 = (S32 - M30*M20 - M31*M21)*md2;                       \
        const float M42 = (S42 - M40*M20 - M41*M21)*md2;                       \
        const float M52 = (S52 - M50*M20 - M51*M21)*md2;                       \
        const float zm2 = (fm2 - M20*zm0 - M21*zm1)*md2;                       \
        const float md3 = rsqrtf(S33 - M30*M30 - M31*M31 - M32*M32);           \
        const float M43 = (S43 - M40*M30 - M41*M31 - M42*M32)*md3;             \
        const float M53 = (S53 - M50*M30 - M51*M31 - M52*M32)*md3;             \
        const float zm3 = (fm3 - M30*zm0 - M31*zm1 - M32*zm2)*md3;             \
        const float md4 = rsqrtf(S44 - M40*M40 - M41*M41 - M42*M42 - M43*M43); \
        const float M54 = (S54 - M50*M40 - M51*M41 - M52*M42 - M53*M43)*md4;   \
        const float zm4 = (fm4 - M40*zm0 - M41*zm1 - M42*zm2 - M43*zm3)*md4;   \
        const float md5 = rsqrtf(S55 - M50*M50 - M51*M51 - M52*M52 - M53*M53 - M54*M54); \
        const float zm5 = (fm5 - M50*zm0 - M51*zm1 - M52*zm2 - M53*zm3 - M54*zm4)*md5;   \
        const float xm5 = zm5*md5;                                             \
        const float xm4 = (zm4 - M54*xm5)*md4;                                 \
        const float xm3 = (zm3 - M43*xm4 - M53*xm5)*md3;                       \
        const float xm2 = (zm2 - M32*xm3 - M42*xm4 - M52*xm5)*md2;             \
        const float xm1 = (zm1 - M21*xm2 - M31*xm3 - M41*xm4 - M51*xm5)*md1;   \
        const float xm0 = (zm0 - M10*xm1 - M20*xm2 - M30*xm3 - M40*xm4 - M50*xm5)*md0;   \
        SX(93) = xm0; SX(94) = xm1; SX(95) = xm2;                              \
        SX(96) = xm3; SX(97) = xm4; SX(98) = xm5;                              \
        float x1 = xm0, x2 = xm1, x3 = xm2, x4 = xm3, x5 = xm4, x6 = xm5;      \
        float w1 = xm5, w2 = xm4, w3 = xm3, w4 = xm2, w5 = xm1, w6 = xm0;      \
        DECL8(TPA) DECL8(TPB) DECL8(TPC) DECL8(TQA) DECL8(TQB) DECL8(TQC)      \
        DECL8(BPA) DECL8(BPB) DECL8(BPC) DECL8(BQA) DECL8(BQB) DECL8(BQC)      \
        LOAD8(TPC, 92) LOAD8(TPB, 91) LOAD8(TPA, 90)                           \
        LOAD8(BPA, 99) LOAD8(BPB, 100) LOAD8(BPC, 101)                         \
        for (int it = 0; it < 32; it += 2) {                                   \
            BS_BODY(TPA,TPB,TPC, TQA,TQB,TQC, BPA,BPB,BPC, BQA,BQB,BQC, it)    \
            BS_BODY(TQA,TQB,TQC, TPA,TPB,TPC, BQA,BQB,BQC, BPA,BPB,BPC, it + 1)\
        }                                                                      \
    }

#define DECL8(P) float P##d = 0, P##1 = 0, P##2 = 0, P##3 = 0,                 \
                       P##4 = 0, P##5 = 0, P##6 = 0, P##y = 0;
#define LOAD8(P, j) { const size_t o8 = (size_t)(j)*8;                         \
        P##d = SL(o8 + 0); P##1 = SL(o8 + 1); P##2 = SL(o8 + 2);               \
        P##3 = SL(o8 + 3); P##4 = SL(o8 + 4); P##5 = SL(o8 + 5);               \
        P##6 = SL(o8 + 6); P##y = SL(o8 + 7); }
#define BSUB_T(P, j) {                                                         \
        const float rest = (P##6*x6 + P##5*x5) + (P##4*x4 + P##3*x3) + P##2*x2;\
        const float xr = ((P##y - rest) - P##1*x1) * P##d;                     \
        SX(j) = xr;                                                            \
        x6 = x5; x5 = x4; x4 = x3; x3 = x2; x2 = x1; x1 = xr; }
#define BSUB_B(P, j) {                                                         \
        const float rest = (P##6*w6 + P##5*w5) + (P##4*w4 + P##3*w3) + P##2*w2;\
        const float xr = ((P##y - rest) - P##1*w1) * P##d;                     \
        SX(j) = xr;                                                            \
        w6 = w5; w5 = w4; w4 = w3; w3 = w2; w2 = w1; w1 = xr; }
#define BS_BODY(TCA,TCB,TCC, TNA,TNB,TNC, BCA,BCB,BCC, BNA,BNB,BNC, IT)        \
    {                                                                          \
        if ((IT) <= 29) {                                                      \
            const int tt = 29 - (IT);                                          \
            LOAD8(TNC, 3*tt + 2) LOAD8(TNB, 3*tt + 1) LOAD8(TNA, 3*tt)         \
            const int bb = 34 + (IT);                                          \
            LOAD8(BNA, 3*bb) LOAD8(BNB, 3*bb + 1) LOAD8(BNC, 3*bb + 2)         \
        }                                                                      \
        if ((IT) <= 30) {                                                      \
            const int ct = 30 - (IT);                                          \
            BSUB_T(TCC, 3*ct + 2) BSUB_T(TCB, 3*ct + 1) BSUB_T(TCA, 3*ct)      \
            const int cb = 33 + (IT);                                          \
            BSUB_B(BCA, 3*cb) BSUB_B(BCB, 3*cb + 1) BSUB_B(BCC, 3*cb + 2)      \
        }                                                                      \
    }

// ============================================================================
// K2 (path A): dual-chain twisted factorization, band pieces PRELOADED from
// wsBP. grid=2 x block=512 -> 8 waves/CU = 2 waves/SIMD (TLP + full ILP).
// ============================================================================
__global__ __launch_bounds__(512, 2)
void ode_fused5(const float* __restrict__ wsIn,
                const float* __restrict__ wsBP,
                float* __restrict__ wsL,
                float* __restrict__ wsX)
{
    const int tid = threadIdx.x;
    const int g   = blockIdx.x * 8 + (tid >> 6);
    const int l   = tid & 63;

    const float* __restrict__ inA = wsIn + (size_t)g * IN_SLOTS * 64 + l;
    const float* __restrict__ bpA = wsBP + (size_t)g * BP_SLOTS * 64 + l;
    float* __restrict__ lnA = wsL + (size_t)g * L_SLOTS * 64 + l;
    float* __restrict__ xA  = wsX + (size_t)g * X_SLOTS * 64 + l;

#define SLI(i) inA[(size_t)(i) * 64]
#define SBP(t, k) bpA[(size_t)((t) * 32 + (k)) * 64]
#define SL(i)  lnA[(size_t)(i) * 64]
#define SX(i)  xA[(size_t)(i) * 64]

    float W11=0,W12=0,W13=0,W14=0,W15=0,W16=0;
    float W22=0,W23=0,W24=0,W25=0,W26=0;
    float W33=0,W34=0,W35=0,W36=0;
    float W44=0,W45=0,W46=0;
    float W55=0,W56=0;
    float W66=0;
    float fy1=0,fy2=0,fy3=0,fy4=0,fy5=0,fy6=0;

    float V11=0,V12=0,V13=0,V14=0,V15=0,V16=0;
    float V22=0,V23=0,V24=0,V25=0,V26=0;
    float V33=0,V34=0,V35=0,V36=0;
    float V44=0,V45=0,V46=0;
    float V55=0,V56=0;
    float V66=0;
    float bz1=0,bz2=0,bz3=0,bz4=0,bz5=0,bz6=0;

    // preload current pieces: fwd t=0 (k 0..15), bwd bt=63 (k 16..31)
    float F0 = SBP(0,0),  F1 = SBP(0,1),  F2 = SBP(0,2),  F3 = SBP(0,3);
    float F4 = SBP(0,4),  F5 = SBP(0,5),  F6 = SBP(0,6),  F7 = SBP(0,7);
    float F8 = SBP(0,8),  F9 = SBP(0,9),  F10 = SBP(0,10), F11 = SBP(0,11);
    float F12 = SBP(0,12), F13 = SBP(0,13), F14 = SBP(0,14), F15 = SBP(0,15);
    float G0 = SBP(63,16), G1 = SBP(63,17), G2 = SBP(63,18), G3 = SBP(63,19);
    float G4 = SBP(63,20), G5 = SBP(63,21), G6 = SBP(63,22), G7 = SBP(63,23);
    float G8 = SBP(63,24), G9 = SBP(63,25), G10 = SBP(63,26), G11 = SBP(63,27);
    float G12 = SBP(63,28), G13 = SBP(63,29), G14 = SBP(63,30), G15 = SBP(63,31);

    for (int t = 0; t <= 30; ++t) {
        const int bt = 63 - t;
        // prefetch next pieces (independent loads; consumed after shift)
        const float nF0 = SBP(t+1,0),  nF1 = SBP(t+1,1),  nF2 = SBP(t+1,2),  nF3 = SBP(t+1,3);
        const float nF4 = SBP(t+1,4),  nF5 = SBP(t+1,5),  nF6 = SBP(t+1,6),  nF7 = SBP(t+1,7);
        const float nF8 = SBP(t+1,8),  nF9 = SBP(t+1,9),  nF10 = SBP(t+1,10), nF11 = SBP(t+1,11);
        const float nF12 = SBP(t+1,12), nF13 = SBP(t+1,13), nF14 = SBP(t+1,14), nF15 = SBP(t+1,15);
        const float nG0 = SBP(bt-1,16), nG1 = SBP(bt-1,17), nG2 = SBP(bt-1,18), nG3 = SBP(bt-1,19);
        const float nG4 = SBP(bt-1,20), nG5 = SBP(bt-1,21), nG6 = SBP(bt-1,22), nG7 = SBP(bt-1,23);
        const float nG8 = SBP(bt-1,24), nG9 = SBP(bt-1,25), nG10 = SBP(bt-1,26), nG11 = SBP(bt-1,27);
        const float nG12 = SBP(bt-1,28), nG13 = SBP(bt-1,29), nG14 = SBP(bt-1,30), nG15 = SBP(bt-1,31);

        const int j0 = 3*t, k0 = 3*bt;
        CHOL_COL_G(W, fy, j0 + 0, F0,  F1,  F2,  -2.f, F3,  F4,  0.f, F13);
        CHOL_COL_G(V, bz, k0 + 2, G5,  G4,  G2,  0.f,  G10, G7,  0.f, G15);
        CHOL_COL_G(W, fy, j0 + 1, F5,  F6,  F7,  F8,   F9,  0.f, -1.f, F14);
        CHOL_COL_G(V, bz, k0 + 1, G3,  G1,  G12, G9,   G6,  0.f, -1.f, G14);
        CHOL_COL_G(W, fy, j0 + 2, F10, F11, F12, 0.f,  0.f, 0.f, 0.f, F15);
        CHOL_COL_G(V, bz, k0 + 0, G0,  G11, G8,  -2.f, 0.f, 0.f, 0.f, G13);

        F0 = nF0; F1 = nF1; F2 = nF2; F3 = nF3; F4 = nF4; F5 = nF5;
        F6 = nF6; F7 = nF7; F8 = nF8; F9 = nF9; F10 = nF10; F11 = nF11;
        F12 = nF12; F13 = nF13; F14 = nF14; F15 = nF15;
        G0 = nG0; G1 = nG1; G2 = nG2; G3 = nG3; G4 = nG4; G5 = nG5;
        G6 = nG6; G7 = nG7; G8 = nG8; G9 = nG9; G10 = nG10; G11 = nG11;
        G12 = nG12; G13 = nG13; G14 = nG14; G15 = nG15;
    }

    MIDDLE_AND_BACKSUB()

#undef SLI
#undef SBP
#undef SL
#undef SX
}

// ============================================================================
// K2 (path B fallback): r5-exact dual-chain kernel (pieces computed inline),
// same 2x512 geometry.
// ============================================================================
__global__ __launch_bounds__(512, 2)
void ode_fused3b(const float* __restrict__ wsIn,
                 float* __restrict__ wsL,
                 float* __restrict__ wsX)
{
    const int tid = threadIdx.x;
    const int g   = blockIdx.x * 8 + (tid >> 6);
    const int l   = tid & 63;

    const float* __restrict__ inA = wsIn + (size_t)g * IN_SLOTS * 64 + l;
    float* __restrict__ lnA = wsL + (size_t)g * L_SLOTS * 64 + l;
    float* __restrict__ xA  = wsX + (size_t)g * X_SLOTS * 64 + l;

#define SLI(i) inA[(size_t)(i) * 64]
#define SL(i)  lnA[(size_t)(i) * 64]
#define SX(i)  xA[(size_t)(i) * 64]

    float W11=0,W12=0,W13=0,W14=0,W15=0,W16=0;
    float W22=0,W23=0,W24=0,W25=0,W26=0;
    float W33=0,W34=0,W35=0,W36=0;
    float W44=0,W45=0,W46=0;
    float W55=0,W56=0;
    float W66=0;
    float fy1=0,fy2=0,fy3=0,fy4=0,fy5=0,fy6=0;

    float V11=0,V12=0,V13=0,V14=0,V15=0,V16=0;
    float V22=0,V23=0,V24=0,V25=0,V26=0;
    float V33=0,V34=0,V35=0,V36=0;
    float V44=0,V45=0,V46=0;
    float V55=0,V56=0;
    float V66=0;
    float bz1=0,bz2=0,bz3=0,bz4=0,bz5=0,bz6=0;

    const float iv00 = SLI(IN_IV + 0);
    const float iv01 = SLI(IN_IV + 1);
    const float iv10 = SLI(IN_IV + 2);
    const float iv11 = SLI(IN_IV + 3);

    float fc0 = SLI(IN_COEF + 0), fc1 = SLI(IN_COEF + 1), fc2 = SLI(IN_COEF + 2);
    float fr  = SLI(IN_RHS + 0);
    float fp  = 0.f;
    float fs  = SLI(IN_STP + 0);
    float fsn = SLI(IN_STP + 1);

    float bc0 = SLI(IN_COEF + 189), bc1 = SLI(IN_COEF + 190), bc2 = SLI(IN_COEF + 191);
    float brr = SLI(IN_RHS + 63);
    float bs  = 0.f;
    float bp  = SLI(IN_STP + 62);
    float bpp = SLI(IN_STP + 61);

    for (int t = 0; t <= 30; ++t) {
        const int bt = 63 - t;
        const float fc0n = SLI(IN_COEF + 3*(t+1) + 0);
        const float fc1n = SLI(IN_COEF + 3*(t+1) + 1);
        const float fc2n = SLI(IN_COEF + 3*(t+1) + 2);
        const float frn  = SLI(IN_RHS + t + 1);
        const float fsnn = SLI(IN_STP + t + 2);
        const float bc0n = SLI(IN_COEF + 3*(bt-1) + 0);
        const float bc1n = SLI(IN_COEF + 3*(bt-1) + 1);
        const float bc2n = SLI(IN_COEF + 3*(bt-1) + 2);
        const float brn  = SLI(IN_RHS + bt - 1);
        const float bppn = SLI(IN_STP + bt - 3);

        const float mP  = (t >= 1) ? 1.f : 0.f;
        const float rg  = (t < 2) ? 1.f : 0.f;
        const float ivA = (t == 0) ? iv00 : ((t == 1) ? iv10 : 0.f);
        const float ivB = (t == 0) ? iv01 : ((t == 1) ? iv11 : 0.f);
        const float fs2 = fs*fs, fs3 = fs2*fs, fp2 = fp*fp, fp3 = fp2*fp;
        const float fgt = fp + fs;
        const float A0 = fc0*fc0 + rg + 2.f*(1.f + mP);
        const float A1 = fc0*fc1 + fs - fp;
        const float A2 = fc0*fc2 + 0.5f*(fs2 + fp2);
        const float A4 = fs;
        const float A5 = -0.5f*fs2;
        const float B0 = fc1*fc1 + 3.f*(fs2 + fp2) + 2.f;
        const float B1 = fc1*fc2 + 1.5f*(fs3 - fp3);
        const float B2 = -fs;
        const float B3 = -2.f*fs2;
        const float B4 = fs3 + (fs + fsn);
        const float Cv0 = fc2*fc2 + 1.25f*(fs2*fs2 + fp2*fp2) + fgt*fgt*mP;
        const float Cv1 = -0.5f*fs2;
        const float Cv2 = -fs3 - fgt*mP;
        const float rv0 = fc0*fr + ivA;
        const float rv1 = fc1*fr + ivB;
        const float rv2 = fc2*fr;

        const float mSb  = (bt < 63) ? 1.f : 0.f;
        const float mCNb = (bt < 62) ? 1.f : 0.f;
        const float bs2 = bs*bs, bs3 = bs2*bs, bp2 = bp*bp, bp3 = bp2*bp;
        const float bgt = bp + bs;
        const float A0b = bc0*bc0 + 2.f*(mSb + 1.f);
        const float A1b = bc0*bc1 + bs - bp;
        const float A2b = bc0*bc2 + 0.5f*(bs2 + bp2);
        const float B0b = bc1*bc1 + 3.f*(bs2 + bp2) + mCNb + 1.f;
        const float B1b = bc1*bc2 + 1.5f*(bs3 - bp3);
        const float Cv0b = bc2*bc2 + 1.25f*(bs2*bs2 + bp2*bp2) + bgt*bgt*mSb;
        const float A4m = bp;
        const float A5m = -0.5f*bp2;
        const float B2m = -bp;
        const float B3m = -2.f*bp2;
        const float B4m = bp3 + (bp + bs)*mSb;
        const float Cv1m = -0.5f*bp2;
        const float Cv2m = -bp3 - (bpp + bp);
        const float rv0b = bc0*brr;
        const float rv1b = bc1*brr;
        const float rv2b = bc2*brr;

        const int j0 = 3*t, k0 = 3*bt;
        CHOL_COL_G(W, fy, j0 + 0, A0,  A1,  A2,  -2.f, A4,  A5,  0.f, rv0);
        CHOL_COL_G(V, bz, k0 + 2, Cv0b, B1b, A2b, 0.f, B4m, A5m, 0.f, rv2b);
        CHOL_COL_G(W, fy, j0 + 1, B0,  B1,  B2,  B3,  B4,  0.f, -1.f, rv1);
        CHOL_COL_G(V, bz, k0 + 1, B0b, A1b, Cv2m, B3m, A4m, 0.f, -1.f, rv1b);
        CHOL_COL_G(W, fy, j0 + 2, Cv0, Cv1, Cv2, 0.f, 0.f, 0.f, 0.f, rv2);
        CHOL_COL_G(V, bz, k0 + 0, A0b, Cv1m, B2m, -2.f, 0.f, 0.f, 0.f, rv0b);

        fp = fs; fs = fsn; fsn = fsnn;
        fc0 = fc0n; fc1 = fc1n; fc2 = fc2n; fr = frn;
        bs = bp; bp = bpp; bpp = bppn;
        bc0 = bc0n; bc1 = bc1n; bc2 = bc2n; brr = brn;
    }

    MIDDLE_AND_BACKSUB()

#undef SLI
#undef SL
#undef SX
}

// ============================================================================
// K3: transpose x from ws X-region to out. Coalesced both sides.
// ============================================================================
__global__ __launch_bounds__(1024, 1)
void ode_tout(const float* __restrict__ wsX, float* __restrict__ out)
{
    const int g   = blockIdx.x;
    const int tid = threadIdx.x;
    __shared__ float tile[64 * 193];

    for (int idx = tid; idx < NV * 64; idx += 1024) {
        const int j = idx >> 6, l = idx & 63;
        tile[l * 193 + j] = wsX[((size_t)g * X_SLOTS + j) * 64 + l];
    }
    __syncthreads();
    for (int idx = tid; idx < 64 * NV; idx += 1024) {
        const int b = idx / NV, j = idx - b * NV;
        out[(size_t)g * 64 * NV + idx] = tile[b * 193 + j];
    }
}

// ============================================================================
// Fallback (round-1 kernel, known-pass): used only if ws is too small
// ============================================================================
__global__ __launch_bounds__(64, 1)
void ode_banded_solve(const float* __restrict__ coeffs,
                      const float* __restrict__ rhs,
                      const float* __restrict__ iv_rhs,
                      const float* __restrict__ steps,
                      float* __restrict__ out)
{
    const int b    = blockIdx.x;
    const int lane = threadIdx.x;

    __shared__ float band[NV * BW];
    __shared__ float rv[NV];
    __shared__ float stp[NT + 1];

    for (int i = lane; i < NV * BW; i += 64) band[i] = 0.0f;
    if (lane < NT) stp[lane] = steps[b * NT + lane];
    __syncthreads();

    {
        const int st = lane;
        const float c0 = coeffs[b * NV + st * 3 + 0];
        const float c1 = coeffs[b * NV + st * 3 + 1];
        const float c2 = coeffs[b * NV + st * 3 + 2];
        const float r  = rhs[b * NS + st];
        const float reg = (st < 2) ? 1.0f : 0.0f;
        atomicAdd(&band[(3 * st + 0) * BW + 0], c0 * c0 + reg);
        atomicAdd(&band[(3 * st + 1) * BW + 0], c1 * c1 + reg);
        atomicAdd(&band[(3 * st + 2) * BW + 0], c2 * c2);
        atomicAdd(&band[(3 * st + 1) * BW + 1], c1 * c0);
        atomicAdd(&band[(3 * st + 2) * BW + 1], c2 * c1);
        atomicAdd(&band[(3 * st + 2) * BW + 2], c2 * c0);
        float b0 = c0 * r, b1 = c1 * r, b2v = c2 * r;
        if (st < 2) {
            b0 += iv_rhs[b * 4 + st * 2 + 0];
            b1 += iv_rhs[b * 4 + st * 2 + 1];
        }
        rv[3 * st + 0] = b0;
        rv[3 * st + 1] = b1;
        rv[3 * st + 2] = b2v;
    }

    for (int t = lane; t < NC; t += 64) {
        int   cols[4];
        float vals[4];
        int   cnt;
        if (t < 126) {
            const int st = t >> 1, i = t & 1;
            const float s = stp[st];
            if (i == 0) {
                cols[0] = 3 * st + 0; vals[0] = 1.0f;
                cols[1] = 3 * st + 1; vals[1] = s;
                cols[2] = 3 * st + 2; vals[2] = 0.5f * s * s;
                cols[3] = 3 * st + 3; vals[3] = -1.0f;
                cnt = 4;
            } else {
                cols[0] = 3 * st + 1; vals[0] = s;
                cols[1] = 3 * st + 2; vals[1] = s * s;
                cols[2] = 3 * st + 4; vals[2] = -s;
                cnt = 3;
            }
        } else if (t < 188) {
            const int st = t - 126 + 1;
            const float cp = stp[st - 1] + stp[st];
            cols[0] = 3 * st - 2; vals[0] = -1.0f;
            cols[1] = 3 * st + 2; vals[1] = -cp;
            cols[2] = 3 * st + 4; vals[2] = 1.0f;
            cnt = 3;
        } else {
            const int tt = t - 188;
            const int st = tt >> 1, i = tt & 1;
            const float s = stp[st];
            if (i == 0) {
                cols[0] = 3 * st + 0; vals[0] = -1.0f;
                cols[1] = 3 * st + 3; vals[1] = 1.0f;
                cols[2] = 3 * st + 4; vals[2] = -s;
                cols[3] = 3 * st + 5; vals[3] = 0.5f * s * s;
                cnt = 4;
            } else {
                cols[0] = 3 * st + 1; vals[0] = s;
                cols[1] = 3 * st + 4; vals[1] = -s;
                cols[2] = 3 * st + 5; vals[2] = s * s;
                cnt = 3;
            }
        }
        for (int a = 0; a < cnt; ++a)
            for (int b2 = 0; b2 <= a; ++b2)
                atomicAdd(&band[cols[a] * BW + (cols[a] - cols[b2])],
                          vals[a] * vals[b2]);
    }
    __syncthreads();

    int pa = 0, pb = 0;
    {
        int idx = 0;
        for (int aa = 1; aa <= 6; ++aa)
            for (int bb = 1; bb <= aa; ++bb) {
                if (idx == lane) { pa = aa; pb = bb; }
                ++idx;
            }
    }
    const int sk = lane - 20;

    for (int j = 0; j < NV; ++j) {
        const int m = (NV - 1 - j < 6) ? (NV - 1 - j) : 6;
        const float diag = band[j * BW];
        const float d    = sqrtf(diag);
        const float dinv = 1.0f / d;

        const bool doU = (lane < 21) && (pa <= m);
        const bool doS = (lane >= 21) && (lane <= 26) && (sk <= m);
        float ca = 0.0f, cb = 0.0f, cs = 0.0f;
        if (doU) { ca = band[(j + pa) * BW + pa]; cb = band[(j + pb) * BW + pb]; }
        if (doS) { cs = band[(j + sk) * BW + sk]; }
        __syncthreads();

        if (lane == 0) band[j * BW] = d;
        if (doU) band[(j + pa) * BW + (pa - pb)] -= ca * cb * (dinv * dinv);
        if (doS) band[(j + sk) * BW + sk] = cs * dinv;
        __syncthreads();
    }

    for (int j = 0; j < NV; ++j) {
        const int m = (NV - 1 - j < 6) ? (NV - 1 - j) : 6;
        const float yj = rv[j] / band[j * BW];
        const bool doK = (lane >= 1) && (lane <= m);
        float sub = 0.0f, rj = 0.0f;
        if (doK) { sub = band[(j + lane) * BW + lane] * yj; rj = rv[j + lane]; }
        __syncthreads();
        if (lane == 0) rv[j] = yj;
        if (doK) rv[j + lane] = rj - sub;
        __syncthreads();
    }

    for (int j = NV - 1; j >= 0; --j) {
        const int m = (j < 6) ? j : 6;
        const float xj = rv[j] / band[j * BW];
        const bool doK = (lane >= 1) && (lane <= m);
        float sub = 0.0f, rj = 0.0f;
        if (doK) { sub = band[j * BW + lane] * xj; rj = rv[j - lane]; }
        __syncthreads();
        if (lane == 0) rv[j] = xj;
        if (doK) rv[j - lane] = rj - sub;
        __syncthreads();
    }

    for (int i = lane; i < NV; i += 64)
        out[b * NV + i] = rv[i];
}

extern "C" void kernel_launch(void* const* d_in, const int* in_sizes, int n_in,
                              void* d_out, int out_size, void* d_ws, size_t ws_size,
                              hipStream_t stream)
{
    const float* coeffs = (const float*)d_in[0];   // 1024*64*3
    const float* rhs    = (const float*)d_in[1];   // 1024*64
    const float* iv_rhs = (const float*)d_in[2];   // 1024*2*2
    const float* steps  = (const float*)d_in[3];   // 1024*63
    float* out = (float*)d_out;                    // 1024*192

    const size_t needA = (size_t)(IN_SLOTS + BP_SLOTS + L_SLOTS + X_SLOTS) * 64 * NG * sizeof(float); // ~16.8 MB
    const size_t needB = (size_t)(IN_SLOTS + L_SLOTS + X_SLOTS) * 64 * NG * sizeof(float);            // ~8.4 MB

    if (ws_size >= needA) {
        float* wsIn = (float*)d_ws;
        float* wsBP = wsIn + (size_t)IN_SLOTS * 64 * NG;
        float* wsL  = wsBP + (size_t)BP_SLOTS * 64 * NG;
        float* wsX  = wsL  + (size_t)L_SLOTS * 64 * NG;
        ode_tin<<<dim3(NG), dim3(1024), 0, stream>>>(coeffs, rhs, steps, iv_rhs, wsIn, wsBP);
        ode_fused5<<<dim3(2), dim3(512), 0, stream>>>(wsIn, wsBP, wsL, wsX);
        ode_tout<<<dim3(NG), dim3(1024), 0, stream>>>(wsX, out);
    } else if (ws_size >= needB) {
        float* wsIn = (float*)d_ws;
        float* wsL  = wsIn + (size_t)IN_SLOTS * 64 * NG;
        float* wsX  = wsL  + (size_t)L_SLOTS * 64 * NG;
        ode_tin<<<dim3(NG), dim3(1024), 0, stream>>>(coeffs, rhs, steps, iv_rhs, wsIn, (float*)nullptr);
        ode_fused3b<<<dim3(2), dim3(512), 0, stream>>>(wsIn, wsL, wsX);
        ode_tout<<<dim3(NG), dim3(1024), 0, stream>>>(wsX, out);
    } else {
        ode_banded_solve<<<dim3(NB), dim3(64), 0, stream>>>(coeffs, rhs, iv_rhs,
                                                            steps, out);
    }
}

// Round 8
// 49.928 us; speedup vs baseline: 2.5220x; 2.5220x over previous
//
#include <hip/hip_runtime.h>
#include <math.h>

// Problem constants (static config)
#define NB 1024
#define NS 64
#define NT 63
#define NV 192
#define BW 7
#define NC 314

#define NW 32               // fused-kernel waves: 1024 batches x 2 chains / 64 lanes
#define BP_PER_W (31*24)    // 31 iters x 3 cols x 8 slots   (x64 lanes)
#define L_PER_W  (93*8)     // 93 cols x 8 slots             (x64 lanes)
#define XQ_PER_W 96         // 93 used                        (x64 lanes)
#define MID_PER_W 27        // middle 6x6 pre-Schur pieces    (x32 pairs)
#define MX_PER_W  6         // middle x values                (x32 pairs)

// ============================================================================
// K1 (prep): per (wave, iter, pair) compute the 24 fwd pieces (step it) and
// 24 bwd pieces (step 63-it), interleaved even/odd lane as float2. Also the 27
// middle-block pre-Schur values per batch. All formulas verbatim from the
// verified r5/r7 kernels.
// ============================================================================
__global__ __launch_bounds__(1024, 1)
void ode_prep(const float* __restrict__ coeffs,
              const float* __restrict__ rhs,
              const float* __restrict__ steps,
              const float* __restrict__ iv_rhs,
              float* __restrict__ wsBP,
              float* __restrict__ wsMID)
{
    const int w   = blockIdx.x;     // 0..31
    const int tid = threadIdx.x;

    for (int idx = tid; idx < 31 * 32; idx += 1024) {
        const int it = idx >> 5;    // 0..30
        const int pr = idx & 31;
        const int b  = w * 32 + pr;
        const float* cf = coeffs + (size_t)b * 192;
        const float* st = steps  + (size_t)b * 63;
        const float* rh = rhs    + (size_t)b * 64;

        float f[24], gv[24];
        {   // fwd pieces, step t = it  (t <= 30: mS = mCN = 1)
            const int t = it;
            const float c0 = cf[3*t], c1 = cf[3*t+1], c2 = cf[3*t+2];
            const float r  = rh[t];
            const float p  = (t >= 1) ? st[t-1] : 0.f;
            const float s  = st[t];
            const float sn = st[t+1];
            const float mP = (t >= 1) ? 1.f : 0.f;
            const float rg = (t < 2) ? 1.f : 0.f;
            float iv0 = 0.f, iv1 = 0.f;
            if (t < 2) { iv0 = iv_rhs[(size_t)b*4 + t*2]; iv1 = iv_rhs[(size_t)b*4 + t*2 + 1]; }
            const float s2 = s*s, s3 = s2*s, p2 = p*p, p3 = p2*p, gt = p + s;
            f[0]  = c0*c0 + rg + 2.f*(1.f + mP);
            f[1]  = c0*c1 + s - p;
            f[2]  = c0*c2 + 0.5f*(s2 + p2);
            f[3]  = -2.f;
            f[4]  = s;
            f[5]  = -0.5f*s2;
            f[6]  = 0.f;
            f[7]  = c0*r + iv0;
            f[8]  = c1*c1 + 3.f*(s2 + p2) + 2.f;
            f[9]  = c1*c2 + 1.5f*(s3 - p3);
            f[10] = -s;
            f[11] = -2.f*s2;
            f[12] = s3 + (s + sn);
            f[13] = 0.f;
            f[14] = -1.f;
            f[15] = c1*r + iv1;
            f[16] = c2*c2 + 1.25f*(s2*s2 + p2*p2) + gt*gt*mP;
            f[17] = -0.5f*s2;
            f[18] = -s3 - gt*mP;
            f[19] = 0.f; f[20] = 0.f; f[21] = 0.f; f[22] = 0.f;
            f[23] = c2*r;
        }
        {   // bwd pieces, step t = 63 - it  (t in 33..63)
            const int t = 63 - it;
            const float c0 = cf[3*t], c1 = cf[3*t+1], c2 = cf[3*t+2];
            const float r  = rh[t];
            const float s  = (t < 63) ? st[t] : 0.f;
            const float p  = st[t-1];
            const float pp = st[t-2];
            const float mSb  = (t < 63) ? 1.f : 0.f;
            const float mCNb = (t < 62) ? 1.f : 0.f;
            const float s2 = s*s, s3 = s2*s, p2 = p*p, p3 = p2*p, gt = p + s;
            gv[0]  = c2*c2 + 1.25f*(s2*s2 + p2*p2) + gt*gt*mSb;   // Cv0b
            gv[1]  = c1*c2 + 1.5f*(s3 - p3);                      // B1b
            gv[2]  = c0*c2 + 0.5f*(s2 + p2);                      // A2b
            gv[3]  = 0.f;
            gv[4]  = p3 + (p + s)*mSb;                            // B4m
            gv[5]  = -0.5f*p2;                                    // A5m
            gv[6]  = 0.f;
            gv[7]  = c2*r;                                        // rv2b
            gv[8]  = c1*c1 + 3.f*(s2 + p2) + mCNb + 1.f;          // B0b
            gv[9]  = c0*c1 + s - p;                               // A1b
            gv[10] = -p3 - (pp + p);                              // Cv2m
            gv[11] = -2.f*p2;                                     // B3m
            gv[12] = p;                                           // A4m
            gv[13] = 0.f;
            gv[14] = -1.f;
            gv[15] = c1*r;                                        // rv1b
            gv[16] = c0*c0 + 2.f*(mSb + 1.f);                     // A0b
            gv[17] = -0.5f*p2;                                    // Cv1m
            gv[18] = -p;                                          // B2m
            gv[19] = -2.f;
            gv[20] = 0.f; gv[21] = 0.f; gv[22] = 0.f;
            gv[23] = c0*r;                                        // rv0b
        }
        float2* dst = (float2*)wsBP + ((size_t)w * BP_PER_W + (size_t)it * 24) * 32 + pr;
        #pragma unroll
        for (int k = 0; k < 24; ++k) dst[(size_t)k * 32] = make_float2(f[k], gv[k]);
    }

    // ---- middle-block pre-Schur values (27 per batch) ----
    if (tid < 32) {
        const int pr = tid;
        const int b  = w * 32 + pr;
        const float* cf = coeffs + (size_t)b * 192;
        const float* st = steps  + (size_t)b * 63;
        const float* rh = rhs    + (size_t)b * 64;
        const float pA = st[30], sA = st[31], snA = st[32];
        const float sB = st[32], pB = sA;
        const float c0A = cf[93], c1A = cf[94], c2A = cf[95];
        const float c0B = cf[96], c1B = cf[97], c2B = cf[98];
        const float rA = rh[31], rB = rh[32];
        const float sA2 = sA*sA, sA3 = sA2*sA, pA2 = pA*pA, pA3 = pA2*pA;
        const float sB2 = sB*sB, sB3 = sB2*sB, pB2 = pB*pB, pB3 = pB2*pB;
        float m[27];
        m[0]  = c0A*c0A + 4.f;
        m[1]  = c0A*c1A + sA - pA;
        m[2]  = c0A*c2A + 0.5f*(sA2 + pA2);
        m[3]  = -2.f;
        m[4]  = sA;
        m[5]  = -0.5f*sA2;
        m[6]  = c1A*c1A + 3.f*(sA2 + pA2) + 2.f;
        m[7]  = c1A*c2A + 1.5f*(sA3 - pA3);
        m[8]  = -sA;
        m[9]  = -2.f*sA2;
        m[10] = sA3 + (sA + snA);
        m[11] = c2A*c2A + 1.25f*(sA2*sA2 + pA2*pA2) + (pA + sA)*(pA + sA);
        m[12] = -0.5f*sA2;
        m[13] = -sA3 - (pA + sA);
        m[14] = 0.f;
        m[15] = c0B*c0B + 4.f;
        m[16] = c0B*c1B + sB - pB;
        m[17] = c0B*c2B + 0.5f*(sB2 + pB2);
        m[18] = c1B*c1B + 3.f*(sB2 + pB2) + 2.f;
        m[19] = c1B*c2B + 1.5f*(sB3 - pB3);
        m[20] = c2B*c2B + 1.25f*(sB2*sB2 + pB2*pB2) + (pB + sB)*(pB + sB);
        m[21] = c0A*rA; m[22] = c1A*rA; m[23] = c2A*rA;
        m[24] = c0B*rB; m[25] = c1B*rB; m[26] = c2B*rB;
        #pragma unroll
        for (int k = 0; k < 27; ++k)
            wsMID[(size_t)w * MID_PER_W * 32 + (size_t)k * 32 + pr] = m[k];
    }
}

// ============================================================================
// K2 (fused6): lane-paired twisted factorization. 32 blocks x 64 threads.
// lane 2k   = fwd chain of batch w*32+k  (cols j = q)
// lane 2k+1 = bwd chain of same batch    (cols j = 191-q)
// q = 3*it+col is the production index -> ALL main-loop addresses are
// wave-uniform and coalesced. Middle 6x6 on even lanes after a shfl_xor
// window exchange. Uniform back-substitution q=92..0 for both chains.
// ============================================================================
__global__ __launch_bounds__(64, 1)
void ode_fused6(const float* __restrict__ wsBP,
                const float* __restrict__ wsMID,
                float* __restrict__ wsL,
                float* __restrict__ wsXq,
                float* __restrict__ wsMX)
{
    const int w     = blockIdx.x;
    const int l     = threadIdx.x;
    const int pair  = l >> 1;
    const int chain = l & 1;

    const float* __restrict__ bp = wsBP + (size_t)w * BP_PER_W * 64 + l;
    float* __restrict__ ln = wsL  + (size_t)w * L_PER_W * 64 + l;
    float* __restrict__ xq = wsXq + (size_t)w * XQ_PER_W * 64 + l;

#define SBP(it, k) bp[(size_t)((it) * 24 + (k)) * 64]
#define SL(i)      ln[(size_t)(i) * 64]
#define SXQ(q)     xq[(size_t)(q) * 64]

    float W11=0,W12=0,W13=0,W14=0,W15=0,W16=0;
    float W22=0,W23=0,W24=0,W25=0,W26=0;
    float W33=0,W34=0,W35=0,W36=0;
    float W44=0,W45=0,W46=0;
    float W55=0,W56=0;
    float W66=0;
    float y1=0,y2=0,y3=0,y4=0,y5=0,y6=0;

#define CHOL_COL(q, b0, b1, b2, b3, b4, b5, b6, rvv)                           \
    {                                                                          \
        const float t0_ = (b0) - (W11*W11 + W22*W22 + W33*W33 +                \
                                  W44*W44 + W55*W55 + W66*W66);                \
        const float di_ = rsqrtf(t0_);                                         \
        const float u1_ = (b1) - (W11*W12 + W22*W23 + W33*W34 +                \
                                  W44*W45 + W55*W56);                          \
        const float u2_ = (b2) - (W11*W13 + W22*W24 + W33*W35 + W44*W46);      \
        const float u3_ = (b3) - (W11*W14 + W22*W25 + W33*W36);                \
        const float u4_ = (b4) - (W11*W15 + W22*W26);                          \
        const float u5_ = (b5) - (W11*W16);                                    \
        const float u6_ = (b6);                                                \
        const float yj_ = ((rvv) - (W11*y1 + W22*y2 + W33*y3 +                 \
                                    W44*y4 + W55*y5 + W66*y6)) * di_;          \
        const float n1_ = u1_*di_, n2_ = u2_*di_, n3_ = u3_*di_;               \
        const float n4_ = u4_*di_, n5_ = u5_*di_, n6_ = u6_*di_;               \
        SL((q)*8 + 0) = di_; SL((q)*8 + 1) = n1_; SL((q)*8 + 2) = n2_;         \
        SL((q)*8 + 3) = n3_; SL((q)*8 + 4) = n4_; SL((q)*8 + 5) = n5_;         \
        SL((q)*8 + 6) = n6_; SL((q)*8 + 7) = yj_;                              \
        W66 = W56;                                                             \
        W55 = W45; W56 = W46;                                                  \
        W44 = W34; W45 = W35; W46 = W36;                                       \
        W33 = W23; W34 = W24; W35 = W25; W36 = W26;                            \
        W22 = W12; W23 = W13; W24 = W14; W25 = W15; W26 = W16;                 \
        W11 = n1_; W12 = n2_; W13 = n3_; W14 = n4_; W15 = n5_; W16 = n6_;      \
        y6 = y5; y5 = y4; y4 = y3; y3 = y2; y2 = y1; y1 = yj_;                 \
    }

    // preload iter 0 pieces
    float C0  = SBP(0,0),  C1  = SBP(0,1),  C2  = SBP(0,2),  C3  = SBP(0,3);
    float C4  = SBP(0,4),  C5  = SBP(0,5),  C6  = SBP(0,6),  C7  = SBP(0,7);
    float C8  = SBP(0,8),  C9  = SBP(0,9),  C10 = SBP(0,10), C11 = SBP(0,11);
    float C12 = SBP(0,12), C13 = SBP(0,13), C14 = SBP(0,14), C15 = SBP(0,15);
    float C16 = SBP(0,16), C17 = SBP(0,17), C18 = SBP(0,18), C19 = SBP(0,19);
    float C20 = SBP(0,20), C21 = SBP(0,21), C22 = SBP(0,22), C23 = SBP(0,23);

    for (int it = 0; it <= 30; ++it) {
        float N0=0,N1=0,N2=0,N3=0,N4=0,N5=0,N6=0,N7=0,N8=0,N9=0,N10=0,N11=0;
        float N12=0,N13=0,N14=0,N15=0,N16=0,N17=0,N18=0,N19=0,N20=0,N21=0,N22=0,N23=0;
        if (it < 30) {
            N0  = SBP(it+1,0);  N1  = SBP(it+1,1);  N2  = SBP(it+1,2);  N3  = SBP(it+1,3);
            N4  = SBP(it+1,4);  N5  = SBP(it+1,5);  N6  = SBP(it+1,6);  N7  = SBP(it+1,7);
            N8  = SBP(it+1,8);  N9  = SBP(it+1,9);  N10 = SBP(it+1,10); N11 = SBP(it+1,11);
            N12 = SBP(it+1,12); N13 = SBP(it+1,13); N14 = SBP(it+1,14); N15 = SBP(it+1,15);
            N16 = SBP(it+1,16); N17 = SBP(it+1,17); N18 = SBP(it+1,18); N19 = SBP(it+1,19);
            N20 = SBP(it+1,20); N21 = SBP(it+1,21); N22 = SBP(it+1,22); N23 = SBP(it+1,23);
        }
        const int q0 = 3 * it;
        CHOL_COL(q0 + 0, C0,  C1,  C2,  C3,  C4,  C5,  C6,  C7);
        CHOL_COL(q0 + 1, C8,  C9,  C10, C11, C12, C13, C14, C15);
        CHOL_COL(q0 + 2, C16, C17, C18, C19, C20, C21, C22, C23);
        C0=N0; C1=N1; C2=N2; C3=N3; C4=N4; C5=N5; C6=N6; C7=N7;
        C8=N8; C9=N9; C10=N10; C11=N11; C12=N12; C13=N13; C14=N14; C15=N15;
        C16=N16; C17=N17; C18=N18; C19=N19; C20=N20; C21=N21; C22=N22; C23=N23;
    }

    // ---- window exchange between lane pairs (all lanes participate) ----
    const float R11=__shfl_xor(W11,1), R12=__shfl_xor(W12,1), R13=__shfl_xor(W13,1);
    const float R14=__shfl_xor(W14,1), R15=__shfl_xor(W15,1), R16=__shfl_xor(W16,1);
    const float R22=__shfl_xor(W22,1), R23=__shfl_xor(W23,1), R24=__shfl_xor(W24,1);
    const float R25=__shfl_xor(W25,1), R26=__shfl_xor(W26,1);
    const float R33=__shfl_xor(W33,1), R34=__shfl_xor(W34,1), R35=__shfl_xor(W35,1);
    const float R36=__shfl_xor(W36,1);
    const float R44=__shfl_xor(W44,1), R45=__shfl_xor(W45,1), R46=__shfl_xor(W46,1);
    const float R55=__shfl_xor(W55,1), R56=__shfl_xor(W56,1);
    const float R66=__shfl_xor(W66,1);
    const float r1=__shfl_xor(y1,1), r2=__shfl_xor(y2,1), r3=__shfl_xor(y3,1);
    const float r4=__shfl_xor(y4,1), r5=__shfl_xor(y5,1), r6=__shfl_xor(y6,1);

    float xm0=0, xm1=0, xm2=0, xm3=0, xm4=0, xm5=0;
    if (chain == 0) {
        // ---- middle 6x6 (even lanes): W = own fwd window, V = received bwd ----
        const float* __restrict__ md = wsMID + (size_t)w * MID_PER_W * 32 + pair;
        float S00 = md[0*32],  S10 = md[1*32],  S20 = md[2*32];
        float S30 = md[3*32],  S40 = md[4*32],  S50 = md[5*32];
        float S11 = md[6*32],  S21 = md[7*32],  S31 = md[8*32];
        float S41 = md[9*32],  S51 = md[10*32], S22 = md[11*32];
        float S32 = md[12*32], S42 = md[13*32], S52 = md[14*32];
        float S33 = md[15*32], S43 = md[16*32], S53 = md[17*32];
        float S44 = md[18*32], S54 = md[19*32], S55 = md[20*32];
        float fm0 = md[21*32], fm1 = md[22*32], fm2 = md[23*32];
        float fm3 = md[24*32], fm4 = md[25*32], fm5 = md[26*32];

        S00 -= W11*W11 + W22*W22 + W33*W33 + W44*W44 + W55*W55 + W66*W66;
        S10 -= W12*W11 + W23*W22 + W34*W33 + W45*W44 + W56*W55;
        S11 -= W12*W12 + W23*W23 + W34*W34 + W45*W45 + W56*W56;
        S20 -= W13*W11 + W24*W22 + W35*W33 + W46*W44;
        S21 -= W13*W12 + W24*W23 + W35*W34 + W46*W45;
        S22 -= W13*W13 + W24*W24 + W35*W35 + W46*W46;
        S30 -= W14*W11 + W25*W22 + W36*W33;
        S31 -= W14*W12 + W25*W23 + W36*W34;
        S32 -= W14*W13 + W25*W24 + W36*W35;
        S33 -= W14*W14 + W25*W25 + W36*W36;
        S40 -= W15*W11 + W26*W22;
        S41 -= W15*W12 + W26*W23;
        S42 -= W15*W13 + W26*W24;
        S43 -= W15*W14 + W26*W25;
        S44 -= W15*W15 + W26*W26;
        S50 -= W16*W11;
        S51 -= W16*W12;
        S52 -= W16*W13;
        S53 -= W16*W14;
        S54 -= W16*W15;
        S55 -= W16*W16;

        S00 -= R16*R16;
        S10 -= R15*R16;
        S11 -= R15*R15 + R26*R26;
        S20 -= R14*R16;
        S21 -= R14*R15 + R25*R26;
        S22 -= R14*R14 + R25*R25 + R36*R36;
        S30 -= R13*R16;
        S31 -= R13*R15 + R24*R26;
        S32 -= R13*R14 + R24*R25 + R35*R36;
        S33 -= R13*R13 + R24*R24 + R35*R35 + R46*R46;
        S40 -= R12*R16;
        S41 -= R12*R15 + R23*R26;
        S42 -= R12*R14 + R23*R25 + R34*R36;
        S43 -= R12*R13 + R23*R24 + R34*R35 + R45*R46;
        S44 -= R12*R12 + R23*R23 + R34*R34 + R45*R45 + R56*R56;
        S50 -= R11*R16;
        S51 -= R11*R15 + R22*R26;
        S52 -= R11*R14 + R22*R25 + R33*R36;
        S53 -= R11*R13 + R22*R24 + R33*R35 + R44*R46;
        S54 -= R11*R12 + R22*R23 + R33*R34 + R44*R45 + R55*R56;
        S55 -= R11*R11 + R22*R22 + R33*R33 + R44*R44 + R55*R55 + R66*R66;

        fm0 -= (W11*y1 + W22*y2 + W33*y3 + W44*y4 + W55*y5 + W66*y6) + (R16*r1);
        fm1 -= (W12*y1 + W23*y2 + W34*y3 + W45*y4 + W56*y5) + (R15*r1 + R26*r2);
        fm2 -= (W13*y1 + W24*y2 + W35*y3 + W46*y4) + (R14*r1 + R25*r2 + R36*r3);
        fm3 -= (W14*y1 + W25*y2 + W36*y3) + (R13*r1 + R24*r2 + R35*r3 + R46*r4);
        fm4 -= (W15*y1 + W26*y2) + (R12*r1 + R23*r2 + R34*r3 + R45*r4 + R56*r5);
        fm5 -= (W16*y1) + (R11*r1 + R22*r2 + R33*r3 + R44*r4 + R55*r5 + R66*r6);

        const float md0 = rsqrtf(S00);
        const float M10 = S10*md0, M20 = S20*md0, M30 = S30*md0,
                    M40 = S40*md0, M50 = S50*md0;
        const float zm0 = fm0*md0;
        const float md1 = rsqrtf(S11 - M10*M10);
        const float M21 = (S21 - M20*M10)*md1;
        const float M31 = (S31 - M30*M10)*md1;
        const float M41 = (S41 - M40*M10)*md1;
        const float M51 = (S51 - M50*M10)*md1;
        const float zm1 = (fm1 - M10*zm0)*md1;
        const float md2 = rsqrtf(S22 - M20*M20 - M21*M21);
        const float M32 = (S32 - M30*M20 - M31*M21)*md2;
        const float M42 = (S42 - M40*M20 - M41*M21)*md2;
        const float M52 = (S52 - M50*M20 - M51*M21)*md2;
        const float zm2 = (fm2 - M20*zm0 - M21*zm1)*md2;
        const float md3 = rsqrtf(S33 - M30*M30 - M31*M31 - M32*M32);
        const float M43 = (S43 - M40*M30 - M41*M31 - M42*M32)*md3;
        const float M53 = (S53 - M50*M30 - M51*M31 - M52*M32)*md3;
        const float zm3 = (fm3 - M30*zm0 - M31*zm1 - M32*zm2)*md3;
        const float md4 = rsqrtf(S44 - M40*M40 - M41*M41 - M42*M42 - M43*M43);
        const float M54 = (S54 - M50*M40 - M51*M41 - M52*M42 - M53*M43)*md4;
        const float zm4 = (fm4 - M40*zm0 - M41*zm1 - M42*zm2 - M43*zm3)*md4;
        const float md5 = rsqrtf(S55 - M50*M50 - M51*M51 - M52*M52 - M53*M53 - M54*M54);
        const float zm5 = (fm5 - M50*zm0 - M51*zm1 - M52*zm2 - M53*zm3 - M54*zm4)*md5;

        xm5 = zm5*md5;
        xm4 = (zm4 - M54*xm5)*md4;
        xm3 = (zm3 - M43*xm4 - M53*xm5)*md3;
        xm2 = (zm2 - M32*xm3 - M42*xm4 - M52*xm5)*md2;
        xm1 = (zm1 - M21*xm2 - M31*xm3 - M41*xm4 - M51*xm5)*md1;
        xm0 = (zm0 - M10*xm1 - M20*xm2 - M30*xm3 - M40*xm4 - M50*xm5)*md0;

        float* __restrict__ mx = wsMX + (size_t)w * MX_PER_W * 32 + pair;
        mx[0*32] = xm0; mx[1*32] = xm1; mx[2*32] = xm2;
        mx[3*32] = xm3; mx[4*32] = xm4; mx[5*32] = xm5;
    }

    // distribute x_mid to odd lanes
    const float g0 = __shfl_xor(xm0, 1), g1 = __shfl_xor(xm1, 1);
    const float g2 = __shfl_xor(xm2, 1), g3 = __shfl_xor(xm3, 1);
    const float g4 = __shfl_xor(xm4, 1), g5 = __shfl_xor(xm5, 1);

    // prev-x init: fwd lane x[93..98]=xm0..5 ; bwd lane x[98..93]=xm5..0
    float x1 = chain ? g5 : xm0;
    float x2 = chain ? g4 : xm1;
    float x3 = chain ? g3 : xm2;
    float x4 = chain ? g2 : xm3;
    float x5 = chain ? g1 : xm4;
    float x6 = chain ? g0 : xm5;

    // ---- uniform back-substitution q = 92..0 (both chains) ----
#define DECL8(P) float P##d = 0, P##1 = 0, P##2 = 0, P##3 = 0,                 \
                       P##4 = 0, P##5 = 0, P##6 = 0, P##y = 0;
#define LOAD8(P, q) { const size_t o8 = (size_t)(q)*8;                         \
        P##d = SL(o8 + 0); P##1 = SL(o8 + 1); P##2 = SL(o8 + 2);               \
        P##3 = SL(o8 + 3); P##4 = SL(o8 + 4); P##5 = SL(o8 + 5);               \
        P##6 = SL(o8 + 6); P##y = SL(o8 + 7); }
#define BSUB(P, q) {                                                           \
        const float rest = (P##6*x6 + P##5*x5) + (P##4*x4 + P##3*x3) + P##2*x2;\
        const float xr = ((P##y - rest) - P##1*x1) * P##d;                     \
        SXQ(q) = xr;                                                           \
        x6 = x5; x5 = x4; x4 = x3; x3 = x2; x2 = x1; x1 = xr; }

    DECL8(PA) DECL8(PB) DECL8(PC)
    DECL8(QA) DECL8(QB) DECL8(QC)
    LOAD8(PC, 92) LOAD8(PB, 91) LOAD8(PA, 90)

    for (int it = 0; it < 32; it += 2) {
        if (it <= 29) { const int st = 29 - it;
            LOAD8(QC, 3*st + 2) LOAD8(QB, 3*st + 1) LOAD8(QA, 3*st) }
        if (it <= 30) { const int st = 30 - it;
            BSUB(PC, 3*st + 2) BSUB(PB, 3*st + 1) BSUB(PA, 3*st) }
        if (it + 1 <= 29) { const int st = 28 - it;
            LOAD8(PC, 3*st + 2) LOAD8(PB, 3*st + 1) LOAD8(PA, 3*st) }
        if (it + 1 <= 30) { const int st = 29 - it;
            BSUB(QC, 3*st + 2) BSUB(QB, 3*st + 1) BSUB(QA, 3*st) }
    }

#undef SBP
#undef SL
#undef SXQ
#undef CHOL_COL
#undef DECL8
#undef LOAD8
#undef BSUB
}

// ============================================================================
// K3 (xout): map lane-paired q-indexed x back to out[b][j]. Coalesced out.
// j < 93   -> even lane, q = j
// 93..98   -> middle values
// j > 98   -> odd lane, q = 191 - j
// ============================================================================
__global__ __launch_bounds__(1024, 1)
void ode_xout(const float* __restrict__ wsXq,
              const float* __restrict__ wsMX,
              float* __restrict__ out)
{
    const int g   = blockIdx.x;     // 0..15 (64 batches = waves 2g, 2g+1)
    const int tid = threadIdx.x;
    __shared__ float xl[2][93][64];
    __shared__ float mx[2][6][32];

    for (int idx = tid; idx < 2 * 93 * 64; idx += 1024) {
        const int wl = idx / (93 * 64);
        const int rest = idx - wl * 93 * 64;
        const int q = rest >> 6, l = rest & 63;
        xl[wl][q][l] = wsXq[(size_t)(2 * g + wl) * XQ_PER_W * 64 + (size_t)q * 64 + l];
    }
    for (int idx = tid; idx < 2 * 6 * 32; idx += 1024) {
        const int wl = idx / 192;
        const int rest = idx - wl * 192;
        const int k = rest >> 5, pr = rest & 31;
        mx[wl][k][pr] = wsMX[(size_t)(2 * g + wl) * MX_PER_W * 32 + (size_t)k * 32 + pr];
    }
    __syncthreads();

    for (int idx = tid; idx < 64 * 192; idx += 1024) {
        const int bl = idx / 192;
        const int j  = idx - bl * 192;
        const int wl = bl >> 5;
        const int pr = bl & 31;
        float v;
        if (j < 93)      v = xl[wl][j][2 * pr];
        else if (j > 98) v = xl[wl][191 - j][2 * pr + 1];
        else             v = mx[wl][j - 93][pr];
        out[(size_t)g * 64 * 192 + idx] = v;
    }
}

// ============================================================================
// Fallback (round-1 kernel, known-pass): used only if ws is too small
// ============================================================================
__global__ __launch_bounds__(64, 1)
void ode_banded_solve(const float* __restrict__ coeffs,
                      const float* __restrict__ rhs,
                      const float* __restrict__ iv_rhs,
                      const float* __restrict__ steps,
                      float* __restrict__ out)
{
    const int b    = blockIdx.x;
    const int lane = threadIdx.x;

    __shared__ float band[NV * BW];
    __shared__ float rv[NV];
    __shared__ float stp[NT + 1];

    for (int i = lane; i < NV * BW; i += 64) band[i] = 0.0f;
    if (lane < NT) stp[lane] = steps[b * NT + lane];
    __syncthreads();

    {
        const int st = lane;
        const float c0 = coeffs[b * NV + st * 3 + 0];
        const float c1 = coeffs[b * NV + st * 3 + 1];
        const float c2 = coeffs[b * NV + st * 3 + 2];
        const float r  = rhs[b * NS + st];
        const float reg = (st < 2) ? 1.0f : 0.0f;
        atomicAdd(&band[(3 * st + 0) * BW + 0], c0 * c0 + reg);
        atomicAdd(&band[(3 * st + 1) * BW + 0], c1 * c1 + reg);
        atomicAdd(&band[(3 * st + 2) * BW + 0], c2 * c2);
        atomicAdd(&band[(3 * st + 1) * BW + 1], c1 * c0);
        atomicAdd(&band[(3 * st + 2) * BW + 1], c2 * c1);
        atomicAdd(&band[(3 * st + 2) * BW + 2], c2 * c0);
        float b0 = c0 * r, b1 = c1 * r, b2v = c2 * r;
        if (st < 2) {
            b0 += iv_rhs[b * 4 + st * 2 + 0];
            b1 += iv_rhs[b * 4 + st * 2 + 1];
        }
        rv[3 * st + 0] = b0;
        rv[3 * st + 1] = b1;
        rv[3 * st + 2] = b2v;
    }

    for (int t = lane; t < NC; t += 64) {
        int   cols[4];
        float vals[4];
        int   cnt;
        if (t < 126) {
            const int st = t >> 1, i = t & 1;
            const float s = stp[st];
            if (i == 0) {
                cols[0] = 3 * st + 0; vals[0] = 1.0f;
                cols[1] = 3 * st + 1; vals[1] = s;
                cols[2] = 3 * st + 2; vals[2] = 0.5f * s * s;
                cols[3] = 3 * st + 3; vals[3] = -1.0f;
                cnt = 4;
            } else {
                cols[0] = 3 * st + 1; vals[0] = s;
                cols[1] = 3 * st + 2; vals[1] = s * s;
                cols[2] = 3 * st + 4; vals[2] = -s;
                cnt = 3;
            }
        } else if (t < 188) {
            const int st = t - 126 + 1;
            const float cp = stp[st - 1] + stp[st];
            cols[0] = 3 * st - 2; vals[0] = -1.0f;
            cols[1] = 3 * st + 2; vals[1] = -cp;
            cols[2] = 3 * st + 4; vals[2] = 1.0f;
            cnt = 3;
        } else {
            const int tt = t - 188;
            const int st = tt >> 1, i = tt & 1;
            const float s = stp[st];
            if (i == 0) {
                cols[0] = 3 * st + 0; vals[0] = -1.0f;
                cols[1] = 3 * st + 3; vals[1] = 1.0f;
                cols[2] = 3 * st + 4; vals[2] = -s;
                cols[3] = 3 * st + 5; vals[3] = 0.5f * s * s;
                cnt = 4;
            } else {
                cols[0] = 3 * st + 1; vals[0] = s;
                cols[1] = 3 * st + 4; vals[1] = -s;
                cols[2] = 3 * st + 5; vals[2] = s * s;
                cnt = 3;
            }
        }
        for (int a = 0; a < cnt; ++a)
            for (int b2 = 0; b2 <= a; ++b2)
                atomicAdd(&band[cols[a] * BW + (cols[a] - cols[b2])],
                          vals[a] * vals[b2]);
    }
    __syncthreads();

    int pa = 0, pb = 0;
    {
        int idx = 0;
        for (int aa = 1; aa <= 6; ++aa)
            for (int bb = 1; bb <= aa; ++bb) {
                if (idx == lane) { pa = aa; pb = bb; }
                ++idx;
            }
    }
    const int sk = lane - 20;

    for (int j = 0; j < NV; ++j) {
        const int m = (NV - 1 - j < 6) ? (NV - 1 - j) : 6;
        const float diag = band[j * BW];
        const float d    = sqrtf(diag);
        const float dinv = 1.0f / d;

        const bool doU = (lane < 21) && (pa <= m);
        const bool doS = (lane >= 21) && (lane <= 26) && (sk <= m);
        float ca = 0.0f, cb = 0.0f, cs = 0.0f;
        if (doU) { ca = band[(j + pa) * BW + pa]; cb = band[(j + pb) * BW + pb]; }
        if (doS) { cs = band[(j + sk) * BW + sk]; }
        __syncthreads();

        if (lane == 0) band[j * BW] = d;
        if (doU) band[(j + pa) * BW + (pa - pb)] -= ca * cb * (dinv * dinv);
        if (doS) band[(j + sk) * BW + sk] = cs * dinv;
        __syncthreads();
    }

    for (int j = 0; j < NV; ++j) {
        const int m = (NV - 1 - j < 6) ? (NV - 1 - j) : 6;
        const float yj = rv[j] / band[j * BW];
        const bool doK = (lane >= 1) && (lane <= m);
        float sub = 0.0f, rj = 0.0f;
        if (doK) { sub = band[(j + lane) * BW + lane] * yj; rj = rv[j + lane]; }
        __syncthreads();
        if (lane == 0) rv[j] = yj;
        if (doK) rv[j + lane] = rj - sub;
        __syncthreads();
    }

    for (int j = NV - 1; j >= 0; --j) {
        const int m = (j < 6) ? j : 6;
        const float xj = rv[j] / band[j * BW];
        const bool doK = (lane >= 1) && (lane <= m);
        float sub = 0.0f, rj = 0.0f;
        if (doK) { sub = band[j * BW + lane] * xj; rj = rv[j - lane]; }
        __syncthreads();
        if (lane == 0) rv[j] = xj;
        if (doK) rv[j - lane] = rj - sub;
        __syncthreads();
    }

    for (int i = lane; i < NV; i += 64)
        out[b * NV + i] = rv[i];
}

extern "C" void kernel_launch(void* const* d_in, const int* in_sizes, int n_in,
                              void* d_out, int out_size, void* d_ws, size_t ws_size,
                              hipStream_t stream)
{
    const float* coeffs = (const float*)d_in[0];   // 1024*64*3
    const float* rhs    = (const float*)d_in[1];   // 1024*64
    const float* iv_rhs = (const float*)d_in[2];   // 1024*2*2
    const float* steps  = (const float*)d_in[3];   // 1024*63
    float* out = (float*)d_out;                    // 1024*192

    const size_t BPf  = (size_t)NW * BP_PER_W * 64;
    const size_t MIDf = (size_t)NW * MID_PER_W * 32;
    const size_t Lf   = (size_t)NW * L_PER_W * 64;
    const size_t XQf  = (size_t)NW * XQ_PER_W * 64;
    const size_t MXf  = (size_t)NW * MX_PER_W * 32;
    const size_t need = (BPf + MIDf + Lf + XQf + MXf) * sizeof(float);   // ~13.1 MB

    if (ws_size >= need) {
        float* wsBP  = (float*)d_ws;
        float* wsMID = wsBP  + BPf;
        float* wsL   = wsMID + MIDf;
        float* wsXq  = wsL   + Lf;
        float* wsMX  = wsXq  + XQf;
        ode_prep<<<dim3(NW), dim3(1024), 0, stream>>>(coeffs, rhs, steps, iv_rhs,
                                                      wsBP, wsMID);
        ode_fused6<<<dim3(NW), dim3(64), 0, stream>>>(wsBP, wsMID, wsL, wsXq, wsMX);
        ode_xout<<<dim3(16), dim3(1024), 0, stream>>>(wsXq, wsMX, out);
    } else {
        ode_banded_solve<<<dim3(NB), dim3(64), 0, stream>>>(coeffs, rhs, iv_rhs,
                                                            steps, out);
    }
}

// Round 9
// 49.161 us; speedup vs baseline: 2.5614x; 1.0156x over previous
//
#include <hip/hip_runtime.h>
#include <math.h>

// Problem constants (static config)
#define NB 1024
#define NS 64
#define NT 63
#define NV 192
#define BW 7
#define NC 314

#define NW 32               // fused-kernel waves: 1024 batches x 2 chains / 64 lanes
#define BP_PER_W (31*16)    // 31 iters x 16 slots (x64 lanes)
#define L_PER_W  (93*8)     // 93 cols x 8 slots   (x64 lanes)
#define XQ_PER_W 96         // 93 used             (x64 lanes)
#define MID_PER_W 27        // middle 6x6 pre-Schur pieces (x32 pairs)
#define MX_PER_W  6         // middle x values             (x32 pairs)

// ============================================================================
// K1 (prep2): LDS-staged, fully coalesced. Block w handles batches w*32..+31.
// Stage coeffs/steps/rhs/iv to LDS (padded, conflict-free), then compute the
// 16 fwd pieces (step it) and 16 bwd pieces (step 63-it) per (it,pair),
// written interleaved even/odd lane as float2. Constant slots removed
// (handled as registers in K2). Formulas verbatim from the verified r8 prep.
// ============================================================================
__global__ __launch_bounds__(1024, 1)
void ode_prep2(const float* __restrict__ coeffs,
               const float* __restrict__ rhs,
               const float* __restrict__ steps,
               const float* __restrict__ iv_rhs,
               float* __restrict__ wsBP,
               float* __restrict__ wsMID)
{
    const int w   = blockIdx.x;     // 0..31
    const int tid = threadIdx.x;

    __shared__ float cf[32 * 193];  // [pr][0..191], stride 193 (bank-free)
    __shared__ float sl[32 * 65];   // steps [pr][0..62]
    __shared__ float rl[32 * 65];   // rhs   [pr][0..63]
    __shared__ float il[128];       // iv    [pr][0..3]

    for (int idx = tid; idx < 32 * 192; idx += 1024) {
        const int b = idx / 192, j = idx - 192 * b;
        cf[b * 193 + j] = coeffs[(size_t)w * 6144 + idx];
    }
    for (int idx = tid; idx < 32 * 63; idx += 1024) {
        const int b = idx / 63, j = idx - 63 * b;
        sl[b * 65 + j] = steps[(size_t)w * 2016 + idx];
    }
    for (int idx = tid; idx < 32 * 64; idx += 1024) {
        const int b = idx >> 6, j = idx & 63;
        rl[b * 65 + j] = rhs[(size_t)w * 2048 + idx];
    }
    if (tid < 128) il[tid] = iv_rhs[(size_t)w * 128 + tid];
    __syncthreads();

    for (int idx = tid; idx < 31 * 32; idx += 1024) {
        const int it = idx >> 5;    // 0..30
        const int pr = idx & 31;
        const float* cfp = cf + pr * 193;
        const float* slp = sl + pr * 65;
        const float* rlp = rl + pr * 65;

        float F[16], G[16];
        {   // fwd pieces, step t = it  (t <= 30: mS = mCN = 1)
            const int t = it;
            const float c0 = cfp[3*t], c1 = cfp[3*t+1], c2 = cfp[3*t+2];
            const float r  = rlp[t];
            const float p  = (t >= 1) ? slp[t-1] : 0.f;
            const float s  = slp[t];
            const float sn = slp[t+1];
            const float mP = (t >= 1) ? 1.f : 0.f;
            const float rg = (t < 2) ? 1.f : 0.f;
            float iv0 = 0.f, iv1 = 0.f;
            if (t < 2) { iv0 = il[pr*4 + t*2]; iv1 = il[pr*4 + t*2 + 1]; }
            const float s2 = s*s, s3 = s2*s, p2 = p*p, p3 = p2*p, gt = p + s;
            F[0]  = c0*c0 + rg + 2.f*(1.f + mP);           // A0
            F[1]  = c0*c1 + s - p;                          // A1
            F[2]  = c0*c2 + 0.5f*(s2 + p2);                 // A2
            F[3]  = s;                                      // A4
            F[4]  = -0.5f*s2;                               // A5
            F[5]  = c0*r + iv0;                             // rv0
            F[6]  = c1*c1 + 3.f*(s2 + p2) + 2.f;            // B0
            F[7]  = c1*c2 + 1.5f*(s3 - p3);                 // B1
            F[8]  = -s;                                     // B2
            F[9]  = -2.f*s2;                                // B3
            F[10] = s3 + (s + sn);                          // B4
            F[11] = c1*r + iv1;                             // rv1
            F[12] = c2*c2 + 1.25f*(s2*s2 + p2*p2) + gt*gt*mP; // Cv0
            F[13] = -0.5f*s2;                               // Cv1
            F[14] = -s3 - gt*mP;                            // Cv2
            F[15] = c2*r;                                   // rv2
        }
        {   // bwd pieces, step t = 63 - it  (t in 33..63)
            const int t = 63 - it;
            const float c0 = cfp[3*t], c1 = cfp[3*t+1], c2 = cfp[3*t+2];
            const float r  = rlp[t];
            const float s  = (t < 63) ? slp[t] : 0.f;
            const float p  = slp[t-1];
            const float pp = slp[t-2];
            const float mSb  = (t < 63) ? 1.f : 0.f;
            const float mCNb = (t < 62) ? 1.f : 0.f;
            const float s2 = s*s, s3 = s2*s, p2 = p*p, p3 = p2*p, gt = p + s;
            G[0]  = c2*c2 + 1.25f*(s2*s2 + p2*p2) + gt*gt*mSb; // Cv0b
            G[1]  = c1*c2 + 1.5f*(s3 - p3);                    // B1b
            G[2]  = c0*c2 + 0.5f*(s2 + p2);                    // A2b
            G[3]  = p3 + (p + s)*mSb;                          // B4m
            G[4]  = -0.5f*p2;                                  // A5m
            G[5]  = c2*r;                                      // rv2b
            G[6]  = c1*c1 + 3.f*(s2 + p2) + mCNb + 1.f;        // B0b
            G[7]  = c0*c1 + s - p;                             // A1b
            G[8]  = -p3 - (pp + p);                            // Cv2m
            G[9]  = -2.f*p2;                                   // B3m
            G[10] = p;                                         // A4m
            G[11] = c1*r;                                      // rv1b
            G[12] = c0*c0 + 2.f*(mSb + 1.f);                   // A0b
            G[13] = -0.5f*p2;                                  // Cv1m
            G[14] = -p;                                        // B2m
            G[15] = c0*r;                                      // rv0b
        }
        float2* dst = (float2*)wsBP + ((size_t)w * BP_PER_W + (size_t)it * 16) * 32 + pr;
        #pragma unroll
        for (int k = 0; k < 16; ++k) dst[(size_t)k * 32] = make_float2(F[k], G[k]);
    }

    // ---- middle-block pre-Schur values (27 per batch) ----
    if (tid < 32) {
        const int pr = tid;
        const float* cfp = cf + pr * 193;
        const float* slp = sl + pr * 65;
        const float* rlp = rl + pr * 65;
        const float pA = slp[30], sA = slp[31], snA = slp[32];
        const float sB = slp[32], pB = sA;
        const float c0A = cfp[93], c1A = cfp[94], c2A = cfp[95];
        const float c0B = cfp[96], c1B = cfp[97], c2B = cfp[98];
        const float rA = rlp[31], rB = rlp[32];
        const float sA2 = sA*sA, sA3 = sA2*sA, pA2 = pA*pA, pA3 = pA2*pA;
        const float sB2 = sB*sB, sB3 = sB2*sB, pB2 = pB*pB, pB3 = pB2*pB;
        float m[27];
        m[0]  = c0A*c0A + 4.f;
        m[1]  = c0A*c1A + sA - pA;
        m[2]  = c0A*c2A + 0.5f*(sA2 + pA2);
        m[3]  = -2.f;
        m[4]  = sA;
        m[5]  = -0.5f*sA2;
        m[6]  = c1A*c1A + 3.f*(sA2 + pA2) + 2.f;
        m[7]  = c1A*c2A + 1.5f*(sA3 - pA3);
        m[8]  = -sA;
        m[9]  = -2.f*sA2;
        m[10] = sA3 + (sA + snA);
        m[11] = c2A*c2A + 1.25f*(sA2*sA2 + pA2*pA2) + (pA + sA)*(pA + sA);
        m[12] = -0.5f*sA2;
        m[13] = -sA3 - (pA + sA);
        m[14] = 0.f;
        m[15] = c0B*c0B + 4.f;
        m[16] = c0B*c1B + sB - pB;
        m[17] = c0B*c2B + 0.5f*(sB2 + pB2);
        m[18] = c1B*c1B + 3.f*(sB2 + pB2) + 2.f;
        m[19] = c1B*c2B + 1.5f*(sB3 - pB3);
        m[20] = c2B*c2B + 1.25f*(sB2*sB2 + pB2*pB2) + (pB + sB)*(pB + sB);
        m[21] = c0A*rA; m[22] = c1A*rA; m[23] = c2A*rA;
        m[24] = c0B*rB; m[25] = c1B*rB; m[26] = c2B*rB;
        #pragma unroll
        for (int k = 0; k < 27; ++k)
            wsMID[(size_t)w * MID_PER_W * 32 + (size_t)k * 32 + pr] = m[k];
    }
}

// ============================================================================
// K2 (fused7): lane-paired twisted factorization. 32 blocks x 64 threads.
// Depth-2 piece prefetch; constant band slots in registers (cA/cB); last
// iteration peeled with register capture (no store->reload at the seam);
// backsub prefetch pre-issued before the middle-block math; 3-role backsub.
// ============================================================================
__global__ __launch_bounds__(64, 1)
void ode_fused7(const float* __restrict__ wsBP,
                const float* __restrict__ wsMID,
                float* __restrict__ wsL,
                float* __restrict__ wsXq,
                float* __restrict__ wsMX)
{
    const int w     = blockIdx.x;
    const int l     = threadIdx.x;
    const int pair  = l >> 1;
    const int chain = l & 1;
    const float cA  = chain ? 0.f : -2.f;   // col0 b3
    const float cB  = chain ? -2.f : 0.f;   // col2 b3

    const float* __restrict__ bp = wsBP + (size_t)w * BP_PER_W * 64 + l;
    float* __restrict__ ln = wsL  + (size_t)w * L_PER_W * 64 + l;
    float* __restrict__ xq = wsXq + (size_t)w * XQ_PER_W * 64 + l;

#define SBP(it, k) bp[(size_t)((it) * 16 + (k)) * 64]
#define SL(i)      ln[(size_t)(i) * 64]
#define SXQ(q)     xq[(size_t)(q) * 64]

    float W11=0,W12=0,W13=0,W14=0,W15=0,W16=0;
    float W22=0,W23=0,W24=0,W25=0,W26=0;
    float W33=0,W34=0,W35=0,W36=0;
    float W44=0,W45=0,W46=0;
    float W55=0,W56=0;
    float W66=0;
    float y1=0,y2=0,y3=0,y4=0,y5=0,y6=0;

#define CHOL_BODY(b0, b1, b2, b3, b4, b5, b6, rvv)                             \
        const float t0_ = (b0) - (W11*W11 + W22*W22 + W33*W33 +                \
                                  W44*W44 + W55*W55 + W66*W66);                \
        const float di_ = rsqrtf(t0_);                                         \
        const float u1_ = (b1) - (W11*W12 + W22*W23 + W33*W34 +                \
                                  W44*W45 + W55*W56);                          \
        const float u2_ = (b2) - (W11*W13 + W22*W24 + W33*W35 + W44*W46);      \
        const float u3_ = (b3) - (W11*W14 + W22*W25 + W33*W36);                \
        const float u4_ = (b4) - (W11*W15 + W22*W26);                          \
        const float u5_ = (b5) - (W11*W16);                                    \
        const float u6_ = (b6);                                                \
        const float yj_ = ((rvv) - (W11*y1 + W22*y2 + W33*y3 +                 \
                                    W44*y4 + W55*y5 + W66*y6)) * di_;          \
        const float n1_ = u1_*di_, n2_ = u2_*di_, n3_ = u3_*di_;               \
        const float n4_ = u4_*di_, n5_ = u5_*di_, n6_ = u6_*di_;

#define CHOL_SHIFT()                                                           \
        W66 = W56;                                                             \
        W55 = W45; W56 = W46;                                                  \
        W44 = W34; W45 = W35; W46 = W36;                                       \
        W33 = W23; W34 = W24; W35 = W25; W36 = W26;                            \
        W22 = W12; W23 = W13; W24 = W14; W25 = W15; W26 = W16;                 \
        W11 = n1_; W12 = n2_; W13 = n3_; W14 = n4_; W15 = n5_; W16 = n6_;      \
        y6 = y5; y5 = y4; y4 = y3; y3 = y2; y2 = y1; y1 = yj_;

#define CHOL_COL(q, b0, b1, b2, b3, b4, b5, b6, rvv)                           \
    {                                                                          \
        CHOL_BODY(b0, b1, b2, b3, b4, b5, b6, rvv)                             \
        SL((q)*8 + 0) = di_; SL((q)*8 + 1) = n1_; SL((q)*8 + 2) = n2_;         \
        SL((q)*8 + 3) = n3_; SL((q)*8 + 4) = n4_; SL((q)*8 + 5) = n5_;         \
        SL((q)*8 + 6) = n6_; SL((q)*8 + 7) = yj_;                              \
        CHOL_SHIFT()                                                           \
    }

// peeled variant: capture column into registers P*, no store
#define CHOL_COL_CAP(P, b0, b1, b2, b3, b4, b5, b6, rvv)                       \
    {                                                                          \
        CHOL_BODY(b0, b1, b2, b3, b4, b5, b6, rvv)                             \
        P##d = di_; P##1 = n1_; P##2 = n2_; P##3 = n3_;                        \
        P##4 = n4_; P##5 = n5_; P##6 = n6_; P##y = yj_;                        \
        CHOL_SHIFT()                                                           \
    }

    // preload pieces for it=0 (C) and it=1 (D)
    float C0 = SBP(0,0),  C1 = SBP(0,1),  C2 = SBP(0,2),  C3 = SBP(0,3);
    float C4 = SBP(0,4),  C5 = SBP(0,5),  C6 = SBP(0,6),  C7 = SBP(0,7);
    float C8 = SBP(0,8),  C9 = SBP(0,9),  C10 = SBP(0,10), C11 = SBP(0,11);
    float C12 = SBP(0,12), C13 = SBP(0,13), C14 = SBP(0,14), C15 = SBP(0,15);
    float D0 = SBP(1,0),  D1 = SBP(1,1),  D2 = SBP(1,2),  D3 = SBP(1,3);
    float D4 = SBP(1,4),  D5 = SBP(1,5),  D6 = SBP(1,6),  D7 = SBP(1,7);
    float D8 = SBP(1,8),  D9 = SBP(1,9),  D10 = SBP(1,10), D11 = SBP(1,11);
    float D12 = SBP(1,12), D13 = SBP(1,13), D14 = SBP(1,14), D15 = SBP(1,15);

    for (int it = 0; it <= 29; ++it) {
        float N0=0,N1=0,N2=0,N3=0,N4=0,N5=0,N6=0,N7=0;
        float N8=0,N9=0,N10=0,N11=0,N12=0,N13=0,N14=0,N15=0;
        if (it + 2 <= 30) {
            N0  = SBP(it+2,0);  N1  = SBP(it+2,1);  N2  = SBP(it+2,2);  N3  = SBP(it+2,3);
            N4  = SBP(it+2,4);  N5  = SBP(it+2,5);  N6  = SBP(it+2,6);  N7  = SBP(it+2,7);
            N8  = SBP(it+2,8);  N9  = SBP(it+2,9);  N10 = SBP(it+2,10); N11 = SBP(it+2,11);
            N12 = SBP(it+2,12); N13 = SBP(it+2,13); N14 = SBP(it+2,14); N15 = SBP(it+2,15);
        }
        const int q0 = 3 * it;
        CHOL_COL(q0 + 0, C0,  C1,  C2,  cA,   C3,  C4,  0.f,  C5);
        CHOL_COL(q0 + 1, C6,  C7,  C8,  C9,   C10, 0.f, -1.f, C11);
        CHOL_COL(q0 + 2, C12, C13, C14, cB,   0.f, 0.f, 0.f,  C15);
        C0=D0; C1=D1; C2=D2; C3=D3; C4=D4; C5=D5; C6=D6; C7=D7;
        C8=D8; C9=D9; C10=D10; C11=D11; C12=D12; C13=D13; C14=D14; C15=D15;
        D0=N0; D1=N1; D2=N2; D3=N3; D4=N4; D5=N5; D6=N6; D7=N7;
        D8=N8; D9=N9; D10=N10; D11=N11; D12=N12; D13=N13; D14=N14; D15=N15;
    }

#define DECL8(P) float P##d = 0, P##1 = 0, P##2 = 0, P##3 = 0,                 \
                       P##4 = 0, P##5 = 0, P##6 = 0, P##y = 0;
#define LOAD8(P, q) { const size_t o8 = (size_t)(q)*8;                         \
        P##d = SL(o8 + 0); P##1 = SL(o8 + 1); P##2 = SL(o8 + 2);               \
        P##3 = SL(o8 + 3); P##4 = SL(o8 + 4); P##5 = SL(o8 + 5);               \
        P##6 = SL(o8 + 6); P##y = SL(o8 + 7); }

    DECL8(PA) DECL8(PB) DECL8(PC)
    DECL8(QA) DECL8(QB) DECL8(QC)
    DECL8(RA) DECL8(RB) DECL8(RC)

    // peel it=30 (C holds it=30 pieces): capture q90..92 in registers
    CHOL_COL_CAP(PA, C0,  C1,  C2,  cA,   C3,  C4,  0.f,  C5);    // q90
    CHOL_COL_CAP(PB, C6,  C7,  C8,  C9,   C10, 0.f, -1.f, C11);   // q91
    CHOL_COL_CAP(PC, C12, C13, C14, cB,   0.f, 0.f, 0.f,  C15);   // q92

    // pre-issue backsub prefetch (hidden under exchange + middle block)
    LOAD8(QC, 89) LOAD8(QB, 88) LOAD8(QA, 87)
    LOAD8(RC, 86) LOAD8(RB, 85) LOAD8(RA, 84)

    // ---- window exchange between lane pairs ----
    const float R11=__shfl_xor(W11,1), R12=__shfl_xor(W12,1), R13=__shfl_xor(W13,1);
    const float R14=__shfl_xor(W14,1), R15=__shfl_xor(W15,1), R16=__shfl_xor(W16,1);
    const float R22=__shfl_xor(W22,1), R23=__shfl_xor(W23,1), R24=__shfl_xor(W24,1);
    const float R25=__shfl_xor(W25,1), R26=__shfl_xor(W26,1);
    const float R33=__shfl_xor(W33,1), R34=__shfl_xor(W34,1), R35=__shfl_xor(W35,1);
    const float R36=__shfl_xor(W36,1);
    const float R44=__shfl_xor(W44,1), R45=__shfl_xor(W45,1), R46=__shfl_xor(W46,1);
    const float R55=__shfl_xor(W55,1), R56=__shfl_xor(W56,1);
    const float R66=__shfl_xor(W66,1);
    const float r1=__shfl_xor(y1,1), r2=__shfl_xor(y2,1), r3=__shfl_xor(y3,1);
    const float r4=__shfl_xor(y4,1), r5=__shfl_xor(y5,1), r6=__shfl_xor(y6,1);

    float xm0=0, xm1=0, xm2=0, xm3=0, xm4=0, xm5=0;
    if (chain == 0) {
        const float* __restrict__ md = wsMID + (size_t)w * MID_PER_W * 32 + pair;
        float S00 = md[0*32],  S10 = md[1*32],  S20 = md[2*32];
        float S30 = md[3*32],  S40 = md[4*32],  S50 = md[5*32];
        float S11 = md[6*32],  S21 = md[7*32],  S31 = md[8*32];
        float S41 = md[9*32],  S51 = md[10*32], S22 = md[11*32];
        float S32 = md[12*32], S42 = md[13*32], S52 = md[14*32];
        float S33 = md[15*32], S43 = md[16*32], S53 = md[17*32];
        float S44 = md[18*32], S54 = md[19*32], S55 = md[20*32];
        float fm0 = md[21*32], fm1 = md[22*32], fm2 = md[23*32];
        float fm3 = md[24*32], fm4 = md[25*32], fm5 = md[26*32];

        S00 -= W11*W11 + W22*W22 + W33*W33 + W44*W44 + W55*W55 + W66*W66;
        S10 -= W12*W11 + W23*W22 + W34*W33 + W45*W44 + W56*W55;
        S11 -= W12*W12 + W23*W23 + W34*W34 + W45*W45 + W56*W56;
        S20 -= W13*W11 + W24*W22 + W35*W33 + W46*W44;
        S21 -= W13*W12 + W24*W23 + W35*W34 + W46*W45;
        S22 -= W13*W13 + W24*W24 + W35*W35 + W46*W46;
        S30 -= W14*W11 + W25*W22 + W36*W33;
        S31 -= W14*W12 + W25*W23 + W36*W34;
        S32 -= W14*W13 + W25*W24 + W36*W35;
        S33 -= W14*W14 + W25*W25 + W36*W36;
        S40 -= W15*W11 + W26*W22;
        S41 -= W15*W12 + W26*W23;
        S42 -= W15*W13 + W26*W24;
        S43 -= W15*W14 + W26*W25;
        S44 -= W15*W15 + W26*W26;
        S50 -= W16*W11;
        S51 -= W16*W12;
        S52 -= W16*W13;
        S53 -= W16*W14;
        S54 -= W16*W15;
        S55 -= W16*W16;

        S00 -= R16*R16;
        S10 -= R15*R16;
        S11 -= R15*R15 + R26*R26;
        S20 -= R14*R16;
        S21 -= R14*R15 + R25*R26;
        S22 -= R14*R14 + R25*R25 + R36*R36;
        S30 -= R13*R16;
        S31 -= R13*R15 + R24*R26;
        S32 -= R13*R14 + R24*R25 + R35*R36;
        S33 -= R13*R13 + R24*R24 + R35*R35 + R46*R46;
        S40 -= R12*R16;
        S41 -= R12*R15 + R23*R26;
        S42 -= R12*R14 + R23*R25 + R34*R36;
        S43 -= R12*R13 + R23*R24 + R34*R35 + R45*R46;
        S44 -= R12*R12 + R23*R23 + R34*R34 + R45*R45 + R56*R56;
        S50 -= R11*R16;
        S51 -= R11*R15 + R22*R26;
        S52 -= R11*R14 + R22*R25 + R33*R36;
        S53 -= R11*R13 + R22*R24 + R33*R35 + R44*R46;
        S54 -= R11*R12 + R22*R23 + R33*R34 + R44*R45 + R55*R56;
        S55 -= R11*R11 + R22*R22 + R33*R33 + R44*R44 + R55*R55 + R66*R66;

        fm0 -= (W11*y1 + W22*y2 + W33*y3 + W44*y4 + W55*y5 + W66*y6) + (R16*r1);
        fm1 -= (W12*y1 + W23*y2 + W34*y3 + W45*y4 + W56*y5) + (R15*r1 + R26*r2);
        fm2 -= (W13*y1 + W24*y2 + W35*y3 + W46*y4) + (R14*r1 + R25*r2 + R36*r3);
        fm3 -= (W14*y1 + W25*y2 + W36*y3) + (R13*r1 + R24*r2 + R35*r3 + R46*r4);
        fm4 -= (W15*y1 + W26*y2) + (R12*r1 + R23*r2 + R34*r3 + R45*r4 + R56*r5);
        fm5 -= (W16*y1) + (R11*r1 + R22*r2 + R33*r3 + R44*r4 + R55*r5 + R66*r6);

        const float md0 = rsqrtf(S00);
        const float M10 = S10*md0, M20 = S20*md0, M30 = S30*md0,
                    M40 = S40*md0, M50 = S50*md0;
        const float zm0 = fm0*md0;
        const float md1 = rsqrtf(S11 - M10*M10);
        const float M21 = (S21 - M20*M10)*md1;
        const float M31 = (S31 - M30*M10)*md1;
        const float M41 = (S41 - M40*M10)*md1;
        const float M51 = (S51 - M50*M10)*md1;
        const float zm1 = (fm1 - M10*zm0)*md1;
        const float md2 = rsqrtf(S22 - M20*M20 - M21*M21);
        const float M32 = (S32 - M30*M20 - M31*M21)*md2;
        const float M42 = (S42 - M40*M20 - M41*M21)*md2;
        const float M52 = (S52 - M50*M20 - M51*M21)*md2;
        const float zm2 = (fm2 - M20*zm0 - M21*zm1)*md2;
        const float md3 = rsqrtf(S33 - M30*M30 - M31*M31 - M32*M32);
        const float M43 = (S43 - M40*M30 - M41*M31 - M42*M32)*md3;
        const float M53 = (S53 - M50*M30 - M51*M31 - M52*M32)*md3;
        const float zm3 = (fm3 - M30*zm0 - M31*zm1 - M32*zm2)*md3;
        const float md4 = rsqrtf(S44 - M40*M40 - M41*M41 - M42*M42 - M43*M43);
        const float M54 = (S54 - M50*M40 - M51*M41 - M52*M42 - M53*M43)*md4;
        const float zm4 = (fm4 - M40*zm0 - M41*zm1 - M42*zm2 - M43*zm3)*md4;
        const float md5 = rsqrtf(S55 - M50*M50 - M51*M51 - M52*M52 - M53*M53 - M54*M54);
        const float zm5 = (fm5 - M50*zm0 - M51*zm1 - M52*zm2 - M53*zm3 - M54*zm4)*md5;

        xm5 = zm5*md5;
        xm4 = (zm4 - M54*xm5)*md4;
        xm3 = (zm3 - M43*xm4 - M53*xm5)*md3;
        xm2 = (zm2 - M32*xm3 - M42*xm4 - M52*xm5)*md2;
        xm1 = (zm1 - M21*xm2 - M31*xm3 - M41*xm4 - M51*xm5)*md1;
        xm0 = (zm0 - M10*xm1 - M20*xm2 - M30*xm3 - M40*xm4 - M50*xm5)*md0;

        float* __restrict__ mx = wsMX + (size_t)w * MX_PER_W * 32 + pair;
        mx[0*32] = xm0; mx[1*32] = xm1; mx[2*32] = xm2;
        mx[3*32] = xm3; mx[4*32] = xm4; mx[5*32] = xm5;
    }

    // distribute x_mid to odd lanes
    const float g0 = __shfl_xor(xm0, 1), g1 = __shfl_xor(xm1, 1);
    const float g2 = __shfl_xor(xm2, 1), g3 = __shfl_xor(xm3, 1);
    const float g4 = __shfl_xor(xm4, 1), g5 = __shfl_xor(xm5, 1);

    float x1 = chain ? g5 : xm0;
    float x2 = chain ? g4 : xm1;
    float x3 = chain ? g3 : xm2;
    float x4 = chain ? g2 : xm3;
    float x5 = chain ? g1 : xm4;
    float x6 = chain ? g0 : xm5;

#define BSUB(P, q) {                                                           \
        const float rest = (P##6*x6 + P##5*x5) + (P##4*x4 + P##3*x3) + P##2*x2;\
        const float xr = ((P##y - rest) - P##1*x1) * P##d;                     \
        SXQ(q) = xr;                                                           \
        x6 = x5; x5 = x4; x4 = x3; x3 = x2; x2 = x1; x1 = xr; }

    // ---- uniform back-substitution, 3-role rotation, distance-2 prefetch ----
    for (int it2 = 0; it2 < 31; it2 += 3) {
        {   const int st = 30 - it2;
            BSUB(PC, 3*st + 2) BSUB(PB, 3*st + 1) BSUB(PA, 3*st)
            if (st - 3 >= 0) { LOAD8(PC, 3*(st-3) + 2) LOAD8(PB, 3*(st-3) + 1) LOAD8(PA, 3*(st-3)) }
        }
        {   const int st = 29 - it2;
            if (st >= 0) {
                BSUB(QC, 3*st + 2) BSUB(QB, 3*st + 1) BSUB(QA, 3*st)
                if (st - 3 >= 0) { LOAD8(QC, 3*(st-3) + 2) LOAD8(QB, 3*(st-3) + 1) LOAD8(QA, 3*(st-3)) }
            }
        }
        {   const int st = 28 - it2;
            if (st >= 0) {
                BSUB(RC, 3*st + 2) BSUB(RB, 3*st + 1) BSUB(RA, 3*st)
                if (st - 3 >= 0) { LOAD8(RC, 3*(st-3) + 2) LOAD8(RB, 3*(st-3) + 1) LOAD8(RA, 3*(st-3)) }
            }
        }
    }

#undef SBP
#undef SL
#undef SXQ
#undef CHOL_BODY
#undef CHOL_SHIFT
#undef CHOL_COL
#undef CHOL_COL_CAP
#undef DECL8
#undef LOAD8
#undef BSUB
}

// ============================================================================
// K3 (xout): map lane-paired q-indexed x back to out[b][j]. Coalesced out.
// ============================================================================
__global__ __launch_bounds__(1024, 1)
void ode_xout(const float* __restrict__ wsXq,
              const float* __restrict__ wsMX,
              float* __restrict__ out)
{
    const int g   = blockIdx.x;     // 0..15 (64 batches = waves 2g, 2g+1)
    const int tid = threadIdx.x;
    __shared__ float xl[2][93][64];
    __shared__ float mx[2][6][32];

    for (int idx = tid; idx < 2 * 93 * 64; idx += 1024) {
        const int wl = idx / (93 * 64);
        const int rest = idx - wl * 93 * 64;
        const int q = rest >> 6, l = rest & 63;
        xl[wl][q][l] = wsXq[(size_t)(2 * g + wl) * XQ_PER_W * 64 + (size_t)q * 64 + l];
    }
    for (int idx = tid; idx < 2 * 6 * 32; idx += 1024) {
        const int wl = idx / 192;
        const int rest = idx - wl * 192;
        const int k = rest >> 5, pr = rest & 31;
        mx[wl][k][pr] = wsMX[(size_t)(2 * g + wl) * MX_PER_W * 32 + (size_t)k * 32 + pr];
    }
    __syncthreads();

    for (int idx = tid; idx < 64 * 192; idx += 1024) {
        const int bl = idx / 192;
        const int j  = idx - bl * 192;
        const int wl = bl >> 5;
        const int pr = bl & 31;
        float v;
        if (j < 93)      v = xl[wl][j][2 * pr];
        else if (j > 98) v = xl[wl][191 - j][2 * pr + 1];
        else             v = mx[wl][j - 93][pr];
        out[(size_t)g * 64 * 192 + idx] = v;
    }
}

// ============================================================================
// Fallback (round-1 kernel, known-pass): used only if ws is too small
// ============================================================================
__global__ __launch_bounds__(64, 1)
void ode_banded_solve(const float* __restrict__ coeffs,
                      const float* __restrict__ rhs,
                      const float* __restrict__ iv_rhs,
                      const float* __restrict__ steps,
                      float* __restrict__ out)
{
    const int b    = blockIdx.x;
    const int lane = threadIdx.x;

    __shared__ float band[NV * BW];
    __shared__ float rv[NV];
    __shared__ float stp[NT + 1];

    for (int i = lane; i < NV * BW; i += 64) band[i] = 0.0f;
    if (lane < NT) stp[lane] = steps[b * NT + lane];
    __syncthreads();

    {
        const int st = lane;
        const float c0 = coeffs[b * NV + st * 3 + 0];
        const float c1 = coeffs[b * NV + st * 3 + 1];
        const float c2 = coeffs[b * NV + st * 3 + 2];
        const float r  = rhs[b * NS + st];
        const float reg = (st < 2) ? 1.0f : 0.0f;
        atomicAdd(&band[(3 * st + 0) * BW + 0], c0 * c0 + reg);
        atomicAdd(&band[(3 * st + 1) * BW + 0], c1 * c1 + reg);
        atomicAdd(&band[(3 * st + 2) * BW + 0], c2 * c2);
        atomicAdd(&band[(3 * st + 1) * BW + 1], c1 * c0);
        atomicAdd(&band[(3 * st + 2) * BW + 1], c2 * c1);
        atomicAdd(&band[(3 * st + 2) * BW + 2], c2 * c0);
        float b0 = c0 * r, b1 = c1 * r, b2v = c2 * r;
        if (st < 2) {
            b0 += iv_rhs[b * 4 + st * 2 + 0];
            b1 += iv_rhs[b * 4 + st * 2 + 1];
        }
        rv[3 * st + 0] = b0;
        rv[3 * st + 1] = b1;
        rv[3 * st + 2] = b2v;
    }

    for (int t = lane; t < NC; t += 64) {
        int   cols[4];
        float vals[4];
        int   cnt;
        if (t < 126) {
            const int st = t >> 1, i = t & 1;
            const float s = stp[st];
            if (i == 0) {
                cols[0] = 3 * st + 0; vals[0] = 1.0f;
                cols[1] = 3 * st + 1; vals[1] = s;
                cols[2] = 3 * st + 2; vals[2] = 0.5f * s * s;
                cols[3] = 3 * st + 3; vals[3] = -1.0f;
                cnt = 4;
            } else {
                cols[0] = 3 * st + 1; vals[0] = s;
                cols[1] = 3 * st + 2; vals[1] = s * s;
                cols[2] = 3 * st + 4; vals[2] = -s;
                cnt = 3;
            }
        } else if (t < 188) {
            const int st = t - 126 + 1;
            const float cp = stp[st - 1] + stp[st];
            cols[0] = 3 * st - 2; vals[0] = -1.0f;
            cols[1] = 3 * st + 2; vals[1] = -cp;
            cols[2] = 3 * st + 4; vals[2] = 1.0f;
            cnt = 3;
        } else {
            const int tt = t - 188;
            const int st = tt >> 1, i = tt & 1;
            const float s = stp[st];
            if (i == 0) {
                cols[0] = 3 * st + 0; vals[0] = -1.0f;
                cols[1] = 3 * st + 3; vals[1] = 1.0f;
                cols[2] = 3 * st + 4; vals[2] = -s;
                cols[3] = 3 * st + 5; vals[3] = 0.5f * s * s;
                cnt = 4;
            } else {
                cols[0] = 3 * st + 1; vals[0] = s;
                cols[1] = 3 * st + 4; vals[1] = -s;
                cols[2] = 3 * st + 5; vals[2] = s * s;
                cnt = 3;
            }
        }
        for (int a = 0; a < cnt; ++a)
            for (int b2 = 0; b2 <= a; ++b2)
                atomicAdd(&band[cols[a] * BW + (cols[a] - cols[b2])],
                          vals[a] * vals[b2]);
    }
    __syncthreads();

    int pa = 0, pb = 0;
    {
        int idx = 0;
        for (int aa = 1; aa <= 6; ++aa)
            for (int bb = 1; bb <= aa; ++bb) {
                if (idx == lane) { pa = aa; pb = bb; }
                ++idx;
            }
    }
    const int sk = lane - 20;

    for (int j = 0; j < NV; ++j) {
        const int m = (NV - 1 - j < 6) ? (NV - 1 - j) : 6;
        const float diag = band[j * BW];
        const float d    = sqrtf(diag);
        const float dinv = 1.0f / d;

        const bool doU = (lane < 21) && (pa <= m);
        const bool doS = (lane >= 21) && (lane <= 26) && (sk <= m);
        float ca = 0.0f, cb = 0.0f, cs = 0.0f;
        if (doU) { ca = band[(j + pa) * BW + pa]; cb = band[(j + pb) * BW + pb]; }
        if (doS) { cs = band[(j + sk) * BW + sk]; }
        __syncthreads();

        if (lane == 0) band[j * BW] = d;
        if (doU) band[(j + pa) * BW + (pa - pb)] -= ca * cb * (dinv * dinv);
        if (doS) band[(j + sk) * BW + sk] = cs * dinv;
        __syncthreads();
    }

    for (int j = 0; j < NV; ++j) {
        const int m = (NV - 1 - j < 6) ? (NV - 1 - j) : 6;
        const float yj = rv[j] / band[j * BW];
        const bool doK = (lane >= 1) && (lane <= m);
        float sub = 0.0f, rj = 0.0f;
        if (doK) { sub = band[(j + lane) * BW + lane] * yj; rj = rv[j + lane]; }
        __syncthreads();
        if (lane == 0) rv[j] = yj;
        if (doK) rv[j + lane] = rj - sub;
        __syncthreads();
    }

    for (int j = NV - 1; j >= 0; --j) {
        const int m = (j < 6) ? j : 6;
        const float xj = rv[j] / band[j * BW];
        const bool doK = (lane >= 1) && (lane <= m);
        float sub = 0.0f, rj = 0.0f;
        if (doK) { sub = band[j * BW + lane] * xj; rj = rv[j - lane]; }
        __syncthreads();
        if (lane == 0) rv[j] = xj;
        if (doK) rv[j - lane] = rj - sub;
        __syncthreads();
    }

    for (int i = lane; i < NV; i += 64)
        out[b * NV + i] = rv[i];
}

extern "C" void kernel_launch(void* const* d_in, const int* in_sizes, int n_in,
                              void* d_out, int out_size, void* d_ws, size_t ws_size,
                              hipStream_t stream)
{
    const float* coeffs = (const float*)d_in[0];   // 1024*64*3
    const float* rhs    = (const float*)d_in[1];   // 1024*64
    const float* iv_rhs = (const float*)d_in[2];   // 1024*2*2
    const float* steps  = (const float*)d_in[3];   // 1024*63
    float* out = (float*)d_out;                    // 1024*192

    const size_t BPf  = (size_t)NW * BP_PER_W * 64;
    const size_t MIDf = (size_t)NW * MID_PER_W * 32;
    const size_t Lf   = (size_t)NW * L_PER_W * 64;
    const size_t XQf  = (size_t)NW * XQ_PER_W * 64;
    const size_t MXf  = (size_t)NW * MX_PER_W * 32;
    const size_t need = (BPf + MIDf + Lf + XQf + MXf) * sizeof(float);   // ~11 MB

    if (ws_size >= need) {
        float* wsBP  = (float*)d_ws;
        float* wsMID = wsBP  + BPf;
        float* wsL   = wsMID + MIDf;
        float* wsXq  = wsL   + Lf;
        float* wsMX  = wsXq  + XQf;
        ode_prep2<<<dim3(NW), dim3(1024), 0, stream>>>(coeffs, rhs, steps, iv_rhs,
                                                       wsBP, wsMID);
        ode_fused7<<<dim3(NW), dim3(64), 0, stream>>>(wsBP, wsMID, wsL, wsXq, wsMX);
        ode_xout<<<dim3(16), dim3(1024), 0, stream>>>(wsXq, wsMX, out);
    } else {
        ode_banded_solve<<<dim3(NB), dim3(64), 0, stream>>>(coeffs, rhs, iv_rhs,
                                                            steps, out);
    }
}

// Round 10
// 44.303 us; speedup vs baseline: 2.8423x; 1.1097x over previous
//
#include <hip/hip_runtime.h>
#include <math.h>

// Problem constants (static config)
#define NB 1024
#define NS 64
#define NT 63
#define NV 192
#define BW 7
#define NC 314

#define NW 32               // blocks; each handles 32 batches (64 lanes = 2 chains)
#define BP_PER_W (31*16)    // 31 iters x 16 slots (x64 lanes)
#define L_PER_W  (93*8)     // 93 cols x 8 slots   (x64 lanes)
#define XQ_PER_W 96         // 93 used             (x64 lanes)

// ============================================================================
// ode_mega: single-kernel pipeline. Block w = batches w*32..w*32+31.
// Phase 0 (1024 thr): stage inputs->LDS; BP pieces->global (L2-local);
//                     middle-block pre-Schur->LDS.
// Phase 1 (wave 0)  : lane-paired twisted Cholesky + backsub (r9 verbatim).
// Phase 2 (1024 thr): map q-indexed x to out (coalesced writes).
// ============================================================================
__global__ __launch_bounds__(1024, 1)
void ode_mega(const float* __restrict__ coeffs,
              const float* __restrict__ rhs,
              const float* __restrict__ steps,
              const float* __restrict__ iv_rhs,
              float* __restrict__ wsBP,
              float* __restrict__ wsL,
              float* __restrict__ wsXq,
              float* __restrict__ out)
{
    const int w   = blockIdx.x;     // 0..31
    const int tid = threadIdx.x;

    __shared__ float cf[32 * 193];  // coeffs [pr][0..191], stride 193
    __shared__ float sl[32 * 65];   // steps  [pr][0..62]
    __shared__ float rl[32 * 65];   // rhs    [pr][0..63]
    __shared__ float il[128];       // iv     [pr][0..3]
    __shared__ float midl[27 * 32]; // middle pre-Schur [k][pr]
    __shared__ float mxl[6 * 32];   // middle x        [k][pr]

    // ---------------- Phase 0a: stage inputs (coalesced) ----------------
    for (int idx = tid; idx < 32 * 192; idx += 1024) {
        const int b = idx / 192, j = idx - 192 * b;
        cf[b * 193 + j] = coeffs[(size_t)w * 6144 + idx];
    }
    for (int idx = tid; idx < 32 * 63; idx += 1024) {
        const int b = idx / 63, j = idx - 63 * b;
        sl[b * 65 + j] = steps[(size_t)w * 2016 + idx];
    }
    for (int idx = tid; idx < 32 * 64; idx += 1024) {
        const int b = idx >> 6, j = idx & 63;
        rl[b * 65 + j] = rhs[(size_t)w * 2048 + idx];
    }
    if (tid < 128) il[tid] = iv_rhs[(size_t)w * 128 + tid];
    __syncthreads();

    // ---------------- Phase 0b: band pieces + middle pre-Schur ----------------
    for (int idx = tid; idx < 31 * 32; idx += 1024) {
        const int it = idx >> 5;    // 0..30
        const int pr = idx & 31;
        const float* cfp = cf + pr * 193;
        const float* slp = sl + pr * 65;
        const float* rlp = rl + pr * 65;

        float F[16], G[16];
        {   // fwd pieces, step t = it  (t <= 30: mS = mCN = 1)
            const int t = it;
            const float c0 = cfp[3*t], c1 = cfp[3*t+1], c2 = cfp[3*t+2];
            const float r  = rlp[t];
            const float p  = (t >= 1) ? slp[t-1] : 0.f;
            const float s  = slp[t];
            const float sn = slp[t+1];
            const float mP = (t >= 1) ? 1.f : 0.f;
            const float rg = (t < 2) ? 1.f : 0.f;
            float iv0 = 0.f, iv1 = 0.f;
            if (t < 2) { iv0 = il[pr*4 + t*2]; iv1 = il[pr*4 + t*2 + 1]; }
            const float s2 = s*s, s3 = s2*s, p2 = p*p, p3 = p2*p, gt = p + s;
            F[0]  = c0*c0 + rg + 2.f*(1.f + mP);
            F[1]  = c0*c1 + s - p;
            F[2]  = c0*c2 + 0.5f*(s2 + p2);
            F[3]  = s;
            F[4]  = -0.5f*s2;
            F[5]  = c0*r + iv0;
            F[6]  = c1*c1 + 3.f*(s2 + p2) + 2.f;
            F[7]  = c1*c2 + 1.5f*(s3 - p3);
            F[8]  = -s;
            F[9]  = -2.f*s2;
            F[10] = s3 + (s + sn);
            F[11] = c1*r + iv1;
            F[12] = c2*c2 + 1.25f*(s2*s2 + p2*p2) + gt*gt*mP;
            F[13] = -0.5f*s2;
            F[14] = -s3 - gt*mP;
            F[15] = c2*r;
        }
        {   // bwd pieces, step t = 63 - it  (t in 33..63)
            const int t = 63 - it;
            const float c0 = cfp[3*t], c1 = cfp[3*t+1], c2 = cfp[3*t+2];
            const float r  = rlp[t];
            const float s  = (t < 63) ? slp[t] : 0.f;
            const float p  = slp[t-1];
            const float pp = slp[t-2];
            const float mSb  = (t < 63) ? 1.f : 0.f;
            const float mCNb = (t < 62) ? 1.f : 0.f;
            const float s2 = s*s, s3 = s2*s, p2 = p*p, p3 = p2*p, gt = p + s;
            G[0]  = c2*c2 + 1.25f*(s2*s2 + p2*p2) + gt*gt*mSb;
            G[1]  = c1*c2 + 1.5f*(s3 - p3);
            G[2]  = c0*c2 + 0.5f*(s2 + p2);
            G[3]  = p3 + (p + s)*mSb;
            G[4]  = -0.5f*p2;
            G[5]  = c2*r;
            G[6]  = c1*c1 + 3.f*(s2 + p2) + mCNb + 1.f;
            G[7]  = c0*c1 + s - p;
            G[8]  = -p3 - (pp + p);
            G[9]  = -2.f*p2;
            G[10] = p;
            G[11] = c1*r;
            G[12] = c0*c0 + 2.f*(mSb + 1.f);
            G[13] = -0.5f*p2;
            G[14] = -p;
            G[15] = c0*r;
        }
        float2* dst = (float2*)wsBP + ((size_t)w * BP_PER_W + (size_t)it * 16) * 32 + pr;
        #pragma unroll
        for (int k = 0; k < 16; ++k) dst[(size_t)k * 32] = make_float2(F[k], G[k]);
    }

    if (tid < 32) {
        const int pr = tid;
        const float* cfp = cf + pr * 193;
        const float* slp = sl + pr * 65;
        const float* rlp = rl + pr * 65;
        const float pA = slp[30], sA = slp[31], snA = slp[32];
        const float sB = slp[32], pB = sA;
        const float c0A = cfp[93], c1A = cfp[94], c2A = cfp[95];
        const float c0B = cfp[96], c1B = cfp[97], c2B = cfp[98];
        const float rA = rlp[31], rB = rlp[32];
        const float sA2 = sA*sA, sA3 = sA2*sA, pA2 = pA*pA, pA3 = pA2*pA;
        const float sB2 = sB*sB, sB3 = sB2*sB, pB2 = pB*pB, pB3 = pB2*pB;
        float m[27];
        m[0]  = c0A*c0A + 4.f;
        m[1]  = c0A*c1A + sA - pA;
        m[2]  = c0A*c2A + 0.5f*(sA2 + pA2);
        m[3]  = -2.f;
        m[4]  = sA;
        m[5]  = -0.5f*sA2;
        m[6]  = c1A*c1A + 3.f*(sA2 + pA2) + 2.f;
        m[7]  = c1A*c2A + 1.5f*(sA3 - pA3);
        m[8]  = -sA;
        m[9]  = -2.f*sA2;
        m[10] = sA3 + (sA + snA);
        m[11] = c2A*c2A + 1.25f*(sA2*sA2 + pA2*pA2) + (pA + sA)*(pA + sA);
        m[12] = -0.5f*sA2;
        m[13] = -sA3 - (pA + sA);
        m[14] = 0.f;
        m[15] = c0B*c0B + 4.f;
        m[16] = c0B*c1B + sB - pB;
        m[17] = c0B*c2B + 0.5f*(sB2 + pB2);
        m[18] = c1B*c1B + 3.f*(sB2 + pB2) + 2.f;
        m[19] = c1B*c2B + 1.5f*(sB3 - pB3);
        m[20] = c2B*c2B + 1.25f*(sB2*sB2 + pB2*pB2) + (pB + sB)*(pB + sB);
        m[21] = c0A*rA; m[22] = c1A*rA; m[23] = c2A*rA;
        m[24] = c0B*rB; m[25] = c1B*rB; m[26] = c2B*rB;
        #pragma unroll
        for (int k = 0; k < 27; ++k) midl[k * 32 + pr] = m[k];
    }

    __syncthreads();   // BP stores drained (vmcnt 0 before barrier); MID visible

    // ---------------- Phase 1: serial twisted solve (wave 0 only) ----------------
    if (tid < 64) {
        const int l     = tid;
        const int pair  = l >> 1;
        const int chain = l & 1;
        const float cA  = chain ? 0.f : -2.f;
        const float cB  = chain ? -2.f : 0.f;

        const float* __restrict__ bp = wsBP + (size_t)w * BP_PER_W * 64 + l;
        float* __restrict__ ln = wsL  + (size_t)w * L_PER_W * 64 + l;
        float* __restrict__ xq = wsXq + (size_t)w * XQ_PER_W * 64 + l;

#define SBP(it, k) bp[(size_t)((it) * 16 + (k)) * 64]
#define SL(i)      ln[(size_t)(i) * 64]
#define SXQ(q)     xq[(size_t)(q) * 64]

        float W11=0,W12=0,W13=0,W14=0,W15=0,W16=0;
        float W22=0,W23=0,W24=0,W25=0,W26=0;
        float W33=0,W34=0,W35=0,W36=0;
        float W44=0,W45=0,W46=0;
        float W55=0,W56=0;
        float W66=0;
        float y1=0,y2=0,y3=0,y4=0,y5=0,y6=0;

#define CHOL_BODY(b0, b1, b2, b3, b4, b5, b6, rvv)                             \
        const float t0_ = (b0) - (W11*W11 + W22*W22 + W33*W33 +                \
                                  W44*W44 + W55*W55 + W66*W66);                \
        const float di_ = rsqrtf(t0_);                                         \
        const float u1_ = (b1) - (W11*W12 + W22*W23 + W33*W34 +                \
                                  W44*W45 + W55*W56);                          \
        const float u2_ = (b2) - (W11*W13 + W22*W24 + W33*W35 + W44*W46);      \
        const float u3_ = (b3) - (W11*W14 + W22*W25 + W33*W36);                \
        const float u4_ = (b4) - (W11*W15 + W22*W26);                          \
        const float u5_ = (b5) - (W11*W16);                                    \
        const float u6_ = (b6);                                                \
        const float yj_ = ((rvv) - (W11*y1 + W22*y2 + W33*y3 +                 \
                                    W44*y4 + W55*y5 + W66*y6)) * di_;          \
        const float n1_ = u1_*di_, n2_ = u2_*di_, n3_ = u3_*di_;               \
        const float n4_ = u4_*di_, n5_ = u5_*di_, n6_ = u6_*di_;

#define CHOL_SHIFT()                                                           \
        W66 = W56;                                                             \
        W55 = W45; W56 = W46;                                                  \
        W44 = W34; W45 = W35; W46 = W36;                                       \
        W33 = W23; W34 = W24; W35 = W25; W36 = W26;                            \
        W22 = W12; W23 = W13; W24 = W14; W25 = W15; W26 = W16;                 \
        W11 = n1_; W12 = n2_; W13 = n3_; W14 = n4_; W15 = n5_; W16 = n6_;      \
        y6 = y5; y5 = y4; y4 = y3; y3 = y2; y2 = y1; y1 = yj_;

#define CHOL_COL(q, b0, b1, b2, b3, b4, b5, b6, rvv)                           \
    {                                                                          \
        CHOL_BODY(b0, b1, b2, b3, b4, b5, b6, rvv)                             \
        SL((q)*8 + 0) = di_; SL((q)*8 + 1) = n1_; SL((q)*8 + 2) = n2_;         \
        SL((q)*8 + 3) = n3_; SL((q)*8 + 4) = n4_; SL((q)*8 + 5) = n5_;         \
        SL((q)*8 + 6) = n6_; SL((q)*8 + 7) = yj_;                              \
        CHOL_SHIFT()                                                           \
    }

#define CHOL_COL_CAP(P, b0, b1, b2, b3, b4, b5, b6, rvv)                       \
    {                                                                          \
        CHOL_BODY(b0, b1, b2, b3, b4, b5, b6, rvv)                             \
        P##d = di_; P##1 = n1_; P##2 = n2_; P##3 = n3_;                        \
        P##4 = n4_; P##5 = n5_; P##6 = n6_; P##y = yj_;                        \
        CHOL_SHIFT()                                                           \
    }

        float C0 = SBP(0,0),  C1 = SBP(0,1),  C2 = SBP(0,2),  C3 = SBP(0,3);
        float C4 = SBP(0,4),  C5 = SBP(0,5),  C6 = SBP(0,6),  C7 = SBP(0,7);
        float C8 = SBP(0,8),  C9 = SBP(0,9),  C10 = SBP(0,10), C11 = SBP(0,11);
        float C12 = SBP(0,12), C13 = SBP(0,13), C14 = SBP(0,14), C15 = SBP(0,15);
        float D0 = SBP(1,0),  D1 = SBP(1,1),  D2 = SBP(1,2),  D3 = SBP(1,3);
        float D4 = SBP(1,4),  D5 = SBP(1,5),  D6 = SBP(1,6),  D7 = SBP(1,7);
        float D8 = SBP(1,8),  D9 = SBP(1,9),  D10 = SBP(1,10), D11 = SBP(1,11);
        float D12 = SBP(1,12), D13 = SBP(1,13), D14 = SBP(1,14), D15 = SBP(1,15);

        for (int it = 0; it <= 29; ++it) {
            float N0=0,N1=0,N2=0,N3=0,N4=0,N5=0,N6=0,N7=0;
            float N8=0,N9=0,N10=0,N11=0,N12=0,N13=0,N14=0,N15=0;
            if (it + 2 <= 30) {
                N0  = SBP(it+2,0);  N1  = SBP(it+2,1);  N2  = SBP(it+2,2);  N3  = SBP(it+2,3);
                N4  = SBP(it+2,4);  N5  = SBP(it+2,5);  N6  = SBP(it+2,6);  N7  = SBP(it+2,7);
                N8  = SBP(it+2,8);  N9  = SBP(it+2,9);  N10 = SBP(it+2,10); N11 = SBP(it+2,11);
                N12 = SBP(it+2,12); N13 = SBP(it+2,13); N14 = SBP(it+2,14); N15 = SBP(it+2,15);
            }
            const int q0 = 3 * it;
            CHOL_COL(q0 + 0, C0,  C1,  C2,  cA,   C3,  C4,  0.f,  C5);
            CHOL_COL(q0 + 1, C6,  C7,  C8,  C9,   C10, 0.f, -1.f, C11);
            CHOL_COL(q0 + 2, C12, C13, C14, cB,   0.f, 0.f, 0.f,  C15);
            C0=D0; C1=D1; C2=D2; C3=D3; C4=D4; C5=D5; C6=D6; C7=D7;
            C8=D8; C9=D9; C10=D10; C11=D11; C12=D12; C13=D13; C14=D14; C15=D15;
            D0=N0; D1=N1; D2=N2; D3=N3; D4=N4; D5=N5; D6=N6; D7=N7;
            D8=N8; D9=N9; D10=N10; D11=N11; D12=N12; D13=N13; D14=N14; D15=N15;
        }

#define DECL8(P) float P##d = 0, P##1 = 0, P##2 = 0, P##3 = 0,                 \
                       P##4 = 0, P##5 = 0, P##6 = 0, P##y = 0;
#define LOAD8(P, q) { const size_t o8 = (size_t)(q)*8;                         \
        P##d = SL(o8 + 0); P##1 = SL(o8 + 1); P##2 = SL(o8 + 2);               \
        P##3 = SL(o8 + 3); P##4 = SL(o8 + 4); P##5 = SL(o8 + 5);               \
        P##6 = SL(o8 + 6); P##y = SL(o8 + 7); }

        DECL8(PA) DECL8(PB) DECL8(PC)
        DECL8(QA) DECL8(QB) DECL8(QC)
        DECL8(RA) DECL8(RB) DECL8(RC)

        // peel it=30: capture q90..92 in registers (no store->reload seam)
        CHOL_COL_CAP(PA, C0,  C1,  C2,  cA,   C3,  C4,  0.f,  C5);
        CHOL_COL_CAP(PB, C6,  C7,  C8,  C9,   C10, 0.f, -1.f, C11);
        CHOL_COL_CAP(PC, C12, C13, C14, cB,   0.f, 0.f, 0.f,  C15);

        LOAD8(QC, 89) LOAD8(QB, 88) LOAD8(QA, 87)
        LOAD8(RC, 86) LOAD8(RB, 85) LOAD8(RA, 84)

        // ---- window exchange between lane pairs ----
        const float R11=__shfl_xor(W11,1), R12=__shfl_xor(W12,1), R13=__shfl_xor(W13,1);
        const float R14=__shfl_xor(W14,1), R15=__shfl_xor(W15,1), R16=__shfl_xor(W16,1);
        const float R22=__shfl_xor(W22,1), R23=__shfl_xor(W23,1), R24=__shfl_xor(W24,1);
        const float R25=__shfl_xor(W25,1), R26=__shfl_xor(W26,1);
        const float R33=__shfl_xor(W33,1), R34=__shfl_xor(W34,1), R35=__shfl_xor(W35,1);
        const float R36=__shfl_xor(W36,1);
        const float R44=__shfl_xor(W44,1), R45=__shfl_xor(W45,1), R46=__shfl_xor(W46,1);
        const float R55=__shfl_xor(W55,1), R56=__shfl_xor(W56,1);
        const float R66=__shfl_xor(W66,1);
        const float r1=__shfl_xor(y1,1), r2=__shfl_xor(y2,1), r3=__shfl_xor(y3,1);
        const float r4=__shfl_xor(y4,1), r5=__shfl_xor(y5,1), r6=__shfl_xor(y6,1);

        float xm0=0, xm1=0, xm2=0, xm3=0, xm4=0, xm5=0;
        if (chain == 0) {
            const float* __restrict__ md = midl + pair;
            float S00 = md[0*32],  S10 = md[1*32],  S20 = md[2*32];
            float S30 = md[3*32],  S40 = md[4*32],  S50 = md[5*32];
            float S11 = md[6*32],  S21 = md[7*32],  S31 = md[8*32];
            float S41 = md[9*32],  S51 = md[10*32], S22 = md[11*32];
            float S32 = md[12*32], S42 = md[13*32], S52 = md[14*32];
            float S33 = md[15*32], S43 = md[16*32], S53 = md[17*32];
            float S44 = md[18*32], S54 = md[19*32], S55 = md[20*32];
            float fm0 = md[21*32], fm1 = md[22*32], fm2 = md[23*32];
            float fm3 = md[24*32], fm4 = md[25*32], fm5 = md[26*32];

            S00 -= W11*W11 + W22*W22 + W33*W33 + W44*W44 + W55*W55 + W66*W66;
            S10 -= W12*W11 + W23*W22 + W34*W33 + W45*W44 + W56*W55;
            S11 -= W12*W12 + W23*W23 + W34*W34 + W45*W45 + W56*W56;
            S20 -= W13*W11 + W24*W22 + W35*W33 + W46*W44;
            S21 -= W13*W12 + W24*W23 + W35*W34 + W46*W45;
            S22 -= W13*W13 + W24*W24 + W35*W35 + W46*W46;
            S30 -= W14*W11 + W25*W22 + W36*W33;
            S31 -= W14*W12 + W25*W23 + W36*W34;
            S32 -= W14*W13 + W25*W24 + W36*W35;
            S33 -= W14*W14 + W25*W25 + W36*W36;
            S40 -= W15*W11 + W26*W22;
            S41 -= W15*W12 + W26*W23;
            S42 -= W15*W13 + W26*W24;
            S43 -= W15*W14 + W26*W25;
            S44 -= W15*W15 + W26*W26;
            S50 -= W16*W11;
            S51 -= W16*W12;
            S52 -= W16*W13;
            S53 -= W16*W14;
            S54 -= W16*W15;
            S55 -= W16*W16;

            S00 -= R16*R16;
            S10 -= R15*R16;
            S11 -= R15*R15 + R26*R26;
            S20 -= R14*R16;
            S21 -= R14*R15 + R25*R26;
            S22 -= R14*R14 + R25*R25 + R36*R36;
            S30 -= R13*R16;
            S31 -= R13*R15 + R24*R26;
            S32 -= R13*R14 + R24*R25 + R35*R36;
            S33 -= R13*R13 + R24*R24 + R35*R35 + R46*R46;
            S40 -= R12*R16;
            S41 -= R12*R15 + R23*R26;
            S42 -= R12*R14 + R23*R25 + R34*R36;
            S43 -= R12*R13 + R23*R24 + R34*R35 + R45*R46;
            S44 -= R12*R12 + R23*R23 + R34*R34 + R45*R45 + R56*R56;
            S50 -= R11*R16;
            S51 -= R11*R15 + R22*R26;
            S52 -= R11*R14 + R22*R25 + R33*R36;
            S53 -= R11*R13 + R22*R24 + R33*R35 + R44*R46;
            S54 -= R11*R12 + R22*R23 + R33*R34 + R44*R45 + R55*R56;
            S55 -= R11*R11 + R22*R22 + R33*R33 + R44*R44 + R55*R55 + R66*R66;

            fm0 -= (W11*y1 + W22*y2 + W33*y3 + W44*y4 + W55*y5 + W66*y6) + (R16*r1);
            fm1 -= (W12*y1 + W23*y2 + W34*y3 + W45*y4 + W56*y5) + (R15*r1 + R26*r2);
            fm2 -= (W13*y1 + W24*y2 + W35*y3 + W46*y4) + (R14*r1 + R25*r2 + R36*r3);
            fm3 -= (W14*y1 + W25*y2 + W36*y3) + (R13*r1 + R24*r2 + R35*r3 + R46*r4);
            fm4 -= (W15*y1 + W26*y2) + (R12*r1 + R23*r2 + R34*r3 + R45*r4 + R56*r5);
            fm5 -= (W16*y1) + (R11*r1 + R22*r2 + R33*r3 + R44*r4 + R55*r5 + R66*r6);

            const float md0 = rsqrtf(S00);
            const float M10 = S10*md0, M20 = S20*md0, M30 = S30*md0,
                        M40 = S40*md0, M50 = S50*md0;
            const float zm0 = fm0*md0;
            const float md1 = rsqrtf(S11 - M10*M10);
            const float M21 = (S21 - M20*M10)*md1;
            const float M31 = (S31 - M30*M10)*md1;
            const float M41 = (S41 - M40*M10)*md1;
            const float M51 = (S51 - M50*M10)*md1;
            const float zm1 = (fm1 - M10*zm0)*md1;
            const float md2 = rsqrtf(S22 - M20*M20 - M21*M21);
            const float M32 = (S32 - M30*M20 - M31*M21)*md2;
            const float M42 = (S42 - M40*M20 - M41*M21)*md2;
            const float M52 = (S52 - M50*M20 - M51*M21)*md2;
            const float zm2 = (fm2 - M20*zm0 - M21*zm1)*md2;
            const float md3 = rsqrtf(S33 - M30*M30 - M31*M31 - M32*M32);
            const float M43 = (S43 - M40*M30 - M41*M31 - M42*M32)*md3;
            const float M53 = (S53 - M50*M30 - M51*M31 - M52*M32)*md3;
            const float zm3 = (fm3 - M30*zm0 - M31*zm1 - M32*zm2)*md3;
            const float md4 = rsqrtf(S44 - M40*M40 - M41*M41 - M42*M42 - M43*M43);
            const float M54 = (S54 - M50*M40 - M51*M41 - M52*M42 - M53*M43)*md4;
            const float zm4 = (fm4 - M40*zm0 - M41*zm1 - M42*zm2 - M43*zm3)*md4;
            const float md5 = rsqrtf(S55 - M50*M50 - M51*M51 - M52*M52 - M53*M53 - M54*M54);
            const float zm5 = (fm5 - M50*zm0 - M51*zm1 - M52*zm2 - M53*zm3 - M54*zm4)*md5;

            xm5 = zm5*md5;
            xm4 = (zm4 - M54*xm5)*md4;
            xm3 = (zm3 - M43*xm4 - M53*xm5)*md3;
            xm2 = (zm2 - M32*xm3 - M42*xm4 - M52*xm5)*md2;
            xm1 = (zm1 - M21*xm2 - M31*xm3 - M41*xm4 - M51*xm5)*md1;
            xm0 = (zm0 - M10*xm1 - M20*xm2 - M30*xm3 - M40*xm4 - M50*xm5)*md0;

            mxl[0*32 + pair] = xm0; mxl[1*32 + pair] = xm1; mxl[2*32 + pair] = xm2;
            mxl[3*32 + pair] = xm3; mxl[4*32 + pair] = xm4; mxl[5*32 + pair] = xm5;
        }

        const float g0 = __shfl_xor(xm0, 1), g1 = __shfl_xor(xm1, 1);
        const float g2 = __shfl_xor(xm2, 1), g3 = __shfl_xor(xm3, 1);
        const float g4 = __shfl_xor(xm4, 1), g5 = __shfl_xor(xm5, 1);

        float x1 = chain ? g5 : xm0;
        float x2 = chain ? g4 : xm1;
        float x3 = chain ? g3 : xm2;
        float x4 = chain ? g2 : xm3;
        float x5 = chain ? g1 : xm4;
        float x6 = chain ? g0 : xm5;

#define BSUB(P, q) {                                                           \
        const float rest = (P##6*x6 + P##5*x5) + (P##4*x4 + P##3*x3) + P##2*x2;\
        const float xr = ((P##y - rest) - P##1*x1) * P##d;                     \
        SXQ(q) = xr;                                                           \
        x6 = x5; x5 = x4; x4 = x3; x3 = x2; x2 = x1; x1 = xr; }

        for (int it2 = 0; it2 < 31; it2 += 3) {
            {   const int st = 30 - it2;
                BSUB(PC, 3*st + 2) BSUB(PB, 3*st + 1) BSUB(PA, 3*st)
                if (st - 3 >= 0) { LOAD8(PC, 3*(st-3) + 2) LOAD8(PB, 3*(st-3) + 1) LOAD8(PA, 3*(st-3)) }
            }
            {   const int st = 29 - it2;
                if (st >= 0) {
                    BSUB(QC, 3*st + 2) BSUB(QB, 3*st + 1) BSUB(QA, 3*st)
                    if (st - 3 >= 0) { LOAD8(QC, 3*(st-3) + 2) LOAD8(QB, 3*(st-3) + 1) LOAD8(QA, 3*(st-3)) }
                }
            }
            {   const int st = 28 - it2;
                if (st >= 0) {
                    BSUB(RC, 3*st + 2) BSUB(RB, 3*st + 1) BSUB(RA, 3*st)
                    if (st - 3 >= 0) { LOAD8(RC, 3*(st-3) + 2) LOAD8(RB, 3*(st-3) + 1) LOAD8(RA, 3*(st-3)) }
                }
            }
        }

#undef SBP
#undef SL
#undef SXQ
#undef CHOL_BODY
#undef CHOL_SHIFT
#undef CHOL_COL
#undef CHOL_COL_CAP
#undef DECL8
#undef LOAD8
#undef BSUB
    }

    __syncthreads();   // XQ stores drained; mxl visible

    // ---------------- Phase 2: output mapping (coalesced writes) ----------------
    {
        const float* __restrict__ xg = wsXq + (size_t)w * XQ_PER_W * 64;
        for (int idx = tid; idx < 32 * 192; idx += 1024) {
            const int bl = idx / 192;      // pair 0..31
            const int j  = idx - bl * 192;
            float v;
            if (j < 93)      v = xg[(size_t)j * 64 + 2 * bl];
            else if (j > 98) v = xg[(size_t)(191 - j) * 64 + 2 * bl + 1];
            else             v = mxl[(j - 93) * 32 + bl];
            out[(size_t)w * 6144 + idx] = v;
        }
    }
}

// ============================================================================
// Fallback (round-1 kernel, known-pass): used only if ws is too small
// ============================================================================
__global__ __launch_bounds__(64, 1)
void ode_banded_solve(const float* __restrict__ coeffs,
                      const float* __restrict__ rhs,
                      const float* __restrict__ iv_rhs,
                      const float* __restrict__ steps,
                      float* __restrict__ out)
{
    const int b    = blockIdx.x;
    const int lane = threadIdx.x;

    __shared__ float band[NV * BW];
    __shared__ float rv[NV];
    __shared__ float stp[NT + 1];

    for (int i = lane; i < NV * BW; i += 64) band[i] = 0.0f;
    if (lane < NT) stp[lane] = steps[b * NT + lane];
    __syncthreads();

    {
        const int st = lane;
        const float c0 = coeffs[b * NV + st * 3 + 0];
        const float c1 = coeffs[b * NV + st * 3 + 1];
        const float c2 = coeffs[b * NV + st * 3 + 2];
        const float r  = rhs[b * NS + st];
        const float reg = (st < 2) ? 1.0f : 0.0f;
        atomicAdd(&band[(3 * st + 0) * BW + 0], c0 * c0 + reg);
        atomicAdd(&band[(3 * st + 1) * BW + 0], c1 * c1 + reg);
        atomicAdd(&band[(3 * st + 2) * BW + 0], c2 * c2);
        atomicAdd(&band[(3 * st + 1) * BW + 1], c1 * c0);
        atomicAdd(&band[(3 * st + 2) * BW + 1], c2 * c1);
        atomicAdd(&band[(3 * st + 2) * BW + 2], c2 * c0);
        float b0 = c0 * r, b1 = c1 * r, b2v = c2 * r;
        if (st < 2) {
            b0 += iv_rhs[b * 4 + st * 2 + 0];
            b1 += iv_rhs[b * 4 + st * 2 + 1];
        }
        rv[3 * st + 0] = b0;
        rv[3 * st + 1] = b1;
        rv[3 * st + 2] = b2v;
    }

    for (int t = lane; t < NC; t += 64) {
        int   cols[4];
        float vals[4];
        int   cnt;
        if (t < 126) {
            const int st = t >> 1, i = t & 1;
            const float s = stp[st];
            if (i == 0) {
                cols[0] = 3 * st + 0; vals[0] = 1.0f;
                cols[1] = 3 * st + 1; vals[1] = s;
                cols[2] = 3 * st + 2; vals[2] = 0.5f * s * s;
                cols[3] = 3 * st + 3; vals[3] = -1.0f;
                cnt = 4;
            } else {
                cols[0] = 3 * st + 1; vals[0] = s;
                cols[1] = 3 * st + 2; vals[1] = s * s;
                cols[2] = 3 * st + 4; vals[2] = -s;
                cnt = 3;
            }
        } else if (t < 188) {
            const int st = t - 126 + 1;
            const float cp = stp[st - 1] + stp[st];
            cols[0] = 3 * st - 2; vals[0] = -1.0f;
            cols[1] = 3 * st + 2; vals[1] = -cp;
            cols[2] = 3 * st + 4; vals[2] = 1.0f;
            cnt = 3;
        } else {
            const int tt = t - 188;
            const int st = tt >> 1, i = tt & 1;
            const float s = stp[st];
            if (i == 0) {
                cols[0] = 3 * st + 0; vals[0] = -1.0f;
                cols[1] = 3 * st + 3; vals[1] = 1.0f;
                cols[2] = 3 * st + 4; vals[2] = -s;
                cols[3] = 3 * st + 5; vals[3] = 0.5f * s * s;
                cnt = 4;
            } else {
                cols[0] = 3 * st + 1; vals[0] = s;
                cols[1] = 3 * st + 4; vals[1] = -s;
                cols[2] = 3 * st + 5; vals[2] = s * s;
                cnt = 3;
            }
        }
        for (int a = 0; a < cnt; ++a)
            for (int b2 = 0; b2 <= a; ++b2)
                atomicAdd(&band[cols[a] * BW + (cols[a] - cols[b2])],
                          vals[a] * vals[b2]);
    }
    __syncthreads();

    int pa = 0, pb = 0;
    {
        int idx = 0;
        for (int aa = 1; aa <= 6; ++aa)
            for (int bb = 1; bb <= aa; ++bb) {
                if (idx == lane) { pa = aa; pb = bb; }
                ++idx;
            }
    }
    const int sk = lane - 20;

    for (int j = 0; j < NV; ++j) {
        const int m = (NV - 1 - j < 6) ? (NV - 1 - j) : 6;
        const float diag = band[j * BW];
        const float d    = sqrtf(diag);
        const float dinv = 1.0f / d;

        const bool doU = (lane < 21) && (pa <= m);
        const bool doS = (lane >= 21) && (lane <= 26) && (sk <= m);
        float ca = 0.0f, cb = 0.0f, cs = 0.0f;
        if (doU) { ca = band[(j + pa) * BW + pa]; cb = band[(j + pb) * BW + pb]; }
        if (doS) { cs = band[(j + sk) * BW + sk]; }
        __syncthreads();

        if (lane == 0) band[j * BW] = d;
        if (doU) band[(j + pa) * BW + (pa - pb)] -= ca * cb * (dinv * dinv);
        if (doS) band[(j + sk) * BW + sk] = cs * dinv;
        __syncthreads();
    }

    for (int j = 0; j < NV; ++j) {
        const int m = (NV - 1 - j < 6) ? (NV - 1 - j) : 6;
        const float yj = rv[j] / band[j * BW];
        const bool doK = (lane >= 1) && (lane <= m);
        float sub = 0.0f, rj = 0.0f;
        if (doK) { sub = band[(j + lane) * BW + lane] * yj; rj = rv[j + lane]; }
        __syncthreads();
        if (lane == 0) rv[j] = yj;
        if (doK) rv[j + lane] = rj - sub;
        __syncthreads();
    }

    for (int j = NV - 1; j >= 0; --j) {
        const int m = (j < 6) ? j : 6;
        const float xj = rv[j] / band[j * BW];
        const bool doK = (lane >= 1) && (lane <= m);
        float sub = 0.0f, rj = 0.0f;
        if (doK) { sub = band[j * BW + lane] * xj; rj = rv[j - lane]; }
        __syncthreads();
        if (lane == 0) rv[j] = xj;
        if (doK) rv[j - lane] = rj - sub;
        __syncthreads();
    }

    for (int i = lane; i < NV; i += 64)
        out[b * NV + i] = rv[i];
}

extern "C" void kernel_launch(void* const* d_in, const int* in_sizes, int n_in,
                              void* d_out, int out_size, void* d_ws, size_t ws_size,
                              hipStream_t stream)
{
    const float* coeffs = (const float*)d_in[0];   // 1024*64*3
    const float* rhs    = (const float*)d_in[1];   // 1024*64
    const float* iv_rhs = (const float*)d_in[2];   // 1024*2*2
    const float* steps  = (const float*)d_in[3];   // 1024*63
    float* out = (float*)d_out;                    // 1024*192

    const size_t BPf = (size_t)NW * BP_PER_W * 64;
    const size_t Lf  = (size_t)NW * L_PER_W * 64;
    const size_t XQf = (size_t)NW * XQ_PER_W * 64;
    const size_t need = (BPf + Lf + XQf) * sizeof(float);   // ~10.9 MB

    if (ws_size >= need) {
        float* wsBP = (float*)d_ws;
        float* wsL  = wsBP + BPf;
        float* wsXq = wsL  + Lf;
        ode_mega<<<dim3(NW), dim3(1024), 0, stream>>>(coeffs, rhs, steps, iv_rhs,
                                                      wsBP, wsL, wsXq, out);
    } else {
        ode_banded_solve<<<dim3(NB), dim3(64), 0, stream>>>(coeffs, rhs, iv_rhs,
                                                            steps, out);
    }
}

// Round 11
// 41.079 us; speedup vs baseline: 3.0653x; 1.0785x over previous
//
#include <hip/hip_runtime.h>
#include <math.h>

// Problem constants (static config)
#define NB 1024
#define NS 64
#define NT 63
#define NV 192
#define BW 7
#define NC 314

#define NBLK 64             // blocks; each handles 16 batches (32 lanes = 2 chains)
#define PB 16               // batches (pairs) per block
#define BP_SLOTS (31*16)    // per-block BP slots, x32 lanes each

// ============================================================================
// ode_mega2: single-kernel pipeline, 64 blocks x 256 threads.
// Block w = batches w*16..w*16+15.
// Phase 0 (256 thr): stage inputs->LDS; BP band pieces->global (L2-local);
//                    middle-block pre-Schur->LDS.
// Phase 1 (lanes 0..31): lane-paired twisted Cholesky + backsub (verified
//                    r9/r10 math); L and XQ live in LDS (ds ops -> lgkmcnt;
//                    vmcnt holds only BP prefetch loads -> clean pipeline).
// Phase 2 (256 thr): map q-indexed x to out (coalesced writes).
// 256-thread block + launch_bounds(256,1) => full VGPR budget (no spill).
// ============================================================================
__global__ __launch_bounds__(256, 1)
void ode_mega2(const float* __restrict__ coeffs,
               const float* __restrict__ rhs,
               const float* __restrict__ steps,
               const float* __restrict__ iv_rhs,
               float* __restrict__ wsBP,
               float* __restrict__ out)
{
    const int w   = blockIdx.x;     // 0..63
    const int tid = threadIdx.x;

    __shared__ float cf[PB * 193];
    __shared__ float sl[PB * 65];
    __shared__ float rl[PB * 65];
    __shared__ float il[PB * 4];
    __shared__ float midl[27 * PB];
    __shared__ float mxl[6 * PB];
    __shared__ float lql[93 * 8 * 32];  // 95 KB
    __shared__ float xql[93 * 32];

    // ---------------- Phase 0a: stage inputs (coalesced) ----------------
    for (int idx = tid; idx < PB * 192; idx += 256) {
        const int b = idx / 192, j = idx - 192 * b;
        cf[b * 193 + j] = coeffs[(size_t)w * (PB * 192) + idx];
    }
    for (int idx = tid; idx < PB * 63; idx += 256) {
        const int b = idx / 63, j = idx - 63 * b;
        sl[b * 65 + j] = steps[(size_t)w * (PB * 63) + idx];
    }
    for (int idx = tid; idx < PB * 64; idx += 256) {
        const int b = idx >> 6, j = idx & 63;
        rl[b * 65 + j] = rhs[(size_t)w * (PB * 64) + idx];
    }
    if (tid < PB * 4) il[tid] = iv_rhs[(size_t)w * (PB * 4) + tid];
    __syncthreads();

    // ---------------- Phase 0b: band pieces + middle pre-Schur ----------------
    for (int idx = tid; idx < 31 * PB; idx += 256) {
        const int it = idx >> 4;
        const int pr = idx & 15;
        const float* cfp = cf + pr * 193;
        const float* slp = sl + pr * 65;
        const float* rlp = rl + pr * 65;

        float F[16], G[16];
        {   // fwd pieces, step t = it
            const int t = it;
            const float c0 = cfp[3*t], c1 = cfp[3*t+1], c2 = cfp[3*t+2];
            const float r  = rlp[t];
            const float p  = (t >= 1) ? slp[t-1] : 0.f;
            const float s  = slp[t];
            const float sn = slp[t+1];
            const float mP = (t >= 1) ? 1.f : 0.f;
            const float rg = (t < 2) ? 1.f : 0.f;
            float iv0 = 0.f, iv1 = 0.f;
            if (t < 2) { iv0 = il[pr*4 + t*2]; iv1 = il[pr*4 + t*2 + 1]; }
            const float s2 = s*s, s3 = s2*s, p2 = p*p, p3 = p2*p, gt = p + s;
            F[0]  = c0*c0 + rg + 2.f*(1.f + mP);
            F[1]  = c0*c1 + s - p;
            F[2]  = c0*c2 + 0.5f*(s2 + p2);
            F[3]  = s;
            F[4]  = -0.5f*s2;
            F[5]  = c0*r + iv0;
            F[6]  = c1*c1 + 3.f*(s2 + p2) + 2.f;
            F[7]  = c1*c2 + 1.5f*(s3 - p3);
            F[8]  = -s;
            F[9]  = -2.f*s2;
            F[10] = s3 + (s + sn);
            F[11] = c1*r + iv1;
            F[12] = c2*c2 + 1.25f*(s2*s2 + p2*p2) + gt*gt*mP;
            F[13] = -0.5f*s2;
            F[14] = -s3 - gt*mP;
            F[15] = c2*r;
        }
        {   // bwd pieces, step t = 63 - it
            const int t = 63 - it;
            const float c0 = cfp[3*t], c1 = cfp[3*t+1], c2 = cfp[3*t+2];
            const float r  = rlp[t];
            const float s  = (t < 63) ? slp[t] : 0.f;
            const float p  = slp[t-1];
            const float pp = slp[t-2];
            const float mSb  = (t < 63) ? 1.f : 0.f;
            const float mCNb = (t < 62) ? 1.f : 0.f;
            const float s2 = s*s, s3 = s2*s, p2 = p*p, p3 = p2*p, gt = p + s;
            G[0]  = c2*c2 + 1.25f*(s2*s2 + p2*p2) + gt*gt*mSb;
            G[1]  = c1*c2 + 1.5f*(s3 - p3);
            G[2]  = c0*c2 + 0.5f*(s2 + p2);
            G[3]  = p3 + (p + s)*mSb;
            G[4]  = -0.5f*p2;
            G[5]  = c2*r;
            G[6]  = c1*c1 + 3.f*(s2 + p2) + mCNb + 1.f;
            G[7]  = c0*c1 + s - p;
            G[8]  = -p3 - (pp + p);
            G[9]  = -2.f*p2;
            G[10] = p;
            G[11] = c1*r;
            G[12] = c0*c0 + 2.f*(mSb + 1.f);
            G[13] = -0.5f*p2;
            G[14] = -p;
            G[15] = c0*r;
        }
        float2* dst = (float2*)wsBP + (size_t)w * (BP_SLOTS * 16)
                                    + (size_t)it * 256 + pr;
        #pragma unroll
        for (int k = 0; k < 16; ++k) dst[(size_t)k * 16] = make_float2(F[k], G[k]);
    }

    if (tid < PB) {
        const int pr = tid;
        const float* cfp = cf + pr * 193;
        const float* slp = sl + pr * 65;
        const float* rlp = rl + pr * 65;
        const float pA = slp[30], sA = slp[31], snA = slp[32];
        const float sB = slp[32], pB2_ = sA;
        const float c0A = cfp[93], c1A = cfp[94], c2A = cfp[95];
        const float c0B = cfp[96], c1B = cfp[97], c2B = cfp[98];
        const float rA = rlp[31], rB = rlp[32];
        const float sA2 = sA*sA, sA3 = sA2*sA, pA2 = pA*pA, pA3 = pA2*pA;
        const float sB2 = sB*sB, sB3 = sB2*sB, pB2 = pB2_*pB2_, pB3 = pB2*pB2_;
        float m[27];
        m[0]  = c0A*c0A + 4.f;
        m[1]  = c0A*c1A + sA - pA;
        m[2]  = c0A*c2A + 0.5f*(sA2 + pA2);
        m[3]  = -2.f;
        m[4]  = sA;
        m[5]  = -0.5f*sA2;
        m[6]  = c1A*c1A + 3.f*(sA2 + pA2) + 2.f;
        m[7]  = c1A*c2A + 1.5f*(sA3 - pA3);
        m[8]  = -sA;
        m[9]  = -2.f*sA2;
        m[10] = sA3 + (sA + snA);
        m[11] = c2A*c2A + 1.25f*(sA2*sA2 + pA2*pA2) + (pA + sA)*(pA + sA);
        m[12] = -0.5f*sA2;
        m[13] = -sA3 - (pA + sA);
        m[14] = 0.f;
        m[15] = c0B*c0B + 4.f;
        m[16] = c0B*c1B + sB - pB2_;
        m[17] = c0B*c2B + 0.5f*(sB2 + pB2);
        m[18] = c1B*c1B + 3.f*(sB2 + pB2) + 2.f;
        m[19] = c1B*c2B + 1.5f*(sB3 - pB3);
        m[20] = c2B*c2B + 1.25f*(sB2*sB2 + pB2*pB2) + (pB2_ + sB)*(pB2_ + sB);
        m[21] = c0A*rA; m[22] = c1A*rA; m[23] = c2A*rA;
        m[24] = c0B*rB; m[25] = c1B*rB; m[26] = c2B*rB;
        #pragma unroll
        for (int k = 0; k < 27; ++k) midl[k * PB + pr] = m[k];
    }

    __syncthreads();

    // ---------------- Phase 1: serial twisted solve (lanes 0..31) ----------------
    if (tid < 32) {
        const int l     = tid;
        const int pair  = l >> 1;
        const int chain = l & 1;
        const float cA  = chain ? 0.f : -2.f;
        const float cB  = chain ? -2.f : 0.f;

        const float* __restrict__ bp = wsBP + (size_t)w * (BP_SLOTS * 32) + l;

#define SBP(it, k) bp[(size_t)(((it) * 16 + (k)) * 32)]
#define SL(i)      lql[(i) * 32 + l]
#define SXQ(q)     xql[(q) * 32 + l]

        float W11=0,W12=0,W13=0,W14=0,W15=0,W16=0;
        float W22=0,W23=0,W24=0,W25=0,W26=0;
        float W33=0,W34=0,W35=0,W36=0;
        float W44=0,W45=0,W46=0;
        float W55=0,W56=0;
        float W66=0;
        float y1=0,y2=0,y3=0,y4=0,y5=0,y6=0;

#define CHOL_BODY(b0, b1, b2, b3, b4, b5, b6, rvv)                             \
        const float t0_ = (b0) - (W11*W11 + W22*W22 + W33*W33 +                \
                                  W44*W44 + W55*W55 + W66*W66);                \
        const float di_ = rsqrtf(t0_);                                         \
        const float u1_ = (b1) - (W11*W12 + W22*W23 + W33*W34 +                \
                                  W44*W45 + W55*W56);                          \
        const float u2_ = (b2) - (W11*W13 + W22*W24 + W33*W35 + W44*W46);      \
        const float u3_ = (b3) - (W11*W14 + W22*W25 + W33*W36);                \
        const float u4_ = (b4) - (W11*W15 + W22*W26);                          \
        const float u5_ = (b5) - (W11*W16);                                    \
        const float u6_ = (b6);                                                \
        const float yj_ = ((rvv) - (W11*y1 + W22*y2 + W33*y3 +                 \
                                    W44*y4 + W55*y5 + W66*y6)) * di_;          \
        const float n1_ = u1_*di_, n2_ = u2_*di_, n3_ = u3_*di_;               \
        const float n4_ = u4_*di_, n5_ = u5_*di_, n6_ = u6_*di_;

#define CHOL_SHIFT()                                                           \
        W66 = W56;                                                             \
        W55 = W45; W56 = W46;                                                  \
        W44 = W34; W45 = W35; W46 = W36;                                       \
        W33 = W23; W34 = W24; W35 = W25; W36 = W26;                            \
        W22 = W12; W23 = W13; W24 = W14; W25 = W15; W26 = W16;                 \
        W11 = n1_; W12 = n2_; W13 = n3_; W14 = n4_; W15 = n5_; W16 = n6_;      \
        y6 = y5; y5 = y4; y4 = y3; y3 = y2; y2 = y1; y1 = yj_;

#define CHOL_COL(q, b0, b1, b2, b3, b4, b5, b6, rvv)                           \
    {                                                                          \
        CHOL_BODY(b0, b1, b2, b3, b4, b5, b6, rvv)                             \
        SL((q)*8 + 0) = di_; SL((q)*8 + 1) = n1_; SL((q)*8 + 2) = n2_;         \
        SL((q)*8 + 3) = n3_; SL((q)*8 + 4) = n4_; SL((q)*8 + 5) = n5_;         \
        SL((q)*8 + 6) = n6_; SL((q)*8 + 7) = yj_;                              \
        CHOL_SHIFT()                                                           \
    }

#define CHOL_COL_CAP(P, b0, b1, b2, b3, b4, b5, b6, rvv)                       \
    {                                                                          \
        CHOL_BODY(b0, b1, b2, b3, b4, b5, b6, rvv)                             \
        P##d = di_; P##1 = n1_; P##2 = n2_; P##3 = n3_;                        \
        P##4 = n4_; P##5 = n5_; P##6 = n6_; P##y = yj_;                        \
        CHOL_SHIFT()                                                           \
    }

        float C0 = SBP(0,0),  C1 = SBP(0,1),  C2 = SBP(0,2),  C3 = SBP(0,3);
        float C4 = SBP(0,4),  C5 = SBP(0,5),  C6 = SBP(0,6),  C7 = SBP(0,7);
        float C8 = SBP(0,8),  C9 = SBP(0,9),  C10 = SBP(0,10), C11 = SBP(0,11);
        float C12 = SBP(0,12), C13 = SBP(0,13), C14 = SBP(0,14), C15 = SBP(0,15);
        float D0 = SBP(1,0),  D1 = SBP(1,1),  D2 = SBP(1,2),  D3 = SBP(1,3);
        float D4 = SBP(1,4),  D5 = SBP(1,5),  D6 = SBP(1,6),  D7 = SBP(1,7);
        float D8 = SBP(1,8),  D9 = SBP(1,9),  D10 = SBP(1,10), D11 = SBP(1,11);
        float D12 = SBP(1,12), D13 = SBP(1,13), D14 = SBP(1,14), D15 = SBP(1,15);

        for (int it = 0; it <= 29; ++it) {
            float N0=0,N1=0,N2=0,N3=0,N4=0,N5=0,N6=0,N7=0;
            float N8=0,N9=0,N10=0,N11=0,N12=0,N13=0,N14=0,N15=0;
            if (it + 2 <= 30) {
                N0  = SBP(it+2,0);  N1  = SBP(it+2,1);  N2  = SBP(it+2,2);  N3  = SBP(it+2,3);
                N4  = SBP(it+2,4);  N5  = SBP(it+2,5);  N6  = SBP(it+2,6);  N7  = SBP(it+2,7);
                N8  = SBP(it+2,8);  N9  = SBP(it+2,9);  N10 = SBP(it+2,10); N11 = SBP(it+2,11);
                N12 = SBP(it+2,12); N13 = SBP(it+2,13); N14 = SBP(it+2,14); N15 = SBP(it+2,15);
            }
            const int q0 = 3 * it;
            CHOL_COL(q0 + 0, C0,  C1,  C2,  cA,   C3,  C4,  0.f,  C5);
            CHOL_COL(q0 + 1, C6,  C7,  C8,  C9,   C10, 0.f, -1.f, C11);
            CHOL_COL(q0 + 2, C12, C13, C14, cB,   0.f, 0.f, 0.f,  C15);
            C0=D0; C1=D1; C2=D2; C3=D3; C4=D4; C5=D5; C6=D6; C7=D7;
            C8=D8; C9=D9; C10=D10; C11=D11; C12=D12; C13=D13; C14=D14; C15=D15;
            D0=N0; D1=N1; D2=N2; D3=N3; D4=N4; D5=N5; D6=N6; D7=N7;
            D8=N8; D9=N9; D10=N10; D11=N11; D12=N12; D13=N13; D14=N14; D15=N15;
        }

#define DECL8(P) float P##d = 0, P##1 = 0, P##2 = 0, P##3 = 0,                 \
                       P##4 = 0, P##5 = 0, P##6 = 0, P##y = 0;
#define LOAD8(P, q) { const int o8 = (q)*8;                                    \
        P##d = SL(o8 + 0); P##1 = SL(o8 + 1); P##2 = SL(o8 + 2);               \
        P##3 = SL(o8 + 3); P##4 = SL(o8 + 4); P##5 = SL(o8 + 5);               \
        P##6 = SL(o8 + 6); P##y = SL(o8 + 7); }

        DECL8(PA) DECL8(PB_) DECL8(PC)
        DECL8(QA) DECL8(QB) DECL8(QC)
        DECL8(RA) DECL8(RB) DECL8(RC)

        CHOL_COL_CAP(PA,  C0,  C1,  C2,  cA,   C3,  C4,  0.f,  C5);
        CHOL_COL_CAP(PB_, C6,  C7,  C8,  C9,   C10, 0.f, -1.f, C11);
        CHOL_COL_CAP(PC,  C12, C13, C14, cB,   0.f, 0.f, 0.f,  C15);

        LOAD8(QC, 89) LOAD8(QB, 88) LOAD8(QA, 87)
        LOAD8(RC, 86) LOAD8(RB, 85) LOAD8(RA, 84)

        const float R11=__shfl_xor(W11,1), R12=__shfl_xor(W12,1), R13=__shfl_xor(W13,1);
        const float R14=__shfl_xor(W14,1), R15=__shfl_xor(W15,1), R16=__shfl_xor(W16,1);
        const float R22=__shfl_xor(W22,1), R23=__shfl_xor(W23,1), R24=__shfl_xor(W24,1);
        const float R25=__shfl_xor(W25,1), R26=__shfl_xor(W26,1);
        const float R33=__shfl_xor(W33,1), R34=__shfl_xor(W34,1), R35=__shfl_xor(W35,1);
        const float R36=__shfl_xor(W36,1);
        const float R44=__shfl_xor(W44,1), R45=__shfl_xor(W45,1), R46=__shfl_xor(W46,1);
        const float R55=__shfl_xor(W55,1), R56=__shfl_xor(W56,1);
        const float R66=__shfl_xor(W66,1);
        const float r1=__shfl_xor(y1,1), r2=__shfl_xor(y2,1), r3=__shfl_xor(y3,1);
        const float r4=__shfl_xor(y4,1), r5=__shfl_xor(y5,1), r6=__shfl_xor(y6,1);

        float xm0=0, xm1=0, xm2=0, xm3=0, xm4=0, xm5=0;
        if (chain == 0) {
            const float* __restrict__ md = midl + pair;
            float S00 = md[0*PB],  S10 = md[1*PB],  S20 = md[2*PB];
            float S30 = md[3*PB],  S40 = md[4*PB],  S50 = md[5*PB];
            float S11 = md[6*PB],  S21 = md[7*PB],  S31 = md[8*PB];
            float S41 = md[9*PB],  S51 = md[10*PB], S22 = md[11*PB];
            float S32 = md[12*PB], S42 = md[13*PB], S52 = md[14*PB];
            float S33 = md[15*PB], S43 = md[16*PB], S53 = md[17*PB];
            float S44 = md[18*PB], S54 = md[19*PB], S55 = md[20*PB];
            float fm0 = md[21*PB], fm1 = md[22*PB], fm2 = md[23*PB];
            float fm3 = md[24*PB], fm4 = md[25*PB], fm5 = md[26*PB];

            S00 -= W11*W11 + W22*W22 + W33*W33 + W44*W44 + W55*W55 + W66*W66;
            S10 -= W12*W11 + W23*W22 + W34*W33 + W45*W44 + W56*W55;
            S11 -= W12*W12 + W23*W23 + W34*W34 + W45*W45 + W56*W56;
            S20 -= W13*W11 + W24*W22 + W35*W33 + W46*W44;
            S21 -= W13*W12 + W24*W23 + W35*W34 + W46*W45;
            S22 -= W13*W13 + W24*W24 + W35*W35 + W46*W46;
            S30 -= W14*W11 + W25*W22 + W36*W33;
            S31 -= W14*W12 + W25*W23 + W36*W34;
            S32 -= W14*W13 + W25*W24 + W36*W35;
            S33 -= W14*W14 + W25*W25 + W36*W36;
            S40 -= W15*W11 + W26*W22;
            S41 -= W15*W12 + W26*W23;
            S42 -= W15*W13 + W26*W24;
            S43 -= W15*W14 + W26*W25;
            S44 -= W15*W15 + W26*W26;
            S50 -= W16*W11;
            S51 -= W16*W12;
            S52 -= W16*W13;
            S53 -= W16*W14;
            S54 -= W16*W15;
            S55 -= W16*W16;

            S00 -= R16*R16;
            S10 -= R15*R16;
            S11 -= R15*R15 + R26*R26;
            S20 -= R14*R16;
            S21 -= R14*R15 + R25*R26;
            S22 -= R14*R14 + R25*R25 + R36*R36;
            S30 -= R13*R16;
            S31 -= R13*R15 + R24*R26;
            S32 -= R13*R14 + R24*R25 + R35*R36;
            S33 -= R13*R13 + R24*R24 + R35*R35 + R46*R46;
            S40 -= R12*R16;
            S41 -= R12*R15 + R23*R26;
            S42 -= R12*R14 + R23*R25 + R34*R36;
            S43 -= R12*R13 + R23*R24 + R34*R35 + R45*R46;
            S44 -= R12*R12 + R23*R23 + R34*R34 + R45*R45 + R56*R56;
            S50 -= R11*R16;
            S51 -= R11*R15 + R22*R26;
            S52 -= R11*R14 + R22*R25 + R33*R36;
            S53 -= R11*R13 + R22*R24 + R33*R35 + R44*R46;
            S54 -= R11*R12 + R22*R23 + R33*R34 + R44*R45 + R55*R56;
            S55 -= R11*R11 + R22*R22 + R33*R33 + R44*R44 + R55*R55 + R66*R66;

            fm0 -= (W11*y1 + W22*y2 + W33*y3 + W44*y4 + W55*y5 + W66*y6) + (R16*r1);
            fm1 -= (W12*y1 + W23*y2 + W34*y3 + W45*y4 + W56*y5) + (R15*r1 + R26*r2);
            fm2 -= (W13*y1 + W24*y2 + W35*y3 + W46*y4) + (R14*r1 + R25*r2 + R36*r3);
            fm3 -= (W14*y1 + W25*y2 + W36*y3) + (R13*r1 + R24*r2 + R35*r3 + R46*r4);
            fm4 -= (W15*y1 + W26*y2) + (R12*r1 + R23*r2 + R34*r3 + R45*r4 + R56*r5);
            fm5 -= (W16*y1) + (R11*r1 + R22*r2 + R33*r3 + R44*r4 + R55*r5 + R66*r6);

            const float md0 = rsqrtf(S00);
            const float M10 = S10*md0, M20 = S20*md0, M30 = S30*md0,
                        M40 = S40*md0, M50 = S50*md0;
            const float zm0 = fm0*md0;
            const float md1 = rsqrtf(S11 - M10*M10);
            const float M21 = (S21 - M20*M10)*md1;
            const float M31 = (S31 - M30*M10)*md1;
            const float M41 = (S41 - M40*M10)*md1;
            const float M51 = (S51 - M50*M10)*md1;
            const float zm1 = (fm1 - M10*zm0)*md1;
            const float md2 = rsqrtf(S22 - M20*M20 - M21*M21);
            const float M32 = (S32 - M30*M20 - M31*M21)*md2;
            const float M42 = (S42 - M40*M20 - M41*M21)*md2;
            const float M52 = (S52 - M50*M20 - M51*M21)*md2;
            const float zm2 = (fm2 - M20*zm0 - M21*zm1)*md2;
            const float md3 = rsqrtf(S33 - M30*M30 - M31*M31 - M32*M32);
            const float M43 = (S43 - M40*M30 - M41*M31 - M42*M32)*md3;
            const float M53 = (S53 - M50*M30 - M51*M31 - M52*M32)*md3;
            const float zm3 = (fm3 - M30*zm0 - M31*zm1 - M32*zm2)*md3;
            const float md4 = rsqrtf(S44 - M40*M40 - M41*M41 - M42*M42 - M43*M43);
            const float M54 = (S54 - M50*M40 - M51*M41 - M52*M42 - M53*M43)*md4;
            const float zm4 = (fm4 - M40*zm0 - M41*zm1 - M42*zm2 - M43*zm3)*md4;
            const float md5 = rsqrtf(S55 - M50*M50 - M51*M51 - M52*M52 - M53*M53 - M54*M54);
            const float zm5 = (fm5 - M50*zm0 - M51*zm1 - M52*zm2 - M53*zm3 - M54*zm4)*md5;

            xm5 = zm5*md5;
            xm4 = (zm4 - M54*xm5)*md4;
            xm3 = (zm3 - M43*xm4 - M53*xm5)*md3;
            xm2 = (zm2 - M32*xm3 - M42*xm4 - M52*xm5)*md2;
            xm1 = (zm1 - M21*xm2 - M31*xm3 - M41*xm4 - M51*xm5)*md1;
            xm0 = (zm0 - M10*xm1 - M20*xm2 - M30*xm3 - M40*xm4 - M50*xm5)*md0;

            mxl[0*PB + pair] = xm0; mxl[1*PB + pair] = xm1; mxl[2*PB + pair] = xm2;
            mxl[3*PB + pair] = xm3; mxl[4*PB + pair] = xm4; mxl[5*PB + pair] = xm5;
        }

        const float g0 = __shfl_xor(xm0, 1), g1 = __shfl_xor(xm1, 1);
        const float g2 = __shfl_xor(xm2, 1), g3 = __shfl_xor(xm3, 1);
        const float g4 = __shfl_xor(xm4, 1), g5 = __shfl_xor(xm5, 1);

        float x1 = chain ? g5 : xm0;
        float x2 = chain ? g4 : xm1;
        float x3 = chain ? g3 : xm2;
        float x4 = chain ? g2 : xm3;
        float x5 = chain ? g1 : xm4;
        float x6 = chain ? g0 : xm5;

#define BSUB(P, q) {                                                           \
        const float rest = (P##6*x6 + P##5*x5) + (P##4*x4 + P##3*x3) + P##2*x2;\
        const float xr = ((P##y - rest) - P##1*x1) * P##d;                     \
        SXQ(q) = xr;                                                           \
        x6 = x5; x5 = x4; x4 = x3; x3 = x2; x2 = x1; x1 = xr; }

        for (int it2 = 0; it2 < 31; it2 += 3) {
            {   const int st = 30 - it2;
                BSUB(PC, 3*st + 2) BSUB(PB_, 3*st + 1) BSUB(PA, 3*st)
                if (st - 3 >= 0) { LOAD8(PC, 3*(st-3) + 2) LOAD8(PB_, 3*(st-3) + 1) LOAD8(PA, 3*(st-3)) }
            }
            {   const int st = 29 - it2;
                if (st >= 0) {
                    BSUB(QC, 3*st + 2) BSUB(QB, 3*st + 1) BSUB(QA, 3*st)
                    if (st - 3 >= 0) { LOAD8(QC, 3*(st-3) + 2) LOAD8(QB, 3*(st-3) + 1) LOAD8(QA, 3*(st-3)) }
                }
            }
            {   const int st = 28 - it2;
                if (st >= 0) {
                    BSUB(RC, 3*st + 2) BSUB(RB, 3*st + 1) BSUB(RA, 3*st)
                    if (st - 3 >= 0) { LOAD8(RC, 3*(st-3) + 2) LOAD8(RB, 3*(st-3) + 1) LOAD8(RA, 3*(st-3)) }
                }
            }
        }

#undef SBP
#undef SL
#undef SXQ
#undef CHOL_BODY
#undef CHOL_SHIFT
#undef CHOL_COL
#undef CHOL_COL_CAP
#undef DECL8
#undef LOAD8
#undef BSUB
    }

    __syncthreads();

    // ---------------- Phase 2: output mapping (coalesced writes) ----------------
    for (int idx = tid; idx < PB * 192; idx += 256) {
        const int bl = idx / 192;
        const int j  = idx - bl * 192;
        float v;
        if (j < 93)      v = xql[j * 32 + 2 * bl];
        else if (j > 98) v = xql[(191 - j) * 32 + 2 * bl + 1];
        else             v = mxl[(j - 93) * PB + bl];
        out[(size_t)w * (PB * 192) + idx] = v;
    }
}

// ============================================================================
// Fallback (round-1 kernel, known-pass): used only if ws is too small
// ============================================================================
__global__ __launch_bounds__(64, 1)
void ode_banded_solve(const float* __restrict__ coeffs,
                      const float* __restrict__ rhs,
                      const float* __restrict__ iv_rhs,
                      const float* __restrict__ steps,
                      float* __restrict__ out)
{
    const int b    = blockIdx.x;
    const int lane = threadIdx.x;

    __shared__ float band[NV * BW];
    __shared__ float rv[NV];
    __shared__ float stp[NT + 1];

    for (int i = lane; i < NV * BW; i += 64) band[i] = 0.0f;
    if (lane < NT) stp[lane] = steps[b * NT + lane];
    __syncthreads();

    {
        const int st = lane;
        const float c0 = coeffs[b * NV + st * 3 + 0];
        const float c1 = coeffs[b * NV + st * 3 + 1];
        const float c2 = coeffs[b * NV + st * 3 + 2];
        const float r  = rhs[b * NS + st];
        const float reg = (st < 2) ? 1.0f : 0.0f;
        atomicAdd(&band[(3 * st + 0) * BW + 0], c0 * c0 + reg);
        atomicAdd(&band[(3 * st + 1) * BW + 0], c1 * c1 + reg);
        atomicAdd(&band[(3 * st + 2) * BW + 0], c2 * c2);
        atomicAdd(&band[(3 * st + 1) * BW + 1], c1 * c0);
        atomicAdd(&band[(3 * st + 2) * BW + 1], c2 * c1);
        atomicAdd(&band[(3 * st + 2) * BW + 2], c2 * c0);
        float b0 = c0 * r, b1 = c1 * r, b2v = c2 * r;
        if (st < 2) {
            b0 += iv_rhs[b * 4 + st * 2 + 0];
            b1 += iv_rhs[b * 4 + st * 2 + 1];
        }
        rv[3 * st + 0] = b0;
        rv[3 * st + 1] = b1;
        rv[3 * st + 2] = b2v;
    }

    for (int t = lane; t < NC; t += 64) {
        int   cols[4];
        float vals[4];
        int   cnt;
        if (t < 126) {
            const int st = t >> 1, i = t & 1;
            const float s = stp[st];
            if (i == 0) {
                cols[0] = 3 * st + 0; vals[0] = 1.0f;
                cols[1] = 3 * st + 1; vals[1] = s;
                cols[2] = 3 * st + 2; vals[2] = 0.5f * s * s;
                cols[3] = 3 * st + 3; vals[3] = -1.0f;
                cnt = 4;
            } else {
                cols[0] = 3 * st + 1; vals[0] = s;
                cols[1] = 3 * st + 2; vals[1] = s * s;
                cols[2] = 3 * st + 4; vals[2] = -s;
                cnt = 3;
            }
        } else if (t < 188) {
            const int st = t - 126 + 1;
            const float cp = stp[st - 1] + stp[st];
            cols[0] = 3 * st - 2; vals[0] = -1.0f;
            cols[1] = 3 * st + 2; vals[1] = -cp;
            cols[2] = 3 * st + 4; vals[2] = 1.0f;
            cnt = 3;
        } else {
            const int tt = t - 188;
            const int st = tt >> 1, i = tt & 1;
            const float s = stp[st];
            if (i == 0) {
                cols[0] = 3 * st + 0; vals[0] = -1.0f;
                cols[1] = 3 * st + 3; vals[1] = 1.0f;
                cols[2] = 3 * st + 4; vals[2] = -s;
                cols[3] = 3 * st + 5; vals[3] = 0.5f * s * s;
                cnt = 4;
            } else {
                cols[0] = 3 * st + 1; vals[0] = s;
                cols[1] = 3 * st + 4; vals[1] = -s;
                cols[2] = 3 * st + 5; vals[2] = s * s;
                cnt = 3;
            }
        }
        for (int a = 0; a < cnt; ++a)
            for (int b2 = 0; b2 <= a; ++b2)
                atomicAdd(&band[cols[a] * BW + (cols[a] - cols[b2])],
                          vals[a] * vals[b2]);
    }
    __syncthreads();

    int pa = 0, pb = 0;
    {
        int idx = 0;
        for (int aa = 1; aa <= 6; ++aa)
            for (int bb = 1; bb <= aa; ++bb) {
                if (idx == lane) { pa = aa; pb = bb; }
                ++idx;
            }
    }
    const int sk = lane - 20;

    for (int j = 0; j < NV; ++j) {
        const int m = (NV - 1 - j < 6) ? (NV - 1 - j) : 6;
        const float diag = band[j * BW];
        const float d    = sqrtf(diag);
        const float dinv = 1.0f / d;

        const bool doU = (lane < 21) && (pa <= m);
        const bool doS = (lane >= 21) && (lane <= 26) && (sk <= m);
        float ca = 0.0f, cb = 0.0f, cs = 0.0f;
        if (doU) { ca = band[(j + pa) * BW + pa]; cb = band[(j + pb) * BW + pb]; }
        if (doS) { cs = band[(j + sk) * BW + sk]; }
        __syncthreads();

        if (lane == 0) band[j * BW] = d;
        if (doU) band[(j + pa) * BW + (pa - pb)] -= ca * cb * (dinv * dinv);
        if (doS) band[(j + sk) * BW + sk] = cs * dinv;
        __syncthreads();
    }

    for (int j = 0; j < NV; ++j) {
        const int m = (NV - 1 - j < 6) ? (NV - 1 - j) : 6;
        const float yj = rv[j] / band[j * BW];
        const bool doK = (lane >= 1) && (lane <= m);
        float sub = 0.0f, rj = 0.0f;
        if (doK) { sub = band[(j + lane) * BW + lane] * yj; rj = rv[j + lane]; }
        __syncthreads();
        if (lane == 0) rv[j] = yj;
        if (doK) rv[j + lane] = rj - sub;
        __syncthreads();
    }

    for (int j = NV - 1; j >= 0; --j) {
        const int m = (j < 6) ? j : 6;
        const float xj = rv[j] / band[j * BW];
        const bool doK = (lane >= 1) && (lane <= m);
        float sub = 0.0f, rj = 0.0f;
        if (doK) { sub = band[j * BW + lane] * xj; rj = rv[j - lane]; }
        __syncthreads();
        if (lane == 0) rv[j] = xj;
        if (doK) rv[j - lane] = rj - sub;
        __syncthreads();
    }

    for (int i = lane; i < NV; i += 64)
        out[b * NV + i] = rv[i];
}

extern "C" void kernel_launch(void* const* d_in, const int* in_sizes, int n_in,
                              void* d_out, int out_size, void* d_ws, size_t ws_size,
                              hipStream_t stream)
{
    const float* coeffs = (const float*)d_in[0];   // 1024*64*3
    const float* rhs    = (const float*)d_in[1];   // 1024*64
    const float* iv_rhs = (const float*)d_in[2];   // 1024*2*2
    const float* steps  = (const float*)d_in[3];   // 1024*63
    float* out = (float*)d_out;                    // 1024*192

    const size_t need = (size_t)NBLK * BP_SLOTS * 32 * sizeof(float);   // ~4.1 MB

    if (ws_size >= need) {
        ode_mega2<<<dim3(NBLK), dim3(256), 0, stream>>>(coeffs, rhs, steps, iv_rhs,
                                                        (float*)d_ws, out);
    } else {
        ode_banded_solve<<<dim3(NB), dim3(64), 0, stream>>>(coeffs, rhs, iv_rhs,
                                                            steps, out);
    }
}

// Round 12
// 37.182 us; speedup vs baseline: 3.3865x; 1.1048x over previous
//
#include <hip/hip_runtime.h>
#include <math.h>

// Problem constants (static config)
#define NB 1024
#define NS 64
#define NT 63
#define NV 192
#define BW 7
#define NC 314

#define NBLK 64             // blocks; each handles 16 batches (32 lanes = 2 chains)
#define PB 16               // batches (pairs) per block
#define BP_SLOTS (31*16)    // per-block BP slots, x32 lanes each

// ============================================================================
// ode_mega3: single-kernel pipeline, 64 blocks x 256 threads.
// Phase 1 factor loop unrolled 6 columns with rotating record roles (A..F):
// the 6-deep window shift becomes register renaming -> zero shift movs.
// Pieces double-buffered (CA/CB <-> MA/MB), loads issued one 6-col body ahead.
// xql padded to stride 33 (kills phase-2 32-way bank conflicts).
// All arithmetic identical to the verified r9-r11 kernels.
// ============================================================================
__global__ __launch_bounds__(256, 1)
void ode_mega3(const float* __restrict__ coeffs,
               const float* __restrict__ rhs,
               const float* __restrict__ steps,
               const float* __restrict__ iv_rhs,
               float* __restrict__ wsBP,
               float* __restrict__ out)
{
    const int w   = blockIdx.x;     // 0..63
    const int tid = threadIdx.x;

    __shared__ float cf[PB * 193];
    __shared__ float sl[PB * 65];
    __shared__ float rl[PB * 65];
    __shared__ float il[PB * 4];
    __shared__ float midl[27 * PB];
    __shared__ float mxl[6 * PB];
    __shared__ float lql[93 * 8 * 32];  // 95 KB
    __shared__ float xql[93 * 33];      // padded stride 33 (conflict-free)

    // ---------------- Phase 0a: stage inputs (coalesced) ----------------
    for (int idx = tid; idx < PB * 192; idx += 256) {
        const int b = idx / 192, j = idx - 192 * b;
        cf[b * 193 + j] = coeffs[(size_t)w * (PB * 192) + idx];
    }
    for (int idx = tid; idx < PB * 63; idx += 256) {
        const int b = idx / 63, j = idx - 63 * b;
        sl[b * 65 + j] = steps[(size_t)w * (PB * 63) + idx];
    }
    for (int idx = tid; idx < PB * 64; idx += 256) {
        const int b = idx >> 6, j = idx & 63;
        rl[b * 65 + j] = rhs[(size_t)w * (PB * 64) + idx];
    }
    if (tid < PB * 4) il[tid] = iv_rhs[(size_t)w * (PB * 4) + tid];
    __syncthreads();

    // ---------------- Phase 0b: band pieces + middle pre-Schur ----------------
    for (int idx = tid; idx < 31 * PB; idx += 256) {
        const int it = idx >> 4;
        const int pr = idx & 15;
        const float* cfp = cf + pr * 193;
        const float* slp = sl + pr * 65;
        const float* rlp = rl + pr * 65;

        float F[16], G[16];
        {   // fwd pieces, step t = it
            const int t = it;
            const float c0 = cfp[3*t], c1 = cfp[3*t+1], c2 = cfp[3*t+2];
            const float r  = rlp[t];
            const float p  = (t >= 1) ? slp[t-1] : 0.f;
            const float s  = slp[t];
            const float sn = slp[t+1];
            const float mP = (t >= 1) ? 1.f : 0.f;
            const float rg = (t < 2) ? 1.f : 0.f;
            float iv0 = 0.f, iv1 = 0.f;
            if (t < 2) { iv0 = il[pr*4 + t*2]; iv1 = il[pr*4 + t*2 + 1]; }
            const float s2 = s*s, s3 = s2*s, p2 = p*p, p3 = p2*p, gt = p + s;
            F[0]  = c0*c0 + rg + 2.f*(1.f + mP);
            F[1]  = c0*c1 + s - p;
            F[2]  = c0*c2 + 0.5f*(s2 + p2);
            F[3]  = s;
            F[4]  = -0.5f*s2;
            F[5]  = c0*r + iv0;
            F[6]  = c1*c1 + 3.f*(s2 + p2) + 2.f;
            F[7]  = c1*c2 + 1.5f*(s3 - p3);
            F[8]  = -s;
            F[9]  = -2.f*s2;
            F[10] = s3 + (s + sn);
            F[11] = c1*r + iv1;
            F[12] = c2*c2 + 1.25f*(s2*s2 + p2*p2) + gt*gt*mP;
            F[13] = -0.5f*s2;
            F[14] = -s3 - gt*mP;
            F[15] = c2*r;
        }
        {   // bwd pieces, step t = 63 - it
            const int t = 63 - it;
            const float c0 = cfp[3*t], c1 = cfp[3*t+1], c2 = cfp[3*t+2];
            const float r  = rlp[t];
            const float s  = (t < 63) ? slp[t] : 0.f;
            const float p  = slp[t-1];
            const float pp = slp[t-2];
            const float mSb  = (t < 63) ? 1.f : 0.f;
            const float mCNb = (t < 62) ? 1.f : 0.f;
            const float s2 = s*s, s3 = s2*s, p2 = p*p, p3 = p2*p, gt = p + s;
            G[0]  = c2*c2 + 1.25f*(s2*s2 + p2*p2) + gt*gt*mSb;
            G[1]  = c1*c2 + 1.5f*(s3 - p3);
            G[2]  = c0*c2 + 0.5f*(s2 + p2);
            G[3]  = p3 + (p + s)*mSb;
            G[4]  = -0.5f*p2;
            G[5]  = c2*r;
            G[6]  = c1*c1 + 3.f*(s2 + p2) + mCNb + 1.f;
            G[7]  = c0*c1 + s - p;
            G[8]  = -p3 - (pp + p);
            G[9]  = -2.f*p2;
            G[10] = p;
            G[11] = c1*r;
            G[12] = c0*c0 + 2.f*(mSb + 1.f);
            G[13] = -0.5f*p2;
            G[14] = -p;
            G[15] = c0*r;
        }
        float2* dst = (float2*)wsBP + (size_t)w * (BP_SLOTS * 16)
                                    + (size_t)it * 256 + pr;
        #pragma unroll
        for (int k = 0; k < 16; ++k) dst[(size_t)k * 16] = make_float2(F[k], G[k]);
    }

    if (tid < PB) {
        const int pr = tid;
        const float* cfp = cf + pr * 193;
        const float* slp = sl + pr * 65;
        const float* rlp = rl + pr * 65;
        const float pA = slp[30], sA = slp[31], snA = slp[32];
        const float sB = slp[32], pBm = sA;
        const float c0A = cfp[93], c1A = cfp[94], c2A = cfp[95];
        const float c0B = cfp[96], c1B = cfp[97], c2B = cfp[98];
        const float rA = rlp[31], rB = rlp[32];
        const float sA2 = sA*sA, sA3 = sA2*sA, pA2 = pA*pA, pA3 = pA2*pA;
        const float sB2 = sB*sB, sB3 = sB2*sB, pB2 = pBm*pBm, pB3 = pB2*pBm;
        float m[27];
        m[0]  = c0A*c0A + 4.f;
        m[1]  = c0A*c1A + sA - pA;
        m[2]  = c0A*c2A + 0.5f*(sA2 + pA2);
        m[3]  = -2.f;
        m[4]  = sA;
        m[5]  = -0.5f*sA2;
        m[6]  = c1A*c1A + 3.f*(sA2 + pA2) + 2.f;
        m[7]  = c1A*c2A + 1.5f*(sA3 - pA3);
        m[8]  = -sA;
        m[9]  = -2.f*sA2;
        m[10] = sA3 + (sA + snA);
        m[11] = c2A*c2A + 1.25f*(sA2*sA2 + pA2*pA2) + (pA + sA)*(pA + sA);
        m[12] = -0.5f*sA2;
        m[13] = -sA3 - (pA + sA);
        m[14] = 0.f;
        m[15] = c0B*c0B + 4.f;
        m[16] = c0B*c1B + sB - pBm;
        m[17] = c0B*c2B + 0.5f*(sB2 + pB2);
        m[18] = c1B*c1B + 3.f*(sB2 + pB2) + 2.f;
        m[19] = c1B*c2B + 1.5f*(sB3 - pB3);
        m[20] = c2B*c2B + 1.25f*(sB2*sB2 + pB2*pB2) + (pBm + sB)*(pBm + sB);
        m[21] = c0A*rA; m[22] = c1A*rA; m[23] = c2A*rA;
        m[24] = c0B*rB; m[25] = c1B*rB; m[26] = c2B*rB;
        #pragma unroll
        for (int k = 0; k < 27; ++k) midl[k * PB + pr] = m[k];
    }

    __syncthreads();

    // ---------------- Phase 1: serial twisted solve (lanes 0..31) ----------------
    if (tid < 32) {
        const int l     = tid;
        const int pair  = l >> 1;
        const int chain = l & 1;
        const float cA  = chain ? 0.f : -2.f;
        const float cB  = chain ? -2.f : 0.f;

        const float* __restrict__ bp = wsBP + (size_t)w * (BP_SLOTS * 32) + l;

#define SBP(it, k) bp[(size_t)(((it) * 16 + (k)) * 32)]
#define SL(i)      lql[(i) * 32 + l]
#define SXQ(q)     xql[(q) * 33 + l]

        // records: the last 6 produced L-columns (n1..n6, y). Zero-init =
        // nonexistent columns before q0.
        float An1=0,An2=0,An3=0,An4=0,An5=0,An6=0,Ay=0;
        float Bn1=0,Bn2=0,Bn3=0,Bn4=0,Bn5=0,Bn6=0,By=0;
        float Cn1=0,Cn2=0,Cn3=0,Cn4=0,Cn5=0,Cn6=0,Cy=0;
        float Dn1=0,Dn2=0,Dn3=0,Dn4=0,Dn5=0,Dn6=0,Dy=0;
        float En1=0,En2=0,En3=0,En4=0,En5=0,En6=0,Ey=0;
        float Fn1=0,Fn2=0,Fn3=0,Fn4=0,Fn5=0,Fn6=0,Fy=0;

// One Cholesky column. R1 = newest record .. R6 = oldest (evicted; new column
// written into R6's registers). W[p][k] == R_p.n[k]; y_p == R_p.y.
#define CHOL_STEP(R1,R2,R3,R4,R5,R6, q, b0, b1, b2, b3, b4, b5, b6, rvv)       \
    {                                                                          \
        const float t0_ = (b0) - (R1##n1*R1##n1 + R2##n2*R2##n2 +              \
            R3##n3*R3##n3 + R4##n4*R4##n4 + R5##n5*R5##n5 + R6##n6*R6##n6);    \
        const float di_ = rsqrtf(t0_);                                         \
        const float u1_ = (b1) - (R1##n1*R1##n2 + R2##n2*R2##n3 +              \
            R3##n3*R3##n4 + R4##n4*R4##n5 + R5##n5*R5##n6);                    \
        const float u2_ = (b2) - (R1##n1*R1##n3 + R2##n2*R2##n4 +              \
            R3##n3*R3##n5 + R4##n4*R4##n6);                                    \
        const float u3_ = (b3) - (R1##n1*R1##n4 + R2##n2*R2##n5 + R3##n3*R3##n6); \
        const float u4_ = (b4) - (R1##n1*R1##n5 + R2##n2*R2##n6);              \
        const float u5_ = (b5) - (R1##n1*R1##n6);                              \
        const float u6_ = (b6);                                                \
        const float yj_ = ((rvv) - (R1##n1*R1##y + R2##n2*R2##y +              \
            R3##n3*R3##y + R4##n4*R4##y + R5##n5*R5##y + R6##n6*R6##y)) * di_; \
        R6##n1 = u1_*di_; R6##n2 = u2_*di_; R6##n3 = u3_*di_;                  \
        R6##n4 = u4_*di_; R6##n5 = u5_*di_; R6##n6 = u6_*di_;                  \
        R6##y  = yj_;                                                          \
        SL((q)*8 + 0) = di_;    SL((q)*8 + 1) = R6##n1;                        \
        SL((q)*8 + 2) = R6##n2; SL((q)*8 + 3) = R6##n3;                        \
        SL((q)*8 + 4) = R6##n4; SL((q)*8 + 5) = R6##n5;                        \
        SL((q)*8 + 6) = R6##n6; SL((q)*8 + 7) = yj_;                           \
    }

// Peeled variant: also capture (d, n1..n6, y) into backsub registers P*.
#define CHOL_CAP(R1,R2,R3,R4,R5,R6, P, b0, b1, b2, b3, b4, b5, b6, rvv)        \
    {                                                                          \
        const float t0_ = (b0) - (R1##n1*R1##n1 + R2##n2*R2##n2 +              \
            R3##n3*R3##n3 + R4##n4*R4##n4 + R5##n5*R5##n5 + R6##n6*R6##n6);    \
        const float di_ = rsqrtf(t0_);                                         \
        const float u1_ = (b1) - (R1##n1*R1##n2 + R2##n2*R2##n3 +              \
            R3##n3*R3##n4 + R4##n4*R4##n5 + R5##n5*R5##n6);                    \
        const float u2_ = (b2) - (R1##n1*R1##n3 + R2##n2*R2##n4 +              \
            R3##n3*R3##n5 + R4##n4*R4##n6);                                    \
        const float u3_ = (b3) - (R1##n1*R1##n4 + R2##n2*R2##n5 + R3##n3*R3##n6); \
        const float u4_ = (b4) - (R1##n1*R1##n5 + R2##n2*R2##n6);              \
        const float u5_ = (b5) - (R1##n1*R1##n6);                              \
        const float u6_ = (b6);                                                \
        const float yj_ = ((rvv) - (R1##n1*R1##y + R2##n2*R2##y +              \
            R3##n3*R3##y + R4##n4*R4##y + R5##n5*R5##y + R6##n6*R6##y)) * di_; \
        R6##n1 = u1_*di_; R6##n2 = u2_*di_; R6##n3 = u3_*di_;                  \
        R6##n4 = u4_*di_; R6##n5 = u5_*di_; R6##n6 = u6_*di_;                  \
        R6##y  = yj_;                                                          \
        P##d = di_;     P##1 = R6##n1; P##2 = R6##n2; P##3 = R6##n3;           \
        P##4 = R6##n4;  P##5 = R6##n5; P##6 = R6##n6; P##y = yj_;              \
    }

#define LD16(X, it) { X##0 = SBP(it,0);  X##1 = SBP(it,1);  X##2 = SBP(it,2);  \
        X##3 = SBP(it,3);  X##4 = SBP(it,4);  X##5 = SBP(it,5);                \
        X##6 = SBP(it,6);  X##7 = SBP(it,7);  X##8 = SBP(it,8);                \
        X##9 = SBP(it,9);  X##10 = SBP(it,10); X##11 = SBP(it,11);             \
        X##12 = SBP(it,12); X##13 = SBP(it,13); X##14 = SBP(it,14);            \
        X##15 = SBP(it,15); }

// 6 columns (two steps X, Y) with full record rotation — role order returns
// to (A..F) after each group.
#define G6(X, Y, q0)                                                           \
    CHOL_STEP(A,B,C,D,E,F, (q0)+0, X##0,  X##1,  X##2,  cA,    X##3,  X##4, 0.f,  X##5)  \
    CHOL_STEP(F,A,B,C,D,E, (q0)+1, X##6,  X##7,  X##8,  X##9,  X##10, 0.f, -1.f, X##11) \
    CHOL_STEP(E,F,A,B,C,D, (q0)+2, X##12, X##13, X##14, cB,    0.f,   0.f, 0.f,  X##15) \
    CHOL_STEP(D,E,F,A,B,C, (q0)+3, Y##0,  Y##1,  Y##2,  cA,    Y##3,  Y##4, 0.f,  Y##5)  \
    CHOL_STEP(C,D,E,F,A,B, (q0)+4, Y##6,  Y##7,  Y##8,  Y##9,  Y##10, 0.f, -1.f, Y##11) \
    CHOL_STEP(B,C,D,E,F,A, (q0)+5, Y##12, Y##13, Y##14, cB,    0.f,   0.f, 0.f,  Y##15)

        float CA0,CA1,CA2,CA3,CA4,CA5,CA6,CA7,CA8,CA9,CA10,CA11,CA12,CA13,CA14,CA15;
        float CB0,CB1,CB2,CB3,CB4,CB5,CB6,CB7,CB8,CB9,CB10,CB11,CB12,CB13,CB14,CB15;
        float MA0,MA1,MA2,MA3,MA4,MA5,MA6,MA7,MA8,MA9,MA10,MA11,MA12,MA13,MA14,MA15;
        float MB0,MB1,MB2,MB3,MB4,MB5,MB6,MB7,MB8,MB9,MB10,MB11,MB12,MB13,MB14,MB15;

        LD16(CA, 0) LD16(CB, 1)

        // groups 0..13 (steps 0..27); group g uses steps (2g, 2g+1)
        for (int g = 0; g < 14; g += 2) {
            LD16(MA, 2*g + 2) LD16(MB, 2*g + 3)     // pieces for group g+1
            G6(CA, CB, 6*g)                          // group g
            LD16(CA, 2*g + 4) LD16(CB, 2*g + 5)     // pieces for group g+2
            G6(MA, MB, 6*(g + 1))                    // group g+1
        }
        // group 14 (steps 28,29) + prefetch step 30 into MA
        LD16(MA, 30)
        G6(CA, CB, 84)

#define DECL8(P) float P##d = 0, P##1 = 0, P##2 = 0, P##3 = 0,                 \
                       P##4 = 0, P##5 = 0, P##6 = 0, P##y = 0;
#define LOAD8(P, q) { const int o8 = (q)*8;                                    \
        P##d = SL(o8 + 0); P##1 = SL(o8 + 1); P##2 = SL(o8 + 2);               \
        P##3 = SL(o8 + 3); P##4 = SL(o8 + 4); P##5 = SL(o8 + 5);               \
        P##6 = SL(o8 + 6); P##y = SL(o8 + 7); }

        DECL8(PA) DECL8(PB_) DECL8(PC)
        DECL8(QA) DECL8(QB) DECL8(QC)
        DECL8(RA) DECL8(RB) DECL8(RC)

        // peel step 30 (cols q90..92), captured into backsub registers
        CHOL_CAP(A,B,C,D,E,F, PA,  MA0,  MA1,  MA2,  cA,   MA3,  MA4, 0.f,  MA5)
        CHOL_CAP(F,A,B,C,D,E, PB_, MA6,  MA7,  MA8,  MA9,  MA10, 0.f, -1.f, MA11)
        CHOL_CAP(E,F,A,B,C,D, PC,  MA12, MA13, MA14, cB,   0.f,  0.f, 0.f,  MA15)

        LOAD8(QC, 89) LOAD8(QB, 88) LOAD8(QA, 87)
        LOAD8(RC, 86) LOAD8(RB, 85) LOAD8(RA, 84)

        // final record order (93 cols, rotation 93 mod 6 = 3): newest..oldest
        // = D, E, F, A, B, C. Map to the verified W/y names.
        const float W11=Dn1, W12=Dn2, W13=Dn3, W14=Dn4, W15=Dn5, W16=Dn6;
        const float W22=En2, W23=En3, W24=En4, W25=En5, W26=En6;
        const float W33=Fn3, W34=Fn4, W35=Fn5, W36=Fn6;
        const float W44=An4, W45=An5, W46=An6;
        const float W55=Bn5, W56=Bn6;
        const float W66=Cn6;
        const float y1=Dy, y2=Ey, y3=Fy, y4=Ay, y5=By, y6=Cy;

        const float R11=__shfl_xor(W11,1), R12=__shfl_xor(W12,1), R13=__shfl_xor(W13,1);
        const float R14=__shfl_xor(W14,1), R15=__shfl_xor(W15,1), R16=__shfl_xor(W16,1);
        const float R22=__shfl_xor(W22,1), R23=__shfl_xor(W23,1), R24=__shfl_xor(W24,1);
        const float R25=__shfl_xor(W25,1), R26=__shfl_xor(W26,1);
        const float R33=__shfl_xor(W33,1), R34=__shfl_xor(W34,1), R35=__shfl_xor(W35,1);
        const float R36=__shfl_xor(W36,1);
        const float R44=__shfl_xor(W44,1), R45=__shfl_xor(W45,1), R46=__shfl_xor(W46,1);
        const float R55=__shfl_xor(W55,1), R56=__shfl_xor(W56,1);
        const float R66=__shfl_xor(W66,1);
        const float r1=__shfl_xor(y1,1), r2=__shfl_xor(y2,1), r3=__shfl_xor(y3,1);
        const float r4=__shfl_xor(y4,1), r5=__shfl_xor(y5,1), r6=__shfl_xor(y6,1);

        float xm0=0, xm1=0, xm2=0, xm3=0, xm4=0, xm5=0;
        if (chain == 0) {
            const float* __restrict__ md = midl + pair;
            float S00 = md[0*PB],  S10 = md[1*PB],  S20 = md[2*PB];
            float S30 = md[3*PB],  S40 = md[4*PB],  S50 = md[5*PB];
            float S11 = md[6*PB],  S21 = md[7*PB],  S31 = md[8*PB];
            float S41 = md[9*PB],  S51 = md[10*PB], S22 = md[11*PB];
            float S32 = md[12*PB], S42 = md[13*PB], S52 = md[14*PB];
            float S33 = md[15*PB], S43 = md[16*PB], S53 = md[17*PB];
            float S44 = md[18*PB], S54 = md[19*PB], S55 = md[20*PB];
            float fm0 = md[21*PB], fm1 = md[22*PB], fm2 = md[23*PB];
            float fm3 = md[24*PB], fm4 = md[25*PB], fm5 = md[26*PB];

            S00 -= W11*W11 + W22*W22 + W33*W33 + W44*W44 + W55*W55 + W66*W66;
            S10 -= W12*W11 + W23*W22 + W34*W33 + W45*W44 + W56*W55;
            S11 -= W12*W12 + W23*W23 + W34*W34 + W45*W45 + W56*W56;
            S20 -= W13*W11 + W24*W22 + W35*W33 + W46*W44;
            S21 -= W13*W12 + W24*W23 + W35*W34 + W46*W45;
            S22 -= W13*W13 + W24*W24 + W35*W35 + W46*W46;
            S30 -= W14*W11 + W25*W22 + W36*W33;
            S31 -= W14*W12 + W25*W23 + W36*W34;
            S32 -= W14*W13 + W25*W24 + W36*W35;
            S33 -= W14*W14 + W25*W25 + W36*W36;
            S40 -= W15*W11 + W26*W22;
            S41 -= W15*W12 + W26*W23;
            S42 -= W15*W13 + W26*W24;
            S43 -= W15*W14 + W26*W25;
            S44 -= W15*W15 + W26*W26;
            S50 -= W16*W11;
            S51 -= W16*W12;
            S52 -= W16*W13;
            S53 -= W16*W14;
            S54 -= W16*W15;
            S55 -= W16*W16;

            S00 -= R16*R16;
            S10 -= R15*R16;
            S11 -= R15*R15 + R26*R26;
            S20 -= R14*R16;
            S21 -= R14*R15 + R25*R26;
            S22 -= R14*R14 + R25*R25 + R36*R36;
            S30 -= R13*R16;
            S31 -= R13*R15 + R24*R26;
            S32 -= R13*R14 + R24*R25 + R35*R36;
            S33 -= R13*R13 + R24*R24 + R35*R35 + R46*R46;
            S40 -= R12*R16;
            S41 -= R12*R15 + R23*R26;
            S42 -= R12*R14 + R23*R25 + R34*R36;
            S43 -= R12*R13 + R23*R24 + R34*R35 + R45*R46;
            S44 -= R12*R12 + R23*R23 + R34*R34 + R45*R45 + R56*R56;
            S50 -= R11*R16;
            S51 -= R11*R15 + R22*R26;
            S52 -= R11*R14 + R22*R25 + R33*R36;
            S53 -= R11*R13 + R22*R24 + R33*R35 + R44*R46;
            S54 -= R11*R12 + R22*R23 + R33*R34 + R44*R45 + R55*R56;
            S55 -= R11*R11 + R22*R22 + R33*R33 + R44*R44 + R55*R55 + R66*R66;

            fm0 -= (W11*y1 + W22*y2 + W33*y3 + W44*y4 + W55*y5 + W66*y6) + (R16*r1);
            fm1 -= (W12*y1 + W23*y2 + W34*y3 + W45*y4 + W56*y5) + (R15*r1 + R26*r2);
            fm2 -= (W13*y1 + W24*y2 + W35*y3 + W46*y4) + (R14*r1 + R25*r2 + R36*r3);
            fm3 -= (W14*y1 + W25*y2 + W36*y3) + (R13*r1 + R24*r2 + R35*r3 + R46*r4);
            fm4 -= (W15*y1 + W26*y2) + (R12*r1 + R23*r2 + R34*r3 + R45*r4 + R56*r5);
            fm5 -= (W16*y1) + (R11*r1 + R22*r2 + R33*r3 + R44*r4 + R55*r5 + R66*r6);

            const float md0 = rsqrtf(S00);
            const float M10 = S10*md0, M20 = S20*md0, M30 = S30*md0,
                        M40 = S40*md0, M50 = S50*md0;
            const float zm0 = fm0*md0;
            const float md1 = rsqrtf(S11 - M10*M10);
            const float M21 = (S21 - M20*M10)*md1;
            const float M31 = (S31 - M30*M10)*md1;
            const float M41 = (S41 - M40*M10)*md1;
            const float M51 = (S51 - M50*M10)*md1;
            const float zm1 = (fm1 - M10*zm0)*md1;
            const float md2 = rsqrtf(S22 - M20*M20 - M21*M21);
            const float M32 = (S32 - M30*M20 - M31*M21)*md2;
            const float M42 = (S42 - M40*M20 - M41*M21)*md2;
            const float M52 = (S52 - M50*M20 - M51*M21)*md2;
            const float zm2 = (fm2 - M20*zm0 - M21*zm1)*md2;
            const float md3 = rsqrtf(S33 - M30*M30 - M31*M31 - M32*M32);
            const float M43 = (S43 - M40*M30 - M41*M31 - M42*M32)*md3;
            const float M53 = (S53 - M50*M30 - M51*M31 - M52*M32)*md3;
            const float zm3 = (fm3 - M30*zm0 - M31*zm1 - M32*zm2)*md3;
            const float md4 = rsqrtf(S44 - M40*M40 - M41*M41 - M42*M42 - M43*M43);
            const float M54 = (S54 - M50*M40 - M51*M41 - M52*M42 - M53*M43)*md4;
            const float zm4 = (fm4 - M40*zm0 - M41*zm1 - M42*zm2 - M43*zm3)*md4;
            const float md5 = rsqrtf(S55 - M50*M50 - M51*M51 - M52*M52 - M53*M53 - M54*M54);
            const float zm5 = (fm5 - M50*zm0 - M51*zm1 - M52*zm2 - M53*zm3 - M54*zm4)*md5;

            xm5 = zm5*md5;
            xm4 = (zm4 - M54*xm5)*md4;
            xm3 = (zm3 - M43*xm4 - M53*xm5)*md3;
            xm2 = (zm2 - M32*xm3 - M42*xm4 - M52*xm5)*md2;
            xm1 = (zm1 - M21*xm2 - M31*xm3 - M41*xm4 - M51*xm5)*md1;
            xm0 = (zm0 - M10*xm1 - M20*xm2 - M30*xm3 - M40*xm4 - M50*xm5)*md0;

            mxl[0*PB + pair] = xm0; mxl[1*PB + pair] = xm1; mxl[2*PB + pair] = xm2;
            mxl[3*PB + pair] = xm3; mxl[4*PB + pair] = xm4; mxl[5*PB + pair] = xm5;
        }

        const float g0 = __shfl_xor(xm0, 1), g1 = __shfl_xor(xm1, 1);
        const float g2 = __shfl_xor(xm2, 1), g3 = __shfl_xor(xm3, 1);
        const float g4 = __shfl_xor(xm4, 1), g5 = __shfl_xor(xm5, 1);

        float x1 = chain ? g5 : xm0;
        float x2 = chain ? g4 : xm1;
        float x3 = chain ? g3 : xm2;
        float x4 = chain ? g2 : xm3;
        float x5 = chain ? g1 : xm4;
        float x6 = chain ? g0 : xm5;

#define BSUB(P, q) {                                                           \
        const float rest = (P##6*x6 + P##5*x5) + (P##4*x4 + P##3*x3) + P##2*x2;\
        const float xr = ((P##y - rest) - P##1*x1) * P##d;                     \
        SXQ(q) = xr;                                                           \
        x6 = x5; x5 = x4; x4 = x3; x3 = x2; x2 = x1; x1 = xr; }

        for (int it2 = 0; it2 < 31; it2 += 3) {
            {   const int st = 30 - it2;
                BSUB(PC, 3*st + 2) BSUB(PB_, 3*st + 1) BSUB(PA, 3*st)
                if (st - 3 >= 0) { LOAD8(PC, 3*(st-3) + 2) LOAD8(PB_, 3*(st-3) + 1) LOAD8(PA, 3*(st-3)) }
            }
            {   const int st = 29 - it2;
                if (st >= 0) {
                    BSUB(QC, 3*st + 2) BSUB(QB, 3*st + 1) BSUB(QA, 3*st)
                    if (st - 3 >= 0) { LOAD8(QC, 3*(st-3) + 2) LOAD8(QB, 3*(st-3) + 1) LOAD8(QA, 3*(st-3)) }
                }
            }
            {   const int st = 28 - it2;
                if (st >= 0) {
                    BSUB(RC, 3*st + 2) BSUB(RB, 3*st + 1) BSUB(RA, 3*st)
                    if (st - 3 >= 0) { LOAD8(RC, 3*(st-3) + 2) LOAD8(RB, 3*(st-3) + 1) LOAD8(RA, 3*(st-3)) }
                }
            }
        }

#undef SBP
#undef SL
#undef SXQ
#undef CHOL_STEP
#undef CHOL_CAP
#undef LD16
#undef G6
#undef DECL8
#undef LOAD8
#undef BSUB
    }

    __syncthreads();

    // ---------------- Phase 2: output mapping (coalesced writes) ----------------
    for (int idx = tid; idx < PB * 192; idx += 256) {
        const int bl = idx / 192;
        const int j  = idx - bl * 192;
        float v;
        if (j < 93)      v = xql[j * 33 + 2 * bl];
        else if (j > 98) v = xql[(191 - j) * 33 + 2 * bl + 1];
        else             v = mxl[(j - 93) * PB + bl];
        out[(size_t)w * (PB * 192) + idx] = v;
    }
}

// ============================================================================
// Fallback (round-1 kernel, known-pass): used only if ws is too small
// ============================================================================
__global__ __launch_bounds__(64, 1)
void ode_banded_solve(const float* __restrict__ coeffs,
                      const float* __restrict__ rhs,
                      const float* __restrict__ iv_rhs,
                      const float* __restrict__ steps,
                      float* __restrict__ out)
{
    const int b    = blockIdx.x;
    const int lane = threadIdx.x;

    __shared__ float band[NV * BW];
    __shared__ float rv[NV];
    __shared__ float stp[NT + 1];

    for (int i = lane; i < NV * BW; i += 64) band[i] = 0.0f;
    if (lane < NT) stp[lane] = steps[b * NT + lane];
    __syncthreads();

    {
        const int st = lane;
        const float c0 = coeffs[b * NV + st * 3 + 0];
        const float c1 = coeffs[b * NV + st * 3 + 1];
        const float c2 = coeffs[b * NV + st * 3 + 2];
        const float r  = rhs[b * NS + st];
        const float reg = (st < 2) ? 1.0f : 0.0f;
        atomicAdd(&band[(3 * st + 0) * BW + 0], c0 * c0 + reg);
        atomicAdd(&band[(3 * st + 1) * BW + 0], c1 * c1 + reg);
        atomicAdd(&band[(3 * st + 2) * BW + 0], c2 * c2);
        atomicAdd(&band[(3 * st + 1) * BW + 1], c1 * c0);
        atomicAdd(&band[(3 * st + 2) * BW + 1], c2 * c1);
        atomicAdd(&band[(3 * st + 2) * BW + 2], c2 * c0);
        float b0 = c0 * r, b1 = c1 * r, b2v = c2 * r;
        if (st < 2) {
            b0 += iv_rhs[b * 4 + st * 2 + 0];
            b1 += iv_rhs[b * 4 + st * 2 + 1];
        }
        rv[3 * st + 0] = b0;
        rv[3 * st + 1] = b1;
        rv[3 * st + 2] = b2v;
    }

    for (int t = lane; t < NC; t += 64) {
        int   cols[4];
        float vals[4];
        int   cnt;
        if (t < 126) {
            const int st = t >> 1, i = t & 1;
            const float s = stp[st];
            if (i == 0) {
                cols[0] = 3 * st + 0; vals[0] = 1.0f;
                cols[1] = 3 * st + 1; vals[1] = s;
                cols[2] = 3 * st + 2; vals[2] = 0.5f * s * s;
                cols[3] = 3 * st + 3; vals[3] = -1.0f;
                cnt = 4;
            } else {
                cols[0] = 3 * st + 1; vals[0] = s;
                cols[1] = 3 * st + 2; vals[1] = s * s;
                cols[2] = 3 * st + 4; vals[2] = -s;
                cnt = 3;
            }
        } else if (t < 188) {
            const int st = t - 126 + 1;
            const float cp = stp[st - 1] + stp[st];
            cols[0] = 3 * st - 2; vals[0] = -1.0f;
            cols[1] = 3 * st + 2; vals[1] = -cp;
            cols[2] = 3 * st + 4; vals[2] = 1.0f;
            cnt = 3;
        } else {
            const int tt = t - 188;
            const int st = tt >> 1, i = tt & 1;
            const float s = stp[st];
            if (i == 0) {
                cols[0] = 3 * st + 0; vals[0] = -1.0f;
                cols[1] = 3 * st + 3; vals[1] = 1.0f;
                cols[2] = 3 * st + 4; vals[2] = -s;
                cols[3] = 3 * st + 5; vals[3] = 0.5f * s * s;
                cnt = 4;
            } else {
                cols[0] = 3 * st + 1; vals[0] = s;
                cols[1] = 3 * st + 4; vals[1] = -s;
                cols[2] = 3 * st + 5; vals[2] = s * s;
                cnt = 3;
            }
        }
        for (int a = 0; a < cnt; ++a)
            for (int b2 = 0; b2 <= a; ++b2)
                atomicAdd(&band[cols[a] * BW + (cols[a] - cols[b2])],
                          vals[a] * vals[b2]);
    }
    __syncthreads();

    int pa = 0, pb = 0;
    {
        int idx = 0;
        for (int aa = 1; aa <= 6; ++aa)
            for (int bb = 1; bb <= aa; ++bb) {
                if (idx == lane) { pa = aa; pb = bb; }
                ++idx;
            }
    }
    const int sk = lane - 20;

    for (int j = 0; j < NV; ++j) {
        const int m = (NV - 1 - j < 6) ? (NV - 1 - j) : 6;
        const float diag = band[j * BW];
        const float d    = sqrtf(diag);
        const float dinv = 1.0f / d;

        const bool doU = (lane < 21) && (pa <= m);
        const bool doS = (lane >= 21) && (lane <= 26) && (sk <= m);
        float ca = 0.0f, cb = 0.0f, cs = 0.0f;
        if (doU) { ca = band[(j + pa) * BW + pa]; cb = band[(j + pb) * BW + pb]; }
        if (doS) { cs = band[(j + sk) * BW + sk]; }
        __syncthreads();

        if (lane == 0) band[j * BW] = d;
        if (doU) band[(j + pa) * BW + (pa - pb)] -= ca * cb * (dinv * dinv);
        if (doS) band[(j + sk) * BW + sk] = cs * dinv;
        __syncthreads();
    }

    for (int j = 0; j < NV; ++j) {
        const int m = (NV - 1 - j < 6) ? (NV - 1 - j) : 6;
        const float yj = rv[j] / band[j * BW];
        const bool doK = (lane >= 1) && (lane <= m);
        float sub = 0.0f, rj = 0.0f;
        if (doK) { sub = band[(j + lane) * BW + lane] * yj; rj = rv[j + lane]; }
        __syncthreads();
        if (lane == 0) rv[j] = yj;
        if (doK) rv[j + lane] = rj - sub;
        __syncthreads();
    }

    for (int j = NV - 1; j >= 0; --j) {
        const int m = (j < 6) ? j : 6;
        const float xj = rv[j] / band[j * BW];
        const bool doK = (lane >= 1) && (lane <= m);
        float sub = 0.0f, rj = 0.0f;
        if (doK) { sub = band[j * BW + lane] * xj; rj = rv[j - lane]; }
        __syncthreads();
        if (lane == 0) rv[j] = xj;
        if (doK) rv[j - lane] = rj - sub;
        __syncthreads();
    }

    for (int i = lane; i < NV; i += 64)
        out[b * NV + i] = rv[i];
}

extern "C" void kernel_launch(void* const* d_in, const int* in_sizes, int n_in,
                              void* d_out, int out_size, void* d_ws, size_t ws_size,
                              hipStream_t stream)
{
    const float* coeffs = (const float*)d_in[0];   // 1024*64*3
    const float* rhs    = (const float*)d_in[1];   // 1024*64
    const float* iv_rhs = (const float*)d_in[2];   // 1024*2*2
    const float* steps  = (const float*)d_in[3];   // 1024*63
    float* out = (float*)d_out;                    // 1024*192

    const size_t need = (size_t)NBLK * BP_SLOTS * 32 * sizeof(float);   // ~4.1 MB

    if (ws_size >= need) {
        ode_mega3<<<dim3(NBLK), dim3(256), 0, stream>>>(coeffs, rhs, steps, iv_rhs,
                                                        (float*)d_ws, out);
    } else {
        ode_banded_solve<<<dim3(NB), dim3(64), 0, stream>>>(coeffs, rhs, iv_rhs,
                                                            steps, out);
    }
}

// Round 13
// 35.720 us; speedup vs baseline: 3.5252x; 1.0409x over previous
//
#include <hip/hip_runtime.h>
#include <math.h>

// Problem constants (static config)
#define NB 1024
#define NS 64
#define NT 63
#define NV 192
#define BW 7
#define NC 314

#define NBLK 64             // blocks; each handles 16 batches (32 lanes = 2 chains)
#define PB 16               // batches (pairs) per block
#define BP_SLOTS (31*16)    // per-block BP slots, x32 lanes each

// ============================================================================
// ode_mega4: single-kernel pipeline, 64 blocks x 256 threads.
// r12 structure (role-rotated 6-col factor groups, zero shift movs) with the
// BP piece loads scheduled THREE buffer-pairs deep (TA/TB, UA/UB, VA/VB):
// each group's 32 loads issue ~2 G6 groups (~1000+ cy) before first use,
// covering HBM-miss latency (counters showed ~40% of BP reads miss L2).
// All arithmetic identical to the verified r9-r12 kernels.
// ============================================================================
__global__ __launch_bounds__(256, 1)
void ode_mega4(const float* __restrict__ coeffs,
               const float* __restrict__ rhs,
               const float* __restrict__ steps,
               const float* __restrict__ iv_rhs,
               float* __restrict__ wsBP,
               float* __restrict__ out)
{
    const int w   = blockIdx.x;     // 0..63
    const int tid = threadIdx.x;

    __shared__ float cf[PB * 193];
    __shared__ float sl[PB * 65];
    __shared__ float rl[PB * 65];
    __shared__ float il[PB * 4];
    __shared__ float midl[27 * PB];
    __shared__ float mxl[6 * PB];
    __shared__ float lql[93 * 8 * 32];  // 95 KB
    __shared__ float xql[93 * 33];      // padded stride 33 (conflict-free)

    // ---------------- Phase 0a: stage inputs (coalesced) ----------------
    for (int idx = tid; idx < PB * 192; idx += 256) {
        const int b = idx / 192, j = idx - 192 * b;
        cf[b * 193 + j] = coeffs[(size_t)w * (PB * 192) + idx];
    }
    for (int idx = tid; idx < PB * 63; idx += 256) {
        const int b = idx / 63, j = idx - 63 * b;
        sl[b * 65 + j] = steps[(size_t)w * (PB * 63) + idx];
    }
    for (int idx = tid; idx < PB * 64; idx += 256) {
        const int b = idx >> 6, j = idx & 63;
        rl[b * 65 + j] = rhs[(size_t)w * (PB * 64) + idx];
    }
    if (tid < PB * 4) il[tid] = iv_rhs[(size_t)w * (PB * 4) + tid];
    __syncthreads();

    // ---------------- Phase 0b: band pieces + middle pre-Schur ----------------
    for (int idx = tid; idx < 31 * PB; idx += 256) {
        const int it = idx >> 4;
        const int pr = idx & 15;
        const float* cfp = cf + pr * 193;
        const float* slp = sl + pr * 65;
        const float* rlp = rl + pr * 65;

        float F[16], G[16];
        {   // fwd pieces, step t = it
            const int t = it;
            const float c0 = cfp[3*t], c1 = cfp[3*t+1], c2 = cfp[3*t+2];
            const float r  = rlp[t];
            const float p  = (t >= 1) ? slp[t-1] : 0.f;
            const float s  = slp[t];
            const float sn = slp[t+1];
            const float mP = (t >= 1) ? 1.f : 0.f;
            const float rg = (t < 2) ? 1.f : 0.f;
            float iv0 = 0.f, iv1 = 0.f;
            if (t < 2) { iv0 = il[pr*4 + t*2]; iv1 = il[pr*4 + t*2 + 1]; }
            const float s2 = s*s, s3 = s2*s, p2 = p*p, p3 = p2*p, gt = p + s;
            F[0]  = c0*c0 + rg + 2.f*(1.f + mP);
            F[1]  = c0*c1 + s - p;
            F[2]  = c0*c2 + 0.5f*(s2 + p2);
            F[3]  = s;
            F[4]  = -0.5f*s2;
            F[5]  = c0*r + iv0;
            F[6]  = c1*c1 + 3.f*(s2 + p2) + 2.f;
            F[7]  = c1*c2 + 1.5f*(s3 - p3);
            F[8]  = -s;
            F[9]  = -2.f*s2;
            F[10] = s3 + (s + sn);
            F[11] = c1*r + iv1;
            F[12] = c2*c2 + 1.25f*(s2*s2 + p2*p2) + gt*gt*mP;
            F[13] = -0.5f*s2;
            F[14] = -s3 - gt*mP;
            F[15] = c2*r;
        }
        {   // bwd pieces, step t = 63 - it
            const int t = 63 - it;
            const float c0 = cfp[3*t], c1 = cfp[3*t+1], c2 = cfp[3*t+2];
            const float r  = rlp[t];
            const float s  = (t < 63) ? slp[t] : 0.f;
            const float p  = slp[t-1];
            const float pp = slp[t-2];
            const float mSb  = (t < 63) ? 1.f : 0.f;
            const float mCNb = (t < 62) ? 1.f : 0.f;
            const float s2 = s*s, s3 = s2*s, p2 = p*p, p3 = p2*p, gt = p + s;
            G[0]  = c2*c2 + 1.25f*(s2*s2 + p2*p2) + gt*gt*mSb;
            G[1]  = c1*c2 + 1.5f*(s3 - p3);
            G[2]  = c0*c2 + 0.5f*(s2 + p2);
            G[3]  = p3 + (p + s)*mSb;
            G[4]  = -0.5f*p2;
            G[5]  = c2*r;
            G[6]  = c1*c1 + 3.f*(s2 + p2) + mCNb + 1.f;
            G[7]  = c0*c1 + s - p;
            G[8]  = -p3 - (pp + p);
            G[9]  = -2.f*p2;
            G[10] = p;
            G[11] = c1*r;
            G[12] = c0*c0 + 2.f*(mSb + 1.f);
            G[13] = -0.5f*p2;
            G[14] = -p;
            G[15] = c0*r;
        }
        float2* dst = (float2*)wsBP + (size_t)w * (BP_SLOTS * 16)
                                    + (size_t)it * 256 + pr;
        #pragma unroll
        for (int k = 0; k < 16; ++k) dst[(size_t)k * 16] = make_float2(F[k], G[k]);
    }

    if (tid < PB) {
        const int pr = tid;
        const float* cfp = cf + pr * 193;
        const float* slp = sl + pr * 65;
        const float* rlp = rl + pr * 65;
        const float pA = slp[30], sA = slp[31], snA = slp[32];
        const float sB = slp[32], pBm = sA;
        const float c0A = cfp[93], c1A = cfp[94], c2A = cfp[95];
        const float c0B = cfp[96], c1B = cfp[97], c2B = cfp[98];
        const float rA = rlp[31], rB = rlp[32];
        const float sA2 = sA*sA, sA3 = sA2*sA, pA2 = pA*pA, pA3 = pA2*pA;
        const float sB2 = sB*sB, sB3 = sB2*sB, pB2 = pBm*pBm, pB3 = pB2*pBm;
        float m[27];
        m[0]  = c0A*c0A + 4.f;
        m[1]  = c0A*c1A + sA - pA;
        m[2]  = c0A*c2A + 0.5f*(sA2 + pA2);
        m[3]  = -2.f;
        m[4]  = sA;
        m[5]  = -0.5f*sA2;
        m[6]  = c1A*c1A + 3.f*(sA2 + pA2) + 2.f;
        m[7]  = c1A*c2A + 1.5f*(sA3 - pA3);
        m[8]  = -sA;
        m[9]  = -2.f*sA2;
        m[10] = sA3 + (sA + snA);
        m[11] = c2A*c2A + 1.25f*(sA2*sA2 + pA2*pA2) + (pA + sA)*(pA + sA);
        m[12] = -0.5f*sA2;
        m[13] = -sA3 - (pA + sA);
        m[14] = 0.f;
        m[15] = c0B*c0B + 4.f;
        m[16] = c0B*c1B + sB - pBm;
        m[17] = c0B*c2B + 0.5f*(sB2 + pB2);
        m[18] = c1B*c1B + 3.f*(sB2 + pB2) + 2.f;
        m[19] = c1B*c2B + 1.5f*(sB3 - pB3);
        m[20] = c2B*c2B + 1.25f*(sB2*sB2 + pB2*pB2) + (pBm + sB)*(pBm + sB);
        m[21] = c0A*rA; m[22] = c1A*rA; m[23] = c2A*rA;
        m[24] = c0B*rB; m[25] = c1B*rB; m[26] = c2B*rB;
        #pragma unroll
        for (int k = 0; k < 27; ++k) midl[k * PB + pr] = m[k];
    }

    __syncthreads();

    // ---------------- Phase 1: serial twisted solve (lanes 0..31) ----------------
    if (tid < 32) {
        const int l     = tid;
        const int pair  = l >> 1;
        const int chain = l & 1;
        const float cA  = chain ? 0.f : -2.f;
        const float cB  = chain ? -2.f : 0.f;

        const float* __restrict__ bp = wsBP + (size_t)w * (BP_SLOTS * 32) + l;

#define SBP(it, k) bp[(size_t)(((it) * 16 + (k)) * 32)]
#define SL(i)      lql[(i) * 32 + l]
#define SXQ(q)     xql[(q) * 33 + l]

        // records: the last 6 produced L-columns (n1..n6, y)
        float An1=0,An2=0,An3=0,An4=0,An5=0,An6=0,Ay=0;
        float Bn1=0,Bn2=0,Bn3=0,Bn4=0,Bn5=0,Bn6=0,By=0;
        float Cn1=0,Cn2=0,Cn3=0,Cn4=0,Cn5=0,Cn6=0,Cy=0;
        float Dn1=0,Dn2=0,Dn3=0,Dn4=0,Dn5=0,Dn6=0,Dy=0;
        float En1=0,En2=0,En3=0,En4=0,En5=0,En6=0,Ey=0;
        float Fn1=0,Fn2=0,Fn3=0,Fn4=0,Fn5=0,Fn6=0,Fy=0;

#define CHOL_STEP(R1,R2,R3,R4,R5,R6, q, b0, b1, b2, b3, b4, b5, b6, rvv)       \
    {                                                                          \
        const float t0_ = (b0) - (R1##n1*R1##n1 + R2##n2*R2##n2 +              \
            R3##n3*R3##n3 + R4##n4*R4##n4 + R5##n5*R5##n5 + R6##n6*R6##n6);    \
        const float di_ = rsqrtf(t0_);                                         \
        const float u1_ = (b1) - (R1##n1*R1##n2 + R2##n2*R2##n3 +              \
            R3##n3*R3##n4 + R4##n4*R4##n5 + R5##n5*R5##n6);                    \
        const float u2_ = (b2) - (R1##n1*R1##n3 + R2##n2*R2##n4 +              \
            R3##n3*R3##n5 + R4##n4*R4##n6);                                    \
        const float u3_ = (b3) - (R1##n1*R1##n4 + R2##n2*R2##n5 + R3##n3*R3##n6); \
        const float u4_ = (b4) - (R1##n1*R1##n5 + R2##n2*R2##n6);              \
        const float u5_ = (b5) - (R1##n1*R1##n6);                              \
        const float u6_ = (b6);                                                \
        const float yj_ = ((rvv) - (R1##n1*R1##y + R2##n2*R2##y +              \
            R3##n3*R3##y + R4##n4*R4##y + R5##n5*R5##y + R6##n6*R6##y)) * di_; \
        R6##n1 = u1_*di_; R6##n2 = u2_*di_; R6##n3 = u3_*di_;                  \
        R6##n4 = u4_*di_; R6##n5 = u5_*di_; R6##n6 = u6_*di_;                  \
        R6##y  = yj_;                                                          \
        SL((q)*8 + 0) = di_;    SL((q)*8 + 1) = R6##n1;                        \
        SL((q)*8 + 2) = R6##n2; SL((q)*8 + 3) = R6##n3;                        \
        SL((q)*8 + 4) = R6##n4; SL((q)*8 + 5) = R6##n5;                        \
        SL((q)*8 + 6) = R6##n6; SL((q)*8 + 7) = yj_;                           \
    }

#define CHOL_CAP(R1,R2,R3,R4,R5,R6, P, b0, b1, b2, b3, b4, b5, b6, rvv)        \
    {                                                                          \
        const float t0_ = (b0) - (R1##n1*R1##n1 + R2##n2*R2##n2 +              \
            R3##n3*R3##n3 + R4##n4*R4##n4 + R5##n5*R5##n5 + R6##n6*R6##n6);    \
        const float di_ = rsqrtf(t0_);                                         \
        const float u1_ = (b1) - (R1##n1*R1##n2 + R2##n2*R2##n3 +              \
            R3##n3*R3##n4 + R4##n4*R4##n5 + R5##n5*R5##n6);                    \
        const float u2_ = (b2) - (R1##n1*R1##n3 + R2##n2*R2##n4 +              \
            R3##n3*R3##n5 + R4##n4*R4##n6);                                    \
        const float u3_ = (b3) - (R1##n1*R1##n4 + R2##n2*R2##n5 + R3##n3*R3##n6); \
        const float u4_ = (b4) - (R1##n1*R1##n5 + R2##n2*R2##n6);              \
        const float u5_ = (b5) - (R1##n1*R1##n6);                              \
        const float u6_ = (b6);                                                \
        const float yj_ = ((rvv) - (R1##n1*R1##y + R2##n2*R2##y +              \
            R3##n3*R3##y + R4##n4*R4##y + R5##n5*R5##y + R6##n6*R6##y)) * di_; \
        R6##n1 = u1_*di_; R6##n2 = u2_*di_; R6##n3 = u3_*di_;                  \
        R6##n4 = u4_*di_; R6##n5 = u5_*di_; R6##n6 = u6_*di_;                  \
        R6##y  = yj_;                                                          \
        P##d = di_;     P##1 = R6##n1; P##2 = R6##n2; P##3 = R6##n3;           \
        P##4 = R6##n4;  P##5 = R6##n5; P##6 = R6##n6; P##y = yj_;              \
    }

#define LD16(X, it) { X##0 = SBP(it,0);  X##1 = SBP(it,1);  X##2 = SBP(it,2);  \
        X##3 = SBP(it,3);  X##4 = SBP(it,4);  X##5 = SBP(it,5);                \
        X##6 = SBP(it,6);  X##7 = SBP(it,7);  X##8 = SBP(it,8);                \
        X##9 = SBP(it,9);  X##10 = SBP(it,10); X##11 = SBP(it,11);             \
        X##12 = SBP(it,12); X##13 = SBP(it,13); X##14 = SBP(it,14);            \
        X##15 = SBP(it,15); }

#define G6(X, Y, q0)                                                           \
    CHOL_STEP(A,B,C,D,E,F, (q0)+0, X##0,  X##1,  X##2,  cA,    X##3,  X##4, 0.f,  X##5)  \
    CHOL_STEP(F,A,B,C,D,E, (q0)+1, X##6,  X##7,  X##8,  X##9,  X##10, 0.f, -1.f, X##11) \
    CHOL_STEP(E,F,A,B,C,D, (q0)+2, X##12, X##13, X##14, cB,    0.f,   0.f, 0.f,  X##15) \
    CHOL_STEP(D,E,F,A,B,C, (q0)+3, Y##0,  Y##1,  Y##2,  cA,    Y##3,  Y##4, 0.f,  Y##5)  \
    CHOL_STEP(C,D,E,F,A,B, (q0)+4, Y##6,  Y##7,  Y##8,  Y##9,  Y##10, 0.f, -1.f, Y##11) \
    CHOL_STEP(B,C,D,E,F,A, (q0)+5, Y##12, Y##13, Y##14, cB,    0.f,   0.f, 0.f,  Y##15)

        // three piece-buffer pairs: TA/TB, UA/UB, VA/VB (groups g, g+1, g+2)
        float TA0,TA1,TA2,TA3,TA4,TA5,TA6,TA7,TA8,TA9,TA10,TA11,TA12,TA13,TA14,TA15;
        float TB0,TB1,TB2,TB3,TB4,TB5,TB6,TB7,TB8,TB9,TB10,TB11,TB12,TB13,TB14,TB15;
        float UA0,UA1,UA2,UA3,UA4,UA5,UA6,UA7,UA8,UA9,UA10,UA11,UA12,UA13,UA14,UA15;
        float UB0,UB1,UB2,UB3,UB4,UB5,UB6,UB7,UB8,UB9,UB10,UB11,UB12,UB13,UB14,UB15;
        float VA0,VA1,VA2,VA3,VA4,VA5,VA6,VA7,VA8,VA9,VA10,VA11,VA12,VA13,VA14,VA15;
        float VB0,VB1,VB2,VB3,VB4,VB5,VB6,VB7,VB8,VB9,VB10,VB11,VB12,VB13,VB14,VB15;

        // preload groups 0..2 (steps 0..5)
        LD16(TA, 0) LD16(TB, 1)
        LD16(UA, 2) LD16(UB, 3)
        LD16(VA, 4) LD16(VB, 5)

        // groups 0..14 (steps 0..29); loads for group g+3 issued after group g
        for (int g = 0; g < 15; g += 3) {
            G6(TA, TB, 6*g)
            {   const int s0 = 2*g + 6, s1 = 2*g + 7;
                if (s0 <= 30) LD16(TA, s0)
                if (s1 <= 30) LD16(TB, s1)
            }
            G6(UA, UB, 6*(g + 1))
            {   const int s0 = 2*g + 8, s1 = 2*g + 9;
                if (s0 <= 30) LD16(UA, s0)
                if (s1 <= 30) LD16(UB, s1)
            }
            G6(VA, VB, 6*(g + 2))
            {   const int s0 = 2*g + 10, s1 = 2*g + 11;
                if (s0 <= 30) LD16(VA, s0)
                if (s1 <= 30) LD16(VB, s1)
            }
        }
        // step-30 pieces were loaded into TA at g=12 (2*12+6 = 30)

#define DECL8(P) float P##d = 0, P##1 = 0, P##2 = 0, P##3 = 0,                 \
                       P##4 = 0, P##5 = 0, P##6 = 0, P##y = 0;
#define LOAD8(P, q) { const int o8 = (q)*8;                                    \
        P##d = SL(o8 + 0); P##1 = SL(o8 + 1); P##2 = SL(o8 + 2);               \
        P##3 = SL(o8 + 3); P##4 = SL(o8 + 4); P##5 = SL(o8 + 5);               \
        P##6 = SL(o8 + 6); P##y = SL(o8 + 7); }

        DECL8(PA) DECL8(PB_) DECL8(PC)
        DECL8(QA) DECL8(QB) DECL8(QC)
        DECL8(RA) DECL8(RB) DECL8(RC)

        // peel step 30 (cols q90..92), captured into backsub registers
        CHOL_CAP(A,B,C,D,E,F, PA,  TA0,  TA1,  TA2,  cA,   TA3,  TA4, 0.f,  TA5)
        CHOL_CAP(F,A,B,C,D,E, PB_, TA6,  TA7,  TA8,  TA9,  TA10, 0.f, -1.f, TA11)
        CHOL_CAP(E,F,A,B,C,D, PC,  TA12, TA13, TA14, cB,   0.f,  0.f, 0.f,  TA15)

        LOAD8(QC, 89) LOAD8(QB, 88) LOAD8(QA, 87)
        LOAD8(RC, 86) LOAD8(RB, 85) LOAD8(RA, 84)

        // final record order (93 cols, rotation 93 mod 6 = 3): newest..oldest
        // = D, E, F, A, B, C. Map to the verified W/y names.
        const float W11=Dn1, W12=Dn2, W13=Dn3, W14=Dn4, W15=Dn5, W16=Dn6;
        const float W22=En2, W23=En3, W24=En4, W25=En5, W26=En6;
        const float W33=Fn3, W34=Fn4, W35=Fn5, W36=Fn6;
        const float W44=An4, W45=An5, W46=An6;
        const float W55=Bn5, W56=Bn6;
        const float W66=Cn6;
        const float y1=Dy, y2=Ey, y3=Fy, y4=Ay, y5=By, y6=Cy;

        const float R11=__shfl_xor(W11,1), R12=__shfl_xor(W12,1), R13=__shfl_xor(W13,1);
        const float R14=__shfl_xor(W14,1), R15=__shfl_xor(W15,1), R16=__shfl_xor(W16,1);
        const float R22=__shfl_xor(W22,1), R23=__shfl_xor(W23,1), R24=__shfl_xor(W24,1);
        const float R25=__shfl_xor(W25,1), R26=__shfl_xor(W26,1);
        const float R33=__shfl_xor(W33,1), R34=__shfl_xor(W34,1), R35=__shfl_xor(W35,1);
        const float R36=__shfl_xor(W36,1);
        const float R44=__shfl_xor(W44,1), R45=__shfl_xor(W45,1), R46=__shfl_xor(W46,1);
        const float R55=__shfl_xor(W55,1), R56=__shfl_xor(W56,1);
        const float R66=__shfl_xor(W66,1);
        const float r1=__shfl_xor(y1,1), r2=__shfl_xor(y2,1), r3=__shfl_xor(y3,1);
        const float r4=__shfl_xor(y4,1), r5=__shfl_xor(y5,1), r6=__shfl_xor(y6,1);

        float xm0=0, xm1=0, xm2=0, xm3=0, xm4=0, xm5=0;
        if (chain == 0) {
            const float* __restrict__ md = midl + pair;
            float S00 = md[0*PB],  S10 = md[1*PB],  S20 = md[2*PB];
            float S30 = md[3*PB],  S40 = md[4*PB],  S50 = md[5*PB];
            float S11 = md[6*PB],  S21 = md[7*PB],  S31 = md[8*PB];
            float S41 = md[9*PB],  S51 = md[10*PB], S22 = md[11*PB];
            float S32 = md[12*PB], S42 = md[13*PB], S52 = md[14*PB];
            float S33 = md[15*PB], S43 = md[16*PB], S53 = md[17*PB];
            float S44 = md[18*PB], S54 = md[19*PB], S55 = md[20*PB];
            float fm0 = md[21*PB], fm1 = md[22*PB], fm2 = md[23*PB];
            float fm3 = md[24*PB], fm4 = md[25*PB], fm5 = md[26*PB];

            S00 -= W11*W11 + W22*W22 + W33*W33 + W44*W44 + W55*W55 + W66*W66;
            S10 -= W12*W11 + W23*W22 + W34*W33 + W45*W44 + W56*W55;
            S11 -= W12*W12 + W23*W23 + W34*W34 + W45*W45 + W56*W56;
            S20 -= W13*W11 + W24*W22 + W35*W33 + W46*W44;
            S21 -= W13*W12 + W24*W23 + W35*W34 + W46*W45;
            S22 -= W13*W13 + W24*W24 + W35*W35 + W46*W46;
            S30 -= W14*W11 + W25*W22 + W36*W33;
            S31 -= W14*W12 + W25*W23 + W36*W34;
            S32 -= W14*W13 + W25*W24 + W36*W35;
            S33 -= W14*W14 + W25*W25 + W36*W36;
            S40 -= W15*W11 + W26*W22;
            S41 -= W15*W12 + W26*W23;
            S42 -= W15*W13 + W26*W24;
            S43 -= W15*W14 + W26*W25;
            S44 -= W15*W15 + W26*W26;
            S50 -= W16*W11;
            S51 -= W16*W12;
            S52 -= W16*W13;
            S53 -= W16*W14;
            S54 -= W16*W15;
            S55 -= W16*W16;

            S00 -= R16*R16;
            S10 -= R15*R16;
            S11 -= R15*R15 + R26*R26;
            S20 -= R14*R16;
            S21 -= R14*R15 + R25*R26;
            S22 -= R14*R14 + R25*R25 + R36*R36;
            S30 -= R13*R16;
            S31 -= R13*R15 + R24*R26;
            S32 -= R13*R14 + R24*R25 + R35*R36;
            S33 -= R13*R13 + R24*R24 + R35*R35 + R46*R46;
            S40 -= R12*R16;
            S41 -= R12*R15 + R23*R26;
            S42 -= R12*R14 + R23*R25 + R34*R36;
            S43 -= R12*R13 + R23*R24 + R34*R35 + R45*R46;
            S44 -= R12*R12 + R23*R23 + R34*R34 + R45*R45 + R56*R56;
            S50 -= R11*R16;
            S51 -= R11*R15 + R22*R26;
            S52 -= R11*R14 + R22*R25 + R33*R36;
            S53 -= R11*R13 + R22*R24 + R33*R35 + R44*R46;
            S54 -= R11*R12 + R22*R23 + R33*R34 + R44*R45 + R55*R56;
            S55 -= R11*R11 + R22*R22 + R33*R33 + R44*R44 + R55*R55 + R66*R66;

            fm0 -= (W11*y1 + W22*y2 + W33*y3 + W44*y4 + W55*y5 + W66*y6) + (R16*r1);
            fm1 -= (W12*y1 + W23*y2 + W34*y3 + W45*y4 + W56*y5) + (R15*r1 + R26*r2);
            fm2 -= (W13*y1 + W24*y2 + W35*y3 + W46*y4) + (R14*r1 + R25*r2 + R36*r3);
            fm3 -= (W14*y1 + W25*y2 + W36*y3) + (R13*r1 + R24*r2 + R35*r3 + R46*r4);
            fm4 -= (W15*y1 + W26*y2) + (R12*r1 + R23*r2 + R34*r3 + R45*r4 + R56*r5);
            fm5 -= (W16*y1) + (R11*r1 + R22*r2 + R33*r3 + R44*r4 + R55*r5 + R66*r6);

            const float md0 = rsqrtf(S00);
            const float M10 = S10*md0, M20 = S20*md0, M30 = S30*md0,
                        M40 = S40*md0, M50 = S50*md0;
            const float zm0 = fm0*md0;
            const float md1 = rsqrtf(S11 - M10*M10);
            const float M21 = (S21 - M20*M10)*md1;
            const float M31 = (S31 - M30*M10)*md1;
            const float M41 = (S41 - M40*M10)*md1;
            const float M51 = (S51 - M50*M10)*md1;
            const float zm1 = (fm1 - M10*zm0)*md1;
            const float md2 = rsqrtf(S22 - M20*M20 - M21*M21);
            const float M32 = (S32 - M30*M20 - M31*M21)*md2;
            const float M42 = (S42 - M40*M20 - M41*M21)*md2;
            const float M52 = (S52 - M50*M20 - M51*M21)*md2;
            const float zm2 = (fm2 - M20*zm0 - M21*zm1)*md2;
            const float md3 = rsqrtf(S33 - M30*M30 - M31*M31 - M32*M32);
            const float M43 = (S43 - M40*M30 - M41*M31 - M42*M32)*md3;
            const float M53 = (S53 - M50*M30 - M51*M31 - M52*M32)*md3;
            const float zm3 = (fm3 - M30*zm0 - M31*zm1 - M32*zm2)*md3;
            const float md4 = rsqrtf(S44 - M40*M40 - M41*M41 - M42*M42 - M43*M43);
            const float M54 = (S54 - M50*M40 - M51*M41 - M52*M42 - M53*M43)*md4;
            const float zm4 = (fm4 - M40*zm0 - M41*zm1 - M42*zm2 - M43*zm3)*md4;
            const float md5 = rsqrtf(S55 - M50*M50 - M51*M51 - M52*M52 - M53*M53 - M54*M54);
            const float zm5 = (fm5 - M50*zm0 - M51*zm1 - M52*zm2 - M53*zm3 - M54*zm4)*md5;

            xm5 = zm5*md5;
            xm4 = (zm4 - M54*xm5)*md4;
            xm3 = (zm3 - M43*xm4 - M53*xm5)*md3;
            xm2 = (zm2 - M32*xm3 - M42*xm4 - M52*xm5)*md2;
            xm1 = (zm1 - M21*xm2 - M31*xm3 - M41*xm4 - M51*xm5)*md1;
            xm0 = (zm0 - M10*xm1 - M20*xm2 - M30*xm3 - M40*xm4 - M50*xm5)*md0;

            mxl[0*PB + pair] = xm0; mxl[1*PB + pair] = xm1; mxl[2*PB + pair] = xm2;
            mxl[3*PB + pair] = xm3; mxl[4*PB + pair] = xm4; mxl[5*PB + pair] = xm5;
        }

        const float g0 = __shfl_xor(xm0, 1), g1 = __shfl_xor(xm1, 1);
        const float g2 = __shfl_xor(xm2, 1), g3 = __shfl_xor(xm3, 1);
        const float g4 = __shfl_xor(xm4, 1), g5 = __shfl_xor(xm5, 1);

        float x1 = chain ? g5 : xm0;
        float x2 = chain ? g4 : xm1;
        float x3 = chain ? g3 : xm2;
        float x4 = chain ? g2 : xm3;
        float x5 = chain ? g1 : xm4;
        float x6 = chain ? g0 : xm5;

#define BSUB(P, q) {                                                           \
        const float rest = (P##6*x6 + P##5*x5) + (P##4*x4 + P##3*x3) + P##2*x2;\
        const float xr = ((P##y - rest) - P##1*x1) * P##d;                     \
        SXQ(q) = xr;                                                           \
        x6 = x5; x5 = x4; x4 = x3; x3 = x2; x2 = x1; x1 = xr; }

        for (int it2 = 0; it2 < 31; it2 += 3) {
            {   const int st = 30 - it2;
                BSUB(PC, 3*st + 2) BSUB(PB_, 3*st + 1) BSUB(PA, 3*st)
                if (st - 3 >= 0) { LOAD8(PC, 3*(st-3) + 2) LOAD8(PB_, 3*(st-3) + 1) LOAD8(PA, 3*(st-3)) }
            }
            {   const int st = 29 - it2;
                if (st >= 0) {
                    BSUB(QC, 3*st + 2) BSUB(QB, 3*st + 1) BSUB(QA, 3*st)
                    if (st - 3 >= 0) { LOAD8(QC, 3*(st-3) + 2) LOAD8(QB, 3*(st-3) + 1) LOAD8(QA, 3*(st-3)) }
                }
            }
            {   const int st = 28 - it2;
                if (st >= 0) {
                    BSUB(RC, 3*st + 2) BSUB(RB, 3*st + 1) BSUB(RA, 3*st)
                    if (st - 3 >= 0) { LOAD8(RC, 3*(st-3) + 2) LOAD8(RB, 3*(st-3) + 1) LOAD8(RA, 3*(st-3)) }
                }
            }
        }

#undef SBP
#undef SL
#undef SXQ
#undef CHOL_STEP
#undef CHOL_CAP
#undef LD16
#undef G6
#undef DECL8
#undef LOAD8
#undef BSUB
    }

    __syncthreads();

    // ---------------- Phase 2: output mapping (coalesced writes) ----------------
    for (int idx = tid; idx < PB * 192; idx += 256) {
        const int bl = idx / 192;
        const int j  = idx - bl * 192;
        float v;
        if (j < 93)      v = xql[j * 33 + 2 * bl];
        else if (j > 98) v = xql[(191 - j) * 33 + 2 * bl + 1];
        else             v = mxl[(j - 93) * PB + bl];
        out[(size_t)w * (PB * 192) + idx] = v;
    }
}

// ============================================================================
// Fallback (round-1 kernel, known-pass): used only if ws is too small
// ============================================================================
__global__ __launch_bounds__(64, 1)
void ode_banded_solve(const float* __restrict__ coeffs,
                      const float* __restrict__ rhs,
                      const float* __restrict__ iv_rhs,
                      const float* __restrict__ steps,
                      float* __restrict__ out)
{
    const int b    = blockIdx.x;
    const int lane = threadIdx.x;

    __shared__ float band[NV * BW];
    __shared__ float rv[NV];
    __shared__ float stp[NT + 1];

    for (int i = lane; i < NV * BW; i += 64) band[i] = 0.0f;
    if (lane < NT) stp[lane] = steps[b * NT + lane];
    __syncthreads();

    {
        const int st = lane;
        const float c0 = coeffs[b * NV + st * 3 + 0];
        const float c1 = coeffs[b * NV + st * 3 + 1];
        const float c2 = coeffs[b * NV + st * 3 + 2];
        const float r  = rhs[b * NS + st];
        const float reg = (st < 2) ? 1.0f : 0.0f;
        atomicAdd(&band[(3 * st + 0) * BW + 0], c0 * c0 + reg);
        atomicAdd(&band[(3 * st + 1) * BW + 0], c1 * c1 + reg);
        atomicAdd(&band[(3 * st + 2) * BW + 0], c2 * c2);
        atomicAdd(&band[(3 * st + 1) * BW + 1], c1 * c0);
        atomicAdd(&band[(3 * st + 2) * BW + 1], c2 * c1);
        atomicAdd(&band[(3 * st + 2) * BW + 2], c2 * c0);
        float b0 = c0 * r, b1 = c1 * r, b2v = c2 * r;
        if (st < 2) {
            b0 += iv_rhs[b * 4 + st * 2 + 0];
            b1 += iv_rhs[b * 4 + st * 2 + 1];
        }
        rv[3 * st + 0] = b0;
        rv[3 * st + 1] = b1;
        rv[3 * st + 2] = b2v;
    }

    for (int t = lane; t < NC; t += 64) {
        int   cols[4];
        float vals[4];
        int   cnt;
        if (t < 126) {
            const int st = t >> 1, i = t & 1;
            const float s = stp[st];
            if (i == 0) {
                cols[0] = 3 * st + 0; vals[0] = 1.0f;
                cols[1] = 3 * st + 1; vals[1] = s;
                cols[2] = 3 * st + 2; vals[2] = 0.5f * s * s;
                cols[3] = 3 * st + 3; vals[3] = -1.0f;
                cnt = 4;
            } else {
                cols[0] = 3 * st + 1; vals[0] = s;
                cols[1] = 3 * st + 2; vals[1] = s * s;
                cols[2] = 3 * st + 4; vals[2] = -s;
                cnt = 3;
            }
        } else if (t < 188) {
            const int st = t - 126 + 1;
            const float cp = stp[st - 1] + stp[st];
            cols[0] = 3 * st - 2; vals[0] = -1.0f;
            cols[1] = 3 * st + 2; vals[1] = -cp;
            cols[2] = 3 * st + 4; vals[2] = 1.0f;
            cnt = 3;
        } else {
            const int tt = t - 188;
            const int st = tt >> 1, i = tt & 1;
            const float s = stp[st];
            if (i == 0) {
                cols[0] = 3 * st + 0; vals[0] = -1.0f;
                cols[1] = 3 * st + 3; vals[1] = 1.0f;
                cols[2] = 3 * st + 4; vals[2] = -s;
                cols[3] = 3 * st + 5; vals[3] = 0.5f * s * s;
                cnt = 4;
            } else {
                cols[0] = 3 * st + 1; vals[0] = s;
                cols[1] = 3 * st + 4; vals[1] = -s;
                cols[2] = 3 * st + 5; vals[2] = s * s;
                cnt = 3;
            }
        }
        for (int a = 0; a < cnt; ++a)
            for (int b2 = 0; b2 <= a; ++b2)
                atomicAdd(&band[cols[a] * BW + (cols[a] - cols[b2])],
                          vals[a] * vals[b2]);
    }
    __syncthreads();

    int pa = 0, pb = 0;
    {
        int idx = 0;
        for (int aa = 1; aa <= 6; ++aa)
            for (int bb = 1; bb <= aa; ++bb) {
                if (idx == lane) { pa = aa; pb = bb; }
                ++idx;
            }
    }
    const int sk = lane - 20;

    for (int j = 0; j < NV; ++j) {
        const int m = (NV - 1 - j < 6) ? (NV - 1 - j) : 6;
        const float diag = band[j * BW];
        const float d    = sqrtf(diag);
        const float dinv = 1.0f / d;

        const bool doU = (lane < 21) && (pa <= m);
        const bool doS = (lane >= 21) && (lane <= 26) && (sk <= m);
        float ca = 0.0f, cb = 0.0f, cs = 0.0f;
        if (doU) { ca = band[(j + pa) * BW + pa]; cb = band[(j + pb) * BW + pb]; }
        if (doS) { cs = band[(j + sk) * BW + sk]; }
        __syncthreads();

        if (lane == 0) band[j * BW] = d;
        if (doU) band[(j + pa) * BW + (pa - pb)] -= ca * cb * (dinv * dinv);
        if (doS) band[(j + sk) * BW + sk] = cs * dinv;
        __syncthreads();
    }

    for (int j = 0; j < NV; ++j) {
        const int m = (NV - 1 - j < 6) ? (NV - 1 - j) : 6;
        const float yj = rv[j] / band[j * BW];
        const bool doK = (lane >= 1) && (lane <= m);
        float sub = 0.0f, rj = 0.0f;
        if (doK) { sub = band[(j + lane) * BW + lane] * yj; rj = rv[j + lane]; }
        __syncthreads();
        if (lane == 0) rv[j] = yj;
        if (doK) rv[j + lane] = rj - sub;
        __syncthreads();
    }

    for (int j = NV - 1; j >= 0; --j) {
        const int m = (j < 6) ? j : 6;
        const float xj = rv[j] / band[j * BW];
        const bool doK = (lane >= 1) && (lane <= m);
        float sub = 0.0f, rj = 0.0f;
        if (doK) { sub = band[j * BW + lane] * xj; rj = rv[j - lane]; }
        __syncthreads();
        if (lane == 0) rv[j] = xj;
        if (doK) rv[j - lane] = rj - sub;
        __syncthreads();
    }

    for (int i = lane; i < NV; i += 64)
        out[b * NV + i] = rv[i];
}

extern "C" void kernel_launch(void* const* d_in, const int* in_sizes, int n_in,
                              void* d_out, int out_size, void* d_ws, size_t ws_size,
                              hipStream_t stream)
{
    const float* coeffs = (const float*)d_in[0];   // 1024*64*3
    const float* rhs    = (const float*)d_in[1];   // 1024*64
    const float* iv_rhs = (const float*)d_in[2];   // 1024*2*2
    const float* steps  = (const float*)d_in[3];   // 1024*63
    float* out = (float*)d_out;                    // 1024*192

    const size_t need = (size_t)NBLK * BP_SLOTS * 32 * sizeof(float);   // ~4.1 MB

    if (ws_size >= need) {
        ode_mega4<<<dim3(NBLK), dim3(256), 0, stream>>>(coeffs, rhs, steps, iv_rhs,
                                                        (float*)d_ws, out);
    } else {
        ode_banded_solve<<<dim3(NB), dim3(64), 0, stream>>>(coeffs, rhs, iv_rhs,
                                                            steps, out);
    }
}